// Round 2
// baseline (2249.952 us; speedup 1.0000x reference)
//
#include <hip/hip_runtime.h>
#include <math.h>

#define D_STATE 16
#define D_INNER 1800
#define DT_RANK 57
#define NB 2
#define SEQ_L 900
#define DMODEL 900
#define MROWS (NB*SEQ_L)
#define XD_LD 96   // padded leading dim for the 89-col x-proj output

// ---------------- GEMM: C[m,n] = sum_k A[m,k]*B[n,k] (+ epilogue) ----------------
#define BM 64
#define BN 64
#define BK 16

// mode 0: v = (acc+bias)*30 + pe[(m%900)*ldc+n]
// mode 1: v = acc
// mode 3: v = softplus(acc + bias)
// mode 4: v = acc + add[m*ldc+n]
__global__ __launch_bounds__(256)
void gemm_k(const float* __restrict__ A, int lda,
            const float* __restrict__ B, int ldb,
            float* __restrict__ C, int ldc,
            int M, int N, int K,
            const float* __restrict__ bias,
            const float* __restrict__ add,
            int mode)
{
    __shared__ float As[BK][BM + 1];
    __shared__ float Bs[BK][BN + 1];
    int tid = threadIdx.x;
    int tx = tid & 15, ty = tid >> 4;
    int m0 = blockIdx.y * BM, n0 = blockIdx.x * BN;
    float acc[4][4] = {};
    int nkt = (K + BK - 1) / BK;
    for (int kt = 0; kt < nkt; ++kt) {
        int k0 = kt * BK;
#pragma unroll
        for (int i = 0; i < 4; ++i) {
            int idx = tid + i * 256;
            int r = idx >> 4, kk = idx & 15;
            int gr = m0 + r, gk = k0 + kk;
            As[kk][r] = (gr < M && gk < K) ? A[(size_t)gr * lda + gk] : 0.f;
        }
#pragma unroll
        for (int i = 0; i < 4; ++i) {
            int idx = tid + i * 256;
            int c = idx >> 4, kk = idx & 15;
            int gc = n0 + c, gk = k0 + kk;
            Bs[kk][c] = (gc < N && gk < K) ? B[(size_t)gc * ldb + gk] : 0.f;
        }
        __syncthreads();
#pragma unroll
        for (int kk = 0; kk < BK; ++kk) {
            float a[4], b[4];
#pragma unroll
            for (int i = 0; i < 4; ++i) a[i] = As[kk][ty * 4 + i];
#pragma unroll
            for (int j = 0; j < 4; ++j) b[j] = Bs[kk][tx * 4 + j];
#pragma unroll
            for (int i = 0; i < 4; ++i)
#pragma unroll
                for (int j = 0; j < 4; ++j)
                    acc[i][j] = fmaf(a[i], b[j], acc[i][j]);
        }
        __syncthreads();
    }
#pragma unroll
    for (int i = 0; i < 4; ++i) {
        int m = m0 + ty * 4 + i;
        if (m >= M) continue;
#pragma unroll
        for (int j = 0; j < 4; ++j) {
            int n = n0 + tx * 4 + j;
            if (n >= N) continue;
            float v = acc[i][j];
            if (bias) v += bias[n];
            if (mode == 0)      v = v * 30.0f + add[(size_t)(m % SEQ_L) * ldc + n];
            else if (mode == 3) v = (v > 20.f) ? v : log1pf(expf(v));
            else if (mode == 4) v = v + add[(size_t)m * ldc + n];
            C[(size_t)m * ldc + n] = v;
        }
    }
}

// ---------------- RMSNorm (one block per row) ----------------
__global__ __launch_bounds__(256)
void rmsnorm_k(const float* __restrict__ x, const float* __restrict__ w,
               float* __restrict__ y, int ncols)
{
    int row = blockIdx.x;
    const float* xr = x + (size_t)row * ncols;
    float s = 0.f;
    for (int c = threadIdx.x; c < ncols; c += 256) { float v = xr[c]; s += v * v; }
    __shared__ float red[4];
#pragma unroll
    for (int off = 32; off; off >>= 1) s += __shfl_down(s, off, 64);
    int wave = threadIdx.x >> 6;
    if ((threadIdx.x & 63) == 0) red[wave] = s;
    __syncthreads();
    float tot = red[0] + red[1] + red[2] + red[3];
    float scale = rsqrtf(tot / (float)ncols + 1e-5f);
    for (int c = threadIdx.x; c < ncols; c += 256)
        y[(size_t)row * ncols + c] = xr[c] * scale * w[c];
}

__device__ inline float silu_f(float x) { return x / (1.f + expf(-x)); }

// ---------------- causal depthwise conv (fwd + channel-reversed) + silu ----------------
__global__ __launch_bounds__(256)
void conv_silu_k(const float* __restrict__ xr, const float* __restrict__ w,
                 const float* __restrict__ cb,
                 float* __restrict__ xmc, float* __restrict__ xbc)
{
    int idx = blockIdx.x * 256 + threadIdx.x;
    if (idx >= MROWS * D_INNER) return;
    int d = idx % D_INNER;
    int row = idx / D_INNER;          // b*L + l
    int l = row % SEQ_L;
    int b = row / SEQ_L;
    float wv[4];
#pragma unroll
    for (int k = 0; k < 4; ++k) wv[k] = w[d * 4 + k];
    float bias = cb[d];
    int rd = D_INNER - 1 - d;
    float sf = 0.f, sb = 0.f;
#pragma unroll
    for (int k = 0; k < 4; ++k) {
        int ll = l - 3 + k;
        if (ll < 0) continue;
        const float* rowp = xr + (size_t)(b * SEQ_L + ll) * (2 * D_INNER);
        sf = fmaf(wv[k], rowp[d], sf);
        sb = fmaf(wv[k], rowp[rd], sb);
    }
    sf += bias; sb += bias;
    xmc[idx] = silu_f(sf);
    xbc[idx] = silu_f(sb);
}

// ---------------- selective scan: one thread per (b,dir,d), 16 states in regs ----------------
__global__ __launch_bounds__(256)
void scan_k(const float* __restrict__ dm, const float* __restrict__ db,
            const float* __restrict__ um, const float* __restrict__ ub,
            const float* __restrict__ xdm, const float* __restrict__ xdb,
            const float* __restrict__ A_log, const float* __restrict__ Dv,
            float* __restrict__ ym, float* __restrict__ yb)
{
    int d = blockIdx.x * 256 + threadIdx.x;
    if (d >= D_INNER) return;
    int b = blockIdx.y;
    int dir = blockIdx.z;
    const float* dl = dir ? db : dm;
    const float* u  = dir ? ub : um;
    const float* xd = dir ? xdb : xdm;
    float* y        = dir ? yb : ym;
    float Aa[D_STATE];
#pragma unroll
    for (int n = 0; n < D_STATE; ++n) Aa[n] = -expf(A_log[d * D_STATE + n]);
    float Dd = Dv[d];
    float h[D_STATE] = {};
    for (int l = 0; l < SEQ_L; ++l) {
        size_t rowi = (size_t)(b * SEQ_L + l);
        float delta = dl[rowi * D_INNER + d];
        float uu    = u[rowi * D_INNER + d];
        const float* bc = xd + rowi * XD_LD;
        float du = delta * uu;
        float acc = uu * Dd;
#pragma unroll
        for (int n = 0; n < D_STATE; ++n) {
            float dA = __expf(delta * Aa[n]);
            h[n] = fmaf(dA, h[n], du * bc[DT_RANK + n]);
            acc = fmaf(h[n], bc[DT_RANK + D_STATE + n], acc);
        }
        y[rowi * D_INNER + d] = acc;   // in-place over delta is safe (read-before-write per element)
    }
}

// ---------------- gating: yc = (ym + yb[channel-reversed]) * silu(res) ----------------
__global__ __launch_bounds__(256)
void gate_k(const float* __restrict__ ym, const float* __restrict__ yb,
            const float* __restrict__ xr, float* __restrict__ yc)
{
    int idx = blockIdx.x * 256 + threadIdx.x;
    if (idx >= MROWS * D_INNER) return;
    int d = idx % D_INNER;
    int row = idx / D_INNER;
    float g = silu_f(xr[(size_t)row * (2 * D_INNER) + D_INNER + d]);
    float v = ym[idx] + yb[(size_t)row * D_INNER + (D_INNER - 1 - d)];
    yc[idx] = v * g;
}

extern "C" void kernel_launch(void* const* d_in, const int* in_sizes, int n_in,
                              void* d_out, int out_size, void* d_ws, size_t ws_size,
                              hipStream_t stream)
{
    const float* inp    = (const float*)d_in[0];
    const float* W_emb  = (const float*)d_in[1];
    const float* b_emb  = (const float*)d_in[2];
    const float* norm_w = (const float*)d_in[3];
    const float* W_in   = (const float*)d_in[4];
    const float* conv_w = (const float*)d_in[5];
    const float* conv_b = (const float*)d_in[6];
    const float* W_xp   = (const float*)d_in[7];
    const float* W_dt   = (const float*)d_in[8];
    const float* b_dt   = (const float*)d_in[9];
    const float* A_log  = (const float*)d_in[10];
    const float* Dv     = (const float*)d_in[11];
    const float* W_out  = (const float*)d_in[12];
    const float* normf_w= (const float*)d_in[13];
    const float* pe     = (const float*)d_in[14];

    float* ws = (float*)d_ws;
    const size_t SZ_X  = (size_t)MROWS * DMODEL;       // 1.62M
    const size_t SZ_XR = (size_t)MROWS * 2 * D_INNER;  // 6.48M
    const size_t SZ_U  = (size_t)MROWS * D_INNER;      // 3.24M
    const size_t SZ_XD = (size_t)MROWS * XD_LD;        // 0.1728M

    float* XS  = ws;                 // pre-norm activations (residual)
    float* XN  = XS  + SZ_X;         // rmsnorm output
    float* XR  = XN  + SZ_X;         // in-proj output (xm | res)
    float* XMC = XR  + SZ_XR;        // conv+silu fwd; dead after scan -> reused as YC
    float* XBC = XMC + SZ_U;         // conv+silu bwd; dead after scan -> reused as Z
    float* XDM = XBC + SZ_U;         // x-proj fwd (ld 96)
    float* XDB = XDM + SZ_XD;        // x-proj bwd
    float* DM  = XDB + SZ_XD;        // delta fwd; scan writes ym in-place
    float* DB  = DM  + SZ_U;         // delta bwd; scan writes yb in-place
    float* YC  = XMC;                // gate output   (XMC dead after scan)
    float* Z   = XBC;                // out-proj+res  (XBC dead after scan)

    dim3 blk(256);

    // 1) embedding GEMM + bias + *30 + pe  -> XS
    {
        dim3 g((DMODEL + BN - 1) / BN, (MROWS + BM - 1) / BM);
        hipLaunchKernelGGL(gemm_k, g, blk, 0, stream,
                           inp, 900, W_emb, 900, XS, DMODEL,
                           MROWS, DMODEL, 900, b_emb, pe, 0);
    }
    // 2) rmsnorm -> XN
    hipLaunchKernelGGL(rmsnorm_k, dim3(MROWS), blk, 0, stream, XS, norm_w, XN, DMODEL);
    // 3) in-proj GEMM -> XR (1800 x 3600)
    {
        dim3 g((2 * D_INNER + BN - 1) / BN, (MROWS + BM - 1) / BM);
        hipLaunchKernelGGL(gemm_k, g, blk, 0, stream,
                           XN, DMODEL, W_in, DMODEL, XR, 2 * D_INNER,
                           MROWS, 2 * D_INNER, DMODEL, (const float*)nullptr, (const float*)nullptr, 1);
    }
    // 4) causal dwconv + silu (fwd + channel-reversed) -> XMC, XBC
    {
        int tot = MROWS * D_INNER;
        hipLaunchKernelGGL(conv_silu_k, dim3((tot + 255) / 256), blk, 0, stream,
                           XR, conv_w, conv_b, XMC, XBC);
    }
    // 5) x-proj GEMMs -> XDM, XDB  (N=89, ld 96)
    {
        dim3 g((89 + BN - 1) / BN, (MROWS + BM - 1) / BM);
        hipLaunchKernelGGL(gemm_k, g, blk, 0, stream,
                           XMC, D_INNER, W_xp, D_INNER, XDM, XD_LD,
                           MROWS, 89, D_INNER, (const float*)nullptr, (const float*)nullptr, 1);
        hipLaunchKernelGGL(gemm_k, g, blk, 0, stream,
                           XBC, D_INNER, W_xp, D_INNER, XDB, XD_LD,
                           MROWS, 89, D_INNER, (const float*)nullptr, (const float*)nullptr, 1);
    }
    // 6) dt GEMMs + softplus -> DM, DB  (K=57 from the ld-96 buffer)
    {
        dim3 g((D_INNER + BN - 1) / BN, (MROWS + BM - 1) / BM);
        hipLaunchKernelGGL(gemm_k, g, blk, 0, stream,
                           XDM, XD_LD, W_dt, DT_RANK, DM, D_INNER,
                           MROWS, D_INNER, DT_RANK, b_dt, (const float*)nullptr, 3);
        hipLaunchKernelGGL(gemm_k, g, blk, 0, stream,
                           XDB, XD_LD, W_dt, DT_RANK, DB, D_INNER,
                           MROWS, D_INNER, DT_RANK, b_dt, (const float*)nullptr, 3);
    }
    // 7) selective scan (both dirs, both batches); writes YM->DM, YB->DB in-place
    {
        dim3 g((D_INNER + 255) / 256, NB, 2);
        hipLaunchKernelGGL(scan_k, g, blk, 0, stream,
                           DM, DB, XMC, XBC, XDM, XDB, A_log, Dv, DM, DB);
    }
    // 8) gating -> YC (=XMC; inputs DM,DB,XR all distinct)
    {
        int tot = MROWS * D_INNER;
        hipLaunchKernelGGL(gate_k, dim3((tot + 255) / 256), blk, 0, stream,
                           DM, DB, XR, YC);
    }
    // 9) out-proj GEMM + residual(XS) -> Z (=XBC; reads YC=XMC, disjoint)
    {
        dim3 g((DMODEL + BN - 1) / BN, (MROWS + BM - 1) / BM);
        hipLaunchKernelGGL(gemm_k, g, blk, 0, stream,
                           YC, D_INNER, W_out, D_INNER, Z, DMODEL,
                           MROWS, DMODEL, D_INNER, (const float*)nullptr, XS, 4);
    }
    // 10) final rmsnorm -> d_out
    hipLaunchKernelGGL(rmsnorm_k, dim3(MROWS), blk, 0, stream, Z, normf_w, (float*)d_out, DMODEL);
}

// Round 3
// 454.456 us; speedup vs baseline: 4.9509x; 4.9509x over previous
//
#include <hip/hip_runtime.h>
#include <math.h>

typedef unsigned short ushortT;
typedef short short8 __attribute__((ext_vector_type(8)));
typedef float f32x4 __attribute__((ext_vector_type(4)));

#define D_STATE 16
#define D_INNER 1800
#define DT_RANK 57
#define SEQ_L 900
#define MROWS 1800            // 2*900
#define MP 1920               // padded rows (15*128)
#define KP_DM 960             // K=900 -> pad
#define KP_DI 1856            // K=1800 -> pad
#define KP_DT 64              // K=57 -> pad
#define NCHUNK 30
#define CLEN 30

__device__ __forceinline__ ushortT f2bf(float f) {
    unsigned u = __float_as_uint(f);
    unsigned r = (u + 0x7FFFu + ((u >> 16) & 1u)) >> 16;
    return (ushortT)r;
}
__device__ __forceinline__ float bf2f(ushortT h) {
    return __uint_as_float((unsigned)h << 16);
}
__device__ __forceinline__ float silu_f(float x) { return x / (1.f + __expf(-x)); }

__device__ __forceinline__ void gload_lds16(const ushortT* g, ushortT* l) {
    __builtin_amdgcn_global_load_lds((const __attribute__((address_space(1))) unsigned int*)g,
                                     (__attribute__((address_space(3))) unsigned int*)l,
                                     16, 0, 0);
}

// ---------------- fp32 -> bf16 with zero padding ----------------
__global__ __launch_bounds__(256)
void cvt_pad_k(const float* __restrict__ src, int M, int K,
               ushortT* __restrict__ dst, int Mpad, int Kpad)
{
    int t = blockIdx.x * 256 + threadIdx.x;
    int K4 = Kpad >> 2;
    if (t >= Mpad * K4) return;
    int r = t / K4, c4 = (t - r * K4) * 4;
    ushortT o[4];
#pragma unroll
    for (int e = 0; e < 4; ++e) {
        int c = c4 + e;
        float v = (r < M && c < K) ? src[(size_t)r * K + c] : 0.f;
        o[e] = f2bf(v);
    }
    uint2 pk;
    pk.x = (unsigned)o[0] | ((unsigned)o[1] << 16);
    pk.y = (unsigned)o[2] | ((unsigned)o[3] << 16);
    *(uint2*)(dst + (size_t)r * Kpad + c4) = pk;
}

// ---------------- bf16 MFMA GEMM: C[m,n] = sum_k A[m,k] B[n,k] ----------------
// modes: 0 emb (+bias)*30+pe ; 1 plain->bf16 ; 2 f32(ldc,N) + bf16 aux(ldx,Nb) ; 3 softplus(+bias) ; 4 +add
__global__ __launch_bounds__(256)
void gemm_mfma_k(const ushortT* __restrict__ A0, const ushortT* __restrict__ A1, int lda,
                 const ushortT* __restrict__ Bw, int ldb, int nk,
                 float* __restrict__ C0, float* __restrict__ C1, int ldc, int N,
                 ushortT* __restrict__ X0, ushortT* __restrict__ X1, int ldx, int Nb,
                 int M,
                 const float* __restrict__ bias,
                 const float* __restrict__ add0, const float* __restrict__ add1, int ldadd,
                 int mode)
{
    __shared__ ushortT As[128 * 64];
    __shared__ ushortT Bs[128 * 64];
    int z = blockIdx.z;
    const ushortT* A = z ? A1 : A0;
    float* C = z ? C1 : C0;
    ushortT* Xo = z ? X1 : X0;
    const float* add = z ? add1 : add0;

    int tid = threadIdx.x;
    int lane = tid & 63, wave = tid >> 6;
    int wr = wave >> 1, wc = wave & 1;
    int m0 = blockIdx.y * 128, n0 = blockIdx.x * 128;

    f32x4 acc[4][4] = {};

    for (int kt = 0; kt < nk; ++kt) {
#pragma unroll
        for (int r = 0; r < 4; ++r) {
            int idx = r * 256 + tid;
            int row = idx >> 3, c8 = (idx & 7) << 3;
            gload_lds16(A + (size_t)(m0 + row) * lda + kt * 64 + c8, As + idx * 8);
        }
#pragma unroll
        for (int r = 0; r < 4; ++r) {
            int idx = r * 256 + tid;
            int row = idx >> 3, c8 = (idx & 7) << 3;
            gload_lds16(Bw + (size_t)(n0 + row) * ldb + kt * 64 + c8, Bs + idx * 8);
        }
        __syncthreads();
#pragma unroll
        for (int ks = 0; ks < 2; ++ks) {
            short8 av[4], bv[4];
            int kcol = ks * 32 + (lane >> 4) * 8;
#pragma unroll
            for (int i = 0; i < 4; ++i)
                av[i] = *(const short8*)(As + (wr * 64 + i * 16 + (lane & 15)) * 64 + kcol);
#pragma unroll
            for (int j = 0; j < 4; ++j)
                bv[j] = *(const short8*)(Bs + (wc * 64 + j * 16 + (lane & 15)) * 64 + kcol);
#pragma unroll
            for (int i = 0; i < 4; ++i)
#pragma unroll
                for (int j = 0; j < 4; ++j)
                    acc[i][j] = __builtin_amdgcn_mfma_f32_16x16x32_bf16(av[i], bv[j], acc[i][j], 0, 0, 0);
        }
        __syncthreads();
    }

#pragma unroll
    for (int i = 0; i < 4; ++i) {
        int rb = m0 + wr * 64 + i * 16 + (lane >> 4) * 4;
#pragma unroll
        for (int j = 0; j < 4; ++j) {
            int col = n0 + wc * 64 + j * 16 + (lane & 15);
#pragma unroll
            for (int rg = 0; rg < 4; ++rg) {
                int m = rb + rg;
                if (m >= M) continue;
                float v = acc[i][j][rg];
                if (C && col < N) {
                    float o = v;
                    if (bias) o += bias[col];
                    if (mode == 0) {
                        int l = (m >= SEQ_L) ? m - SEQ_L : m;
                        o = o * 30.0f + add[(size_t)l * ldadd + col];
                    } else if (mode == 3) {
                        o = (o > 20.f) ? o : log1pf(expf(o));
                    } else if (mode == 4) {
                        o = o + add[(size_t)m * ldadd + col];
                    }
                    C[(size_t)m * ldc + col] = o;
                }
                if (Xo && col < Nb) {
                    Xo[(size_t)m * ldx + col] = f2bf(v);
                }
            }
        }
    }
}

// ---------------- RMSNorm (one block per row); bf16 or f32 out ----------------
__global__ __launch_bounds__(256)
void rmsnorm_k(const float* __restrict__ x, const float* __restrict__ w,
               float* __restrict__ yf, ushortT* __restrict__ yb, int ldy, int ncols)
{
    int row = blockIdx.x;
    const float* xr = x + (size_t)row * ncols;
    float s = 0.f;
    for (int c = threadIdx.x; c < ncols; c += 256) { float v = xr[c]; s += v * v; }
#pragma unroll
    for (int off = 32; off; off >>= 1) s += __shfl_down(s, off, 64);
    __shared__ float red[4];
    int wv = threadIdx.x >> 6;
    if ((threadIdx.x & 63) == 0) red[wv] = s;
    __syncthreads();
    float tot = red[0] + red[1] + red[2] + red[3];
    float scale = rsqrtf(tot / (float)ncols + 1e-5f);
    for (int c = threadIdx.x; c < ncols; c += 256) {
        float v = xr[c] * scale * w[c];
        if (yb) yb[(size_t)row * ldy + c] = f2bf(v);
        else    yf[(size_t)row * ldy + c] = v;
    }
}

// ---------------- causal dwconv + silu (fwd + channel-reversed), bf16 in/out ----------------
__global__ __launch_bounds__(256)
void conv_silu_k(const ushortT* __restrict__ xr, const float* __restrict__ w,
                 const float* __restrict__ cb,
                 ushortT* __restrict__ xmc, ushortT* __restrict__ xbc)
{
    int idx = blockIdx.x * 256 + threadIdx.x;
    if (idx >= MROWS * D_INNER) return;
    int d = idx % D_INNER;
    int row = idx / D_INNER;
    int l = row % SEQ_L;
    float wv[4];
#pragma unroll
    for (int k = 0; k < 4; ++k) wv[k] = w[d * 4 + k];
    int rd = D_INNER - 1 - d;
    float sf = cb[d], sb = cb[d];
#pragma unroll
    for (int k = 0; k < 4; ++k) {
        int ll = l - 3 + k;
        if (ll < 0) continue;
        const ushortT* rp = xr + (size_t)(row - l + ll) * (2 * D_INNER);
        sf = fmaf(wv[k], bf2f(rp[d]), sf);
        sb = fmaf(wv[k], bf2f(rp[rd]), sb);
    }
    xmc[(size_t)row * KP_DI + d] = f2bf(silu_f(sf));
    xbc[(size_t)row * KP_DI + d] = f2bf(silu_f(sb));
}

// ---------------- chunked selective scan ----------------
// level 1: per (zz=b*2+dir, chunk, d): local scan h from 0; store h_end and sum(delta)
__global__ __launch_bounds__(256)
void scan_l1_k(const float* __restrict__ DM, const float* __restrict__ DB,
               const ushortT* __restrict__ Um, const ushortT* __restrict__ Ub,
               const float* __restrict__ XDm, const float* __restrict__ XDb,
               const float* __restrict__ A_log,
               float* __restrict__ HL, float* __restrict__ SD)
{
    int d = blockIdx.x * 256 + threadIdx.x;
    if (d >= D_INNER) return;
    int c = blockIdx.y, zz = blockIdx.z;
    int b = zz >> 1, dir = zz & 1;
    const float* DL = dir ? DB : DM;
    const ushortT* U = dir ? Ub : Um;
    const float* XD = dir ? XDb : XDm;
    float Aa[D_STATE];
#pragma unroll
    for (int n = 0; n < D_STATE; ++n) Aa[n] = -__expf(A_log[d * D_STATE + n]);
    float h[D_STATE] = {};
    float S = 0.f;
    int l0 = c * CLEN;
    for (int i = 0; i < CLEN; ++i) {
        size_t rowi = (size_t)b * SEQ_L + l0 + i;
        float delta = DL[rowi * D_INNER + d];
        float u = bf2f(U[rowi * KP_DI + d]);
        const float* bc = XD + rowi * 96 + DT_RANK;
        float du = delta * u;
        S += delta;
#pragma unroll
        for (int n = 0; n < D_STATE; ++n)
            h[n] = fmaf(__expf(delta * Aa[n]), h[n], du * bc[n]);
    }
    float* hp = HL + (((size_t)zz * NCHUNK + c) * D_INNER + d) * D_STATE;
#pragma unroll
    for (int n = 0; n < D_STATE; ++n) hp[n] = h[n];
    SD[((size_t)zz * NCHUNK + c) * D_INNER + d] = S;
}

// level 2: per (zz,d,n): sequentially combine chunks; replace HL[c] with incoming state h0 of chunk c
__global__ __launch_bounds__(256)
void scan_l2_k(float* __restrict__ HL, const float* __restrict__ SD,
               const float* __restrict__ A_log)
{
    int t = blockIdx.x * 256 + threadIdx.x;
    if (t >= 4 * D_INNER * D_STATE) return;
    int n = t & 15;
    int d = (t >> 4) % D_INNER;
    int zz = t / (D_INNER * D_STATE);
    float Aa = -__expf(A_log[d * D_STATE + n]);
    float h0 = 0.f;
    for (int c = 0; c < NCHUNK; ++c) {
        size_t ih = (((size_t)zz * NCHUNK + c) * D_INNER + d) * D_STATE + n;
        float hl = HL[ih];
        float T = __expf(Aa * SD[((size_t)zz * NCHUNK + c) * D_INNER + d]);
        HL[ih] = h0;
        h0 = fmaf(T, h0, hl);
    }
}

// level 3: re-scan with correct h0, write y in-place over delta buffer
__global__ __launch_bounds__(256)
void scan_l3_k(float* __restrict__ DM, float* __restrict__ DB,
               const ushortT* __restrict__ Um, const ushortT* __restrict__ Ub,
               const float* __restrict__ XDm, const float* __restrict__ XDb,
               const float* __restrict__ A_log, const float* __restrict__ Dv,
               const float* __restrict__ HL)
{
    int d = blockIdx.x * 256 + threadIdx.x;
    if (d >= D_INNER) return;
    int c = blockIdx.y, zz = blockIdx.z;
    int b = zz >> 1, dir = zz & 1;
    float* DL = dir ? DB : DM;
    const ushortT* U = dir ? Ub : Um;
    const float* XD = dir ? XDb : XDm;
    float Aa[D_STATE];
#pragma unroll
    for (int n = 0; n < D_STATE; ++n) Aa[n] = -__expf(A_log[d * D_STATE + n]);
    float Dd = Dv[d];
    float h[D_STATE];
    const float* hp = HL + (((size_t)zz * NCHUNK + c) * D_INNER + d) * D_STATE;
#pragma unroll
    for (int n = 0; n < D_STATE; ++n) h[n] = hp[n];
    int l0 = c * CLEN;
    for (int i = 0; i < CLEN; ++i) {
        size_t rowi = (size_t)b * SEQ_L + l0 + i;
        float delta = DL[rowi * D_INNER + d];
        float u = bf2f(U[rowi * KP_DI + d]);
        const float* bc = XD + rowi * 96 + DT_RANK;
        const float* cc = bc + D_STATE;
        float du = delta * u;
        float acc = u * Dd;
#pragma unroll
        for (int n = 0; n < D_STATE; ++n) {
            h[n] = fmaf(__expf(delta * Aa[n]), h[n], du * bc[n]);
            acc = fmaf(h[n], cc[n], acc);
        }
        DL[rowi * D_INNER + d] = acc;
    }
}

// ---------------- gating -> bf16 ----------------
__global__ __launch_bounds__(256)
void gate_k(const float* __restrict__ ym, const float* __restrict__ yb,
            const ushortT* __restrict__ xrb, ushortT* __restrict__ yc)
{
    int idx = blockIdx.x * 256 + threadIdx.x;
    if (idx >= MROWS * D_INNER) return;
    int d = idx % D_INNER;
    int row = idx / D_INNER;
    float g = silu_f(bf2f(xrb[(size_t)row * (2 * D_INNER) + D_INNER + d]));
    float v = ym[(size_t)row * D_INNER + d] + yb[(size_t)row * D_INNER + (D_INNER - 1 - d)];
    yc[(size_t)row * KP_DI + d] = f2bf(v * g);
}

extern "C" void kernel_launch(void* const* d_in, const int* in_sizes, int n_in,
                              void* d_out, int out_size, void* d_ws, size_t ws_size,
                              hipStream_t stream)
{
    const float* inp    = (const float*)d_in[0];
    const float* W_emb  = (const float*)d_in[1];
    const float* b_emb  = (const float*)d_in[2];
    const float* norm_w = (const float*)d_in[3];
    const float* W_in   = (const float*)d_in[4];
    const float* conv_w = (const float*)d_in[5];
    const float* conv_b = (const float*)d_in[6];
    const float* W_xp   = (const float*)d_in[7];
    const float* W_dt   = (const float*)d_in[8];
    const float* b_dt   = (const float*)d_in[9];
    const float* A_log  = (const float*)d_in[10];
    const float* Dv     = (const float*)d_in[11];
    const float* W_out  = (const float*)d_in[12];
    const float* normf_w= (const float*)d_in[13];
    const float* pe     = (const float*)d_in[14];

    char* base = (char*)d_ws;
    size_t off = 0;
    auto alloc = [&](size_t bytes) { char* p = base + off; off += (bytes + 255) & ~(size_t)255; return p; };

    float* XS    = (float*)alloc((size_t)MROWS * 900 * 4);
    float* XDMf  = (float*)alloc((size_t)MROWS * 96 * 4);
    float* XDBf  = (float*)alloc((size_t)MROWS * 96 * 4);
    float* DM    = (float*)alloc((size_t)MROWS * D_INNER * 4);
    float* DB    = (float*)alloc((size_t)MROWS * D_INNER * 4);
    float* HL    = (float*)alloc((size_t)4 * NCHUNK * D_INNER * D_STATE * 4);
    float* SD    = (float*)alloc((size_t)4 * NCHUNK * D_INNER * 4);
    ushortT* inp_bf  = (ushortT*)alloc((size_t)MP * KP_DM * 2);
    ushortT* XN_bf   = (ushortT*)alloc((size_t)MP * KP_DM * 2);
    ushortT* Wemb_bf = (ushortT*)alloc((size_t)1024 * KP_DM * 2);
    ushortT* Win_bf  = (ushortT*)alloc((size_t)3712 * KP_DM * 2);
    ushortT* Wxp_bf  = (ushortT*)alloc((size_t)128 * KP_DI * 2);
    ushortT* Wdt_bf  = (ushortT*)alloc((size_t)MP * KP_DT * 2);
    ushortT* Wout_bf = (ushortT*)alloc((size_t)1024 * KP_DI * 2);
    ushortT* XR_bf   = (ushortT*)alloc((size_t)MROWS * 3600 * 2);
    ushortT* XBC_bf  = (ushortT*)alloc((size_t)MP * KP_DI * 2);
    ushortT* XDM_bf  = (ushortT*)alloc((size_t)MP * KP_DT * 2);
    ushortT* XDB_bf  = (ushortT*)alloc((size_t)MP * KP_DT * 2);
    ushortT* XMC_bf  = Win_bf;    // alias: W_in dead after in-proj, conv runs later
    ushortT* YC_bf   = inp_bf;    // alias: inp/XN dead after in-proj; 1920*1856 fits in 2*1920*960
    float*   Z       = HL;        // alias: HL dead after scan_l3

    dim3 blk(256);
    auto cdiv = [](int a, int b) { return (a + b - 1) / b; };

    // conversions
    hipLaunchKernelGGL(cvt_pad_k, dim3(cdiv(MP * (KP_DM/4), 256)), blk, 0, stream, inp,   MROWS, 900,  inp_bf,  MP,   KP_DM);
    hipLaunchKernelGGL(cvt_pad_k, dim3(cdiv(1024 * (KP_DM/4), 256)), blk, 0, stream, W_emb, 900, 900,  Wemb_bf, 1024, KP_DM);
    hipLaunchKernelGGL(cvt_pad_k, dim3(cdiv(3712 * (KP_DM/4), 256)), blk, 0, stream, W_in, 3600, 900,  Win_bf,  3712, KP_DM);
    hipLaunchKernelGGL(cvt_pad_k, dim3(cdiv(128 * (KP_DI/4), 256)), blk, 0, stream, W_xp,  89, 1800,  Wxp_bf,  128,  KP_DI);
    hipLaunchKernelGGL(cvt_pad_k, dim3(cdiv(MP * (KP_DT/4), 256)), blk, 0, stream, W_dt, 1800, 57,    Wdt_bf,  MP,   KP_DT);
    hipLaunchKernelGGL(cvt_pad_k, dim3(cdiv(1024 * (KP_DI/4), 256)), blk, 0, stream, W_out, 900, 1800, Wout_bf, 1024, KP_DI);

    // 1) embedding: XS = (inp@W_emb^T + b)*30 + pe
    hipLaunchKernelGGL(gemm_mfma_k, dim3(8, 15, 1), blk, 0, stream,
                       inp_bf, inp_bf, KP_DM, Wemb_bf, KP_DM, KP_DM/64,
                       XS, XS, 900, 900, (ushortT*)nullptr, (ushortT*)nullptr, 0, 0,
                       MROWS, b_emb, pe, pe, 900, 0);
    // 2) rmsnorm -> XN_bf
    hipLaunchKernelGGL(rmsnorm_k, dim3(MROWS), blk, 0, stream, XS, norm_w, (float*)nullptr, XN_bf, KP_DM, 900);
    // 3) in-proj -> XR_bf (bf16)
    hipLaunchKernelGGL(gemm_mfma_k, dim3(29, 15, 1), blk, 0, stream,
                       XN_bf, XN_bf, KP_DM, Win_bf, KP_DM, KP_DM/64,
                       (float*)nullptr, (float*)nullptr, 0, 0, XR_bf, XR_bf, 3600, 3600,
                       MROWS, (const float*)nullptr, (const float*)nullptr, (const float*)nullptr, 0, 1);
    // 4) conv + silu -> XMC_bf, XBC_bf
    hipLaunchKernelGGL(conv_silu_k, dim3(cdiv(MROWS * D_INNER, 256)), blk, 0, stream,
                       XR_bf, conv_w, conv_b, XMC_bf, XBC_bf);
    // 5) x-proj (both dirs): XD f32 + bf16 dt-input
    hipLaunchKernelGGL(gemm_mfma_k, dim3(1, 15, 2), blk, 0, stream,
                       XMC_bf, XBC_bf, KP_DI, Wxp_bf, KP_DI, KP_DI/64,
                       XDMf, XDBf, 96, 89, XDM_bf, XDB_bf, KP_DT, DT_RANK,
                       MROWS, (const float*)nullptr, (const float*)nullptr, (const float*)nullptr, 0, 2);
    // 6) dt (both dirs): DM/DB = softplus(xd@W_dt^T + b_dt)
    hipLaunchKernelGGL(gemm_mfma_k, dim3(15, 15, 2), blk, 0, stream,
                       XDM_bf, XDB_bf, KP_DT, Wdt_bf, KP_DT, 1,
                       DM, DB, D_INNER, D_INNER, (ushortT*)nullptr, (ushortT*)nullptr, 0, 0,
                       MROWS, b_dt, (const float*)nullptr, (const float*)nullptr, 0, 3);
    // 7) chunked scan
    hipLaunchKernelGGL(scan_l1_k, dim3(cdiv(D_INNER, 256), NCHUNK, 4), blk, 0, stream,
                       DM, DB, XMC_bf, XBC_bf, XDMf, XDBf, A_log, HL, SD);
    hipLaunchKernelGGL(scan_l2_k, dim3(cdiv(4 * D_INNER * D_STATE, 256)), blk, 0, stream, HL, SD, A_log);
    hipLaunchKernelGGL(scan_l3_k, dim3(cdiv(D_INNER, 256), NCHUNK, 4), blk, 0, stream,
                       DM, DB, XMC_bf, XBC_bf, XDMf, XDBf, A_log, Dv, HL);
    // 8) gate -> YC_bf
    hipLaunchKernelGGL(gate_k, dim3(cdiv(MROWS * D_INNER, 256)), blk, 0, stream, DM, DB, XR_bf, YC_bf);
    // 9) out-proj + residual -> Z
    hipLaunchKernelGGL(gemm_mfma_k, dim3(8, 15, 1), blk, 0, stream,
                       YC_bf, YC_bf, KP_DI, Wout_bf, KP_DI, KP_DI/64,
                       Z, Z, 900, 900, (ushortT*)nullptr, (ushortT*)nullptr, 0, 0,
                       MROWS, (const float*)nullptr, XS, XS, 900, 4);
    // 10) final rmsnorm -> d_out
    hipLaunchKernelGGL(rmsnorm_k, dim3(MROWS), blk, 0, stream, Z, normf_w, (float*)d_out, (ushortT*)nullptr, 900, 900);
}

// Round 4
// 356.073 us; speedup vs baseline: 6.3188x; 1.2763x over previous
//
#include <hip/hip_runtime.h>
#include <math.h>

typedef unsigned short ushortT;
typedef short short8 __attribute__((ext_vector_type(8)));
typedef float f32x4 __attribute__((ext_vector_type(4)));

#define D_STATE 16
#define D_INNER 1800
#define DT_RANK 57
#define SEQ_L 900
#define MROWS 1800            // 2*900
#define MP 1920               // padded rows (15*128)
#define KP_DM 960             // K=900 -> pad
#define KP_DI 1856            // K=1800 -> pad
#define KP_DT 64              // K=57 -> pad
#define NCHUNK 30
#define CLEN 30

__device__ __forceinline__ ushortT f2bf(float f) {
    unsigned u = __float_as_uint(f);
    unsigned r = (u + 0x7FFFu + ((u >> 16) & 1u)) >> 16;
    return (ushortT)r;
}
__device__ __forceinline__ float bf2f(ushortT h) {
    return __uint_as_float((unsigned)h << 16);
}
__device__ __forceinline__ float silu_f(float x) { return x / (1.f + __expf(-x)); }

__device__ __forceinline__ void gload_lds16(const ushortT* g, ushortT* l) {
    __builtin_amdgcn_global_load_lds((const __attribute__((address_space(1))) unsigned int*)g,
                                     (__attribute__((address_space(3))) unsigned int*)l,
                                     16, 0, 0);
}

// ---------------- fp32 -> bf16 with zero padding ----------------
__global__ __launch_bounds__(256)
void cvt_pad_k(const float* __restrict__ src, int M, int K,
               ushortT* __restrict__ dst, int Mpad, int Kpad)
{
    int t = blockIdx.x * 256 + threadIdx.x;
    int K4 = Kpad >> 2;
    if (t >= Mpad * K4) return;
    int r = t / K4, c4 = (t - r * K4) * 4;
    ushortT o[4];
#pragma unroll
    for (int e = 0; e < 4; ++e) {
        int c = c4 + e;
        float v = (r < M && c < K) ? src[(size_t)r * K + c] : 0.f;
        o[e] = f2bf(v);
    }
    uint2 pk;
    pk.x = (unsigned)o[0] | ((unsigned)o[1] << 16);
    pk.y = (unsigned)o[2] | ((unsigned)o[3] << 16);
    *(uint2*)(dst + (size_t)r * Kpad + c4) = pk;
}

// ---------------- bf16 MFMA GEMM with K-split ----------------
// z decodes: dir = z/split, s = z%split. K-iters [kt0, kt0+kcnt) from nkTotal.
// mode 0: raw f32 partial -> C + s*cstride
// mode 1: raw bf16 partial -> Xo + s*xstride
// mode 3: softplus(acc + bias) f32 -> C (split must be 1)
__global__ __launch_bounds__(256)
void gemm_mfma_k(const ushortT* __restrict__ A0, const ushortT* __restrict__ A1, int lda,
                 const ushortT* __restrict__ Bw, int ldb, int nkTotal, int split,
                 float* __restrict__ C0, float* __restrict__ C1, int ldc, int N, size_t cstride,
                 ushortT* __restrict__ X0, ushortT* __restrict__ X1, int ldx, int Nb, size_t xstride,
                 int M, const float* __restrict__ bias, int mode)
{
    __shared__ ushortT As[128 * 64];
    __shared__ ushortT Bs[128 * 64];
    int z = blockIdx.z;
    int dir = z / split, s = z % split;
    int per = (nkTotal + split - 1) / split;
    int kt0 = s * per;
    int kcnt = nkTotal - kt0; if (kcnt > per) kcnt = per;

    const ushortT* A = dir ? A1 : A0;
    float* C = (dir ? C1 : C0);
    ushortT* Xo = (dir ? X1 : X0);
    if (C)  C  += (size_t)s * cstride;
    if (Xo) Xo += (size_t)s * xstride;

    int tid = threadIdx.x;
    int lane = tid & 63, wave = tid >> 6;
    int wr = wave >> 1, wc = wave & 1;
    int m0 = blockIdx.y * 128, n0 = blockIdx.x * 128;

    f32x4 acc[4][4] = {};

    for (int kt = kt0; kt < kt0 + kcnt; ++kt) {
#pragma unroll
        for (int r = 0; r < 4; ++r) {
            int idx = r * 256 + tid;
            int row = idx >> 3, c8 = (idx & 7) << 3;
            gload_lds16(A + (size_t)(m0 + row) * lda + kt * 64 + c8, As + idx * 8);
        }
#pragma unroll
        for (int r = 0; r < 4; ++r) {
            int idx = r * 256 + tid;
            int row = idx >> 3, c8 = (idx & 7) << 3;
            gload_lds16(Bw + (size_t)(n0 + row) * ldb + kt * 64 + c8, Bs + idx * 8);
        }
        __syncthreads();
#pragma unroll
        for (int ks = 0; ks < 2; ++ks) {
            short8 av[4], bv[4];
            int kcol = ks * 32 + (lane >> 4) * 8;
#pragma unroll
            for (int i = 0; i < 4; ++i)
                av[i] = *(const short8*)(As + (wr * 64 + i * 16 + (lane & 15)) * 64 + kcol);
#pragma unroll
            for (int j = 0; j < 4; ++j)
                bv[j] = *(const short8*)(Bs + (wc * 64 + j * 16 + (lane & 15)) * 64 + kcol);
#pragma unroll
            for (int i = 0; i < 4; ++i)
#pragma unroll
                for (int j = 0; j < 4; ++j)
                    acc[i][j] = __builtin_amdgcn_mfma_f32_16x16x32_bf16(av[i], bv[j], acc[i][j], 0, 0, 0);
        }
        __syncthreads();
    }

#pragma unroll
    for (int i = 0; i < 4; ++i) {
        int rb = m0 + wr * 64 + i * 16 + (lane >> 4) * 4;
#pragma unroll
        for (int j = 0; j < 4; ++j) {
            int col = n0 + wc * 64 + j * 16 + (lane & 15);
#pragma unroll
            for (int rg = 0; rg < 4; ++rg) {
                int m = rb + rg;
                if (m >= M) continue;
                float v = acc[i][j][rg];
                if (mode == 1) {
                    if (col < Nb) Xo[(size_t)m * ldx + col] = f2bf(v);
                } else {
                    if (col < N) {
                        if (mode == 3) {
                            v += bias[col];
                            v = (v > 20.f) ? v : log1pf(expf(v));
                        }
                        C[(size_t)m * ldc + col] = v;
                    }
                }
            }
        }
    }
}

// ---------------- emb epilogue + rmsnorm: sums 4 partials, v=30*(acc+b)+pe ----------------
__global__ __launch_bounds__(256)
void rmsnorm_emb_k(const float* __restrict__ P, size_t pstride,
                   const float* __restrict__ b_emb, const float* __restrict__ pe,
                   const float* __restrict__ norm_w,
                   float* __restrict__ XS, ushortT* __restrict__ XN, int ldxn)
{
    int row = blockIdx.x;
    int l = (row >= SEQ_L) ? row - SEQ_L : row;
    float vv[4];
    float ssum = 0.f;
#pragma unroll
    for (int k = 0; k < 4; ++k) {
        int c = threadIdx.x + k * 256;
        if (c < 900) {
            size_t i = (size_t)row * 900 + c;
            float a = P[i] + P[i + pstride] + P[i + 2 * pstride] + P[i + 3 * pstride];
            float v = 30.f * (a + b_emb[c]) + pe[(size_t)l * 900 + c];
            vv[k] = v;
            ssum += v * v;
        } else vv[k] = 0.f;
    }
#pragma unroll
    for (int off = 32; off; off >>= 1) ssum += __shfl_down(ssum, off, 64);
    __shared__ float red[4];
    int wv = threadIdx.x >> 6;
    if ((threadIdx.x & 63) == 0) red[wv] = ssum;
    __syncthreads();
    float tot = red[0] + red[1] + red[2] + red[3];
    float scale = rsqrtf(tot / 900.f + 1e-5f);
#pragma unroll
    for (int k = 0; k < 4; ++k) {
        int c = threadIdx.x + k * 256;
        if (c < 900) {
            XS[(size_t)row * 900 + c] = vv[k];
            XN[(size_t)row * ldxn + c] = f2bf(vv[k] * scale * norm_w[c]);
        }
    }
}

// ---------------- final: sums 4 out-proj partials + residual, rmsnorm -> out ----------------
__global__ __launch_bounds__(256)
void rmsnorm_final_k(const float* __restrict__ ZP, size_t zstride,
                     const float* __restrict__ XS, const float* __restrict__ w,
                     float* __restrict__ out)
{
    int row = blockIdx.x;
    float vv[4];
    float ssum = 0.f;
#pragma unroll
    for (int k = 0; k < 4; ++k) {
        int c = threadIdx.x + k * 256;
        if (c < 900) {
            size_t i = (size_t)row * 900 + c;
            float v = ZP[i] + ZP[i + zstride] + ZP[i + 2 * zstride] + ZP[i + 3 * zstride] + XS[i];
            vv[k] = v;
            ssum += v * v;
        } else vv[k] = 0.f;
    }
#pragma unroll
    for (int off = 32; off; off >>= 1) ssum += __shfl_down(ssum, off, 64);
    __shared__ float red[4];
    int wv = threadIdx.x >> 6;
    if ((threadIdx.x & 63) == 0) red[wv] = ssum;
    __syncthreads();
    float tot = red[0] + red[1] + red[2] + red[3];
    float scale = rsqrtf(tot / 900.f + 1e-5f);
#pragma unroll
    for (int k = 0; k < 4; ++k) {
        int c = threadIdx.x + k * 256;
        if (c < 900) out[(size_t)row * 900 + c] = vv[k] * scale * w[c];
    }
}

// ---------------- conv: sums 2 in-proj partials, dwconv+silu both dirs, + G=silu(res) ----------------
__global__ __launch_bounds__(256)
void conv_silu_k(const ushortT* __restrict__ xr0, const ushortT* __restrict__ xr1,
                 const float* __restrict__ w, const float* __restrict__ cb,
                 ushortT* __restrict__ xmc, ushortT* __restrict__ xbc,
                 ushortT* __restrict__ gout)
{
    int idx = blockIdx.x * 256 + threadIdx.x;
    if (idx >= MROWS * D_INNER) return;
    int d = idx % D_INNER;
    int row = idx / D_INNER;
    int l = row % SEQ_L;
    float wv[4];
#pragma unroll
    for (int k = 0; k < 4; ++k) wv[k] = w[d * 4 + k];
    int rd = D_INNER - 1 - d;
    float sf = cb[d], sb = cb[d];
#pragma unroll
    for (int k = 0; k < 4; ++k) {
        int ll = l - 3 + k;
        if (ll < 0) continue;
        size_t ro = (size_t)(row - l + ll) * 3600;
        sf = fmaf(wv[k], bf2f(xr0[ro + d]) + bf2f(xr1[ro + d]), sf);
        sb = fmaf(wv[k], bf2f(xr0[ro + rd]) + bf2f(xr1[ro + rd]), sb);
    }
    xmc[(size_t)row * KP_DI + d] = f2bf(silu_f(sf));
    xbc[(size_t)row * KP_DI + d] = f2bf(silu_f(sb));
    size_t rro = (size_t)row * 3600 + D_INNER + d;
    gout[(size_t)row * D_INNER + d] = f2bf(silu_f(bf2f(xr0[rro]) + bf2f(xr1[rro])));
}

// ---------------- xp reduce: sum 8 partials -> XD f32 + bf16 dt-input ----------------
__global__ __launch_bounds__(256)
void xp_reduce_k(const float* __restrict__ XPp, size_t pstride,
                 float* __restrict__ XDMf, float* __restrict__ XDBf,
                 ushortT* __restrict__ XDMb, ushortT* __restrict__ XDBb)
{
    int t = blockIdx.x * 256 + threadIdx.x;
    if (t >= 2 * MROWS * 96) return;
    int dir = t / (MROWS * 96);
    int rem = t - dir * (MROWS * 96);
    int row = rem / 96, c = rem - row * 96;
    const float* base = XPp + (size_t)dir * 8 * pstride + (size_t)row * 96 + c;
    float s = 0.f;
#pragma unroll
    for (int p = 0; p < 8; ++p) s += base[p * pstride];
    (dir ? XDBf : XDMf)[(size_t)row * 96 + c] = s;
    if (c < KP_DT) {
        ushortT o = (c < DT_RANK) ? f2bf(s) : (ushortT)0;
        (dir ? XDBb : XDMb)[(size_t)row * KP_DT + c] = o;
    }
}

// ---------------- chunked selective scan ----------------
__global__ __launch_bounds__(256)
void scan_l1_k(const float* __restrict__ DM, const float* __restrict__ DB,
               const ushortT* __restrict__ Um, const ushortT* __restrict__ Ub,
               const float* __restrict__ XDm, const float* __restrict__ XDb,
               const float* __restrict__ A_log,
               float* __restrict__ HL, float* __restrict__ SD)
{
    int d = blockIdx.x * 256 + threadIdx.x;
    if (d >= D_INNER) return;
    int c = blockIdx.y, zz = blockIdx.z;
    int b = zz >> 1, dir = zz & 1;
    const float* DL = dir ? DB : DM;
    const ushortT* U = dir ? Ub : Um;
    const float* XD = dir ? XDb : XDm;
    float Aa[D_STATE];
#pragma unroll
    for (int n = 0; n < D_STATE; ++n) Aa[n] = -__expf(A_log[d * D_STATE + n]);
    float h[D_STATE] = {};
    float S = 0.f;
    int l0 = c * CLEN;
    for (int i = 0; i < CLEN; ++i) {
        size_t rowi = (size_t)b * SEQ_L + l0 + i;
        float delta = DL[rowi * D_INNER + d];
        float u = bf2f(U[rowi * KP_DI + d]);
        const float* bc = XD + rowi * 96 + DT_RANK;
        float du = delta * u;
        S += delta;
#pragma unroll
        for (int n = 0; n < D_STATE; ++n)
            h[n] = fmaf(__expf(delta * Aa[n]), h[n], du * bc[n]);
    }
    float* hp = HL + (((size_t)zz * NCHUNK + c) * D_INNER + d) * D_STATE;
#pragma unroll
    for (int n = 0; n < D_STATE; ++n) hp[n] = h[n];
    SD[((size_t)zz * NCHUNK + c) * D_INNER + d] = S;
}

__global__ __launch_bounds__(256)
void scan_l2_k(float* __restrict__ HL, const float* __restrict__ SD,
               const float* __restrict__ A_log)
{
    int t = blockIdx.x * 256 + threadIdx.x;
    if (t >= 4 * D_INNER * D_STATE) return;
    int n = t & 15;
    int d = (t >> 4) % D_INNER;
    int zz = t / (D_INNER * D_STATE);
    float Aa = -__expf(A_log[d * D_STATE + n]);
    float h0 = 0.f;
    for (int c = 0; c < NCHUNK; ++c) {
        size_t ih = (((size_t)zz * NCHUNK + c) * D_INNER + d) * D_STATE + n;
        float hl = HL[ih];
        float T = __expf(Aa * SD[((size_t)zz * NCHUNK + c) * D_INNER + d]);
        HL[ih] = h0;
        h0 = fmaf(T, h0, hl);
    }
}

__global__ __launch_bounds__(256)
void scan_l3_k(float* __restrict__ DM, float* __restrict__ DB,
               const ushortT* __restrict__ Um, const ushortT* __restrict__ Ub,
               const float* __restrict__ XDm, const float* __restrict__ XDb,
               const float* __restrict__ A_log, const float* __restrict__ Dv,
               const float* __restrict__ HL)
{
    int d = blockIdx.x * 256 + threadIdx.x;
    if (d >= D_INNER) return;
    int c = blockIdx.y, zz = blockIdx.z;
    int b = zz >> 1, dir = zz & 1;
    float* DL = dir ? DB : DM;
    const ushortT* U = dir ? Ub : Um;
    const float* XD = dir ? XDb : XDm;
    float Aa[D_STATE];
#pragma unroll
    for (int n = 0; n < D_STATE; ++n) Aa[n] = -__expf(A_log[d * D_STATE + n]);
    float Dd = Dv[d];
    float h[D_STATE];
    const float* hp = HL + (((size_t)zz * NCHUNK + c) * D_INNER + d) * D_STATE;
#pragma unroll
    for (int n = 0; n < D_STATE; ++n) h[n] = hp[n];
    int l0 = c * CLEN;
    for (int i = 0; i < CLEN; ++i) {
        size_t rowi = (size_t)b * SEQ_L + l0 + i;
        float delta = DL[rowi * D_INNER + d];
        float u = bf2f(U[rowi * KP_DI + d]);
        const float* bc = XD + rowi * 96 + DT_RANK;
        const float* cc = bc + D_STATE;
        float du = delta * u;
        float acc = u * Dd;
#pragma unroll
        for (int n = 0; n < D_STATE; ++n) {
            h[n] = fmaf(__expf(delta * Aa[n]), h[n], du * bc[n]);
            acc = fmaf(h[n], cc[n], acc);
        }
        DL[rowi * D_INNER + d] = acc;
    }
}

// ---------------- gating: yc = (ym + yb[rev]) * G ----------------
__global__ __launch_bounds__(256)
void gate_k(const float* __restrict__ ym, const float* __restrict__ yb,
            const ushortT* __restrict__ gin, ushortT* __restrict__ yc)
{
    int idx = blockIdx.x * 256 + threadIdx.x;
    if (idx >= MROWS * D_INNER) return;
    int d = idx % D_INNER;
    int row = idx / D_INNER;
    float g = bf2f(gin[(size_t)row * D_INNER + d]);
    float v = ym[(size_t)row * D_INNER + d] + yb[(size_t)row * D_INNER + (D_INNER - 1 - d)];
    yc[(size_t)row * KP_DI + d] = f2bf(v * g);
}

extern "C" void kernel_launch(void* const* d_in, const int* in_sizes, int n_in,
                              void* d_out, int out_size, void* d_ws, size_t ws_size,
                              hipStream_t stream)
{
    const float* inp    = (const float*)d_in[0];
    const float* W_emb  = (const float*)d_in[1];
    const float* b_emb  = (const float*)d_in[2];
    const float* norm_w = (const float*)d_in[3];
    const float* W_in   = (const float*)d_in[4];
    const float* conv_w = (const float*)d_in[5];
    const float* conv_b = (const float*)d_in[6];
    const float* W_xp   = (const float*)d_in[7];
    const float* W_dt   = (const float*)d_in[8];
    const float* b_dt   = (const float*)d_in[9];
    const float* A_log  = (const float*)d_in[10];
    const float* Dv     = (const float*)d_in[11];
    const float* W_out  = (const float*)d_in[12];
    const float* normf_w= (const float*)d_in[13];
    const float* pe     = (const float*)d_in[14];

    char* base = (char*)d_ws;
    size_t off = 0;
    auto alloc = [&](size_t bytes) { char* p = base + off; off += (bytes + 255) & ~(size_t)255; return p; };

    float* XS = (float*)alloc((size_t)MROWS * 900 * 4);               // residual, lives to the end

    // time-phased arena 1: XPp (11.06M) -> HL+SD (14.69M) -> Wout_bf (3.80M)
    char* arena = alloc(14688000);
    float*   XPp     = (float*)arena;                 // 16 x 1800 x 96 f32
    float*   HL      = (float*)arena;                 // 4 x 30 x 1800 x 16 f32
    float*   SD      = (float*)(arena + 13824000);    // 4 x 30 x 1800 f32
    ushortT* Wout_bf = (ushortT*)arena;               // 1024 x 1856 bf16

    ushortT* inp_bf  = (ushortT*)alloc((size_t)MP * KP_DM * 2);
    ushortT* XN_bf   = (ushortT*)alloc((size_t)MP * KP_DM * 2);
    ushortT* Wemb_bf = (ushortT*)alloc((size_t)1024 * KP_DM * 2);
    ushortT* Win_bf  = (ushortT*)alloc((size_t)3712 * KP_DM * 2);     // -> XMC_bf after in-proj
    ushortT* Wxp_bf  = (ushortT*)alloc((size_t)128 * KP_DI * 2);
    ushortT* Wdt_bf  = (ushortT*)alloc((size_t)MP * KP_DT * 2);
    ushortT* XBC_bf  = (ushortT*)alloc((size_t)MP * KP_DI * 2);
    float*   XDMf    = (float*)alloc((size_t)MROWS * 96 * 4);
    float*   XDBf    = (float*)alloc((size_t)MROWS * 96 * 4);
    ushortT* XDM_bf  = (ushortT*)alloc((size_t)MP * KP_DT * 2);
    ushortT* XDB_bf  = (ushortT*)alloc((size_t)MP * KP_DT * 2);

    // time-phased arena 2 (25.92M): Pemb(4) -> XR0/XR1 -> DM/DB -> ZP(4)
    char* arena2 = alloc((size_t)2 * MROWS * D_INNER * 4);
    float*   Pemb = (float*)arena2;                   // stride 1620000
    ushortT* XR0  = (ushortT*)arena2;                 // 1800 x 3600 bf16
    ushortT* XR1  = XR0 + (size_t)MROWS * 3600;
    float*   DM   = (float*)arena2;
    float*   DB   = DM + (size_t)MROWS * D_INNER;
    float*   ZP   = (float*)arena2;                   // stride 1620000

    ushortT* G_bf  = (ushortT*)alloc((size_t)MROWS * D_INNER * 2);
    ushortT* XMC_bf = Win_bf;                         // 1920*1856*2 == 3712*960*2
    ushortT* YC_bf  = inp_bf;                         // inp_bf+XN_bf contiguous: 7.37M >= 7.13M

    dim3 blk(256);
    auto cdiv = [](int a, int b) { return (a + b - 1) / b; };
    const size_t PSTR = (size_t)MROWS * 900;          // 1620000
    const size_t XPSTR = (size_t)MROWS * 96;          // 172800

    // conversions
    hipLaunchKernelGGL(cvt_pad_k, dim3(cdiv(MP * (KP_DM/4), 256)), blk, 0, stream, inp,   MROWS, 900,  inp_bf,  MP,   KP_DM);
    hipLaunchKernelGGL(cvt_pad_k, dim3(cdiv(1024 * (KP_DM/4), 256)), blk, 0, stream, W_emb, 900, 900,  Wemb_bf, 1024, KP_DM);
    hipLaunchKernelGGL(cvt_pad_k, dim3(cdiv(3712 * (KP_DM/4), 256)), blk, 0, stream, W_in, 3600, 900,  Win_bf,  3712, KP_DM);
    hipLaunchKernelGGL(cvt_pad_k, dim3(cdiv(128 * (KP_DI/4), 256)), blk, 0, stream, W_xp,  89, 1800,  Wxp_bf,  128,  KP_DI);
    hipLaunchKernelGGL(cvt_pad_k, dim3(cdiv(MP * (KP_DT/4), 256)), blk, 0, stream, W_dt, 1800, 57,    Wdt_bf,  MP,   KP_DT);

    // 1) embedding GEMM split-4 -> Pemb
    hipLaunchKernelGGL(gemm_mfma_k, dim3(8, 15, 4), blk, 0, stream,
                       inp_bf, inp_bf, KP_DM, Wemb_bf, KP_DM, KP_DM/64, 4,
                       Pemb, Pemb, 900, 900, PSTR,
                       (ushortT*)nullptr, (ushortT*)nullptr, 0, 0, (size_t)0,
                       MROWS, (const float*)nullptr, 0);
    // 2) emb epilogue + rmsnorm -> XS, XN_bf
    hipLaunchKernelGGL(rmsnorm_emb_k, dim3(MROWS), blk, 0, stream,
                       Pemb, PSTR, b_emb, pe, norm_w, XS, XN_bf, KP_DM);
    // 3) in-proj GEMM split-2 -> XR0/XR1 (bf16 partials)
    hipLaunchKernelGGL(gemm_mfma_k, dim3(29, 15, 2), blk, 0, stream,
                       XN_bf, XN_bf, KP_DM, Win_bf, KP_DM, KP_DM/64, 2,
                       (float*)nullptr, (float*)nullptr, 0, 0, (size_t)0,
                       XR0, XR0, 3600, 3600, (size_t)MROWS * 3600,
                       MROWS, (const float*)nullptr, 1);
    // 4) conv + silu (sums partials) -> XMC, XBC, G
    hipLaunchKernelGGL(conv_silu_k, dim3(cdiv(MROWS * D_INNER, 256)), blk, 0, stream,
                       XR0, XR1, conv_w, conv_b, XMC_bf, XBC_bf, G_bf);
    // 5) x-proj GEMM split-8 both dirs -> XPp
    hipLaunchKernelGGL(gemm_mfma_k, dim3(1, 15, 16), blk, 0, stream,
                       XMC_bf, XBC_bf, KP_DI, Wxp_bf, KP_DI, KP_DI/64, 8,
                       XPp, XPp + 8 * XPSTR, 96, 96, XPSTR,
                       (ushortT*)nullptr, (ushortT*)nullptr, 0, 0, (size_t)0,
                       MROWS, (const float*)nullptr, 0);
    // 5b) xp reduce -> XDMf/XDBf + XDM_bf/XDB_bf
    hipLaunchKernelGGL(xp_reduce_k, dim3(cdiv(2 * MROWS * 96, 256)), blk, 0, stream,
                       XPp, XPSTR, XDMf, XDBf, XDM_bf, XDB_bf);
    // 6) dt GEMM both dirs + softplus -> DM, DB
    hipLaunchKernelGGL(gemm_mfma_k, dim3(15, 15, 2), blk, 0, stream,
                       XDM_bf, XDB_bf, KP_DT, Wdt_bf, KP_DT, 1, 1,
                       DM, DB, D_INNER, D_INNER, (size_t)0,
                       (ushortT*)nullptr, (ushortT*)nullptr, 0, 0, (size_t)0,
                       MROWS, b_dt, 3);
    // 7) chunked scan
    hipLaunchKernelGGL(scan_l1_k, dim3(cdiv(D_INNER, 256), NCHUNK, 4), blk, 0, stream,
                       DM, DB, XMC_bf, XBC_bf, XDMf, XDBf, A_log, HL, SD);
    hipLaunchKernelGGL(scan_l2_k, dim3(cdiv(4 * D_INNER * D_STATE, 256)), blk, 0, stream, HL, SD, A_log);
    hipLaunchKernelGGL(scan_l3_k, dim3(cdiv(D_INNER, 256), NCHUNK, 4), blk, 0, stream,
                       DM, DB, XMC_bf, XBC_bf, XDMf, XDBf, A_log, Dv, HL);
    // 8) gate -> YC_bf
    hipLaunchKernelGGL(gate_k, dim3(cdiv(MROWS * D_INNER, 256)), blk, 0, stream, DM, DB, G_bf, YC_bf);
    // 8b) convert W_out (arena free now)
    hipLaunchKernelGGL(cvt_pad_k, dim3(cdiv(1024 * (KP_DI/4), 256)), blk, 0, stream, W_out, 900, 1800, Wout_bf, 1024, KP_DI);
    // 9) out-proj GEMM split-4 -> ZP
    hipLaunchKernelGGL(gemm_mfma_k, dim3(8, 15, 4), blk, 0, stream,
                       YC_bf, YC_bf, KP_DI, Wout_bf, KP_DI, KP_DI/64, 4,
                       ZP, ZP, 900, 900, PSTR,
                       (ushortT*)nullptr, (ushortT*)nullptr, 0, 0, (size_t)0,
                       MROWS, (const float*)nullptr, 0);
    // 10) final reduce + residual + rmsnorm -> d_out
    hipLaunchKernelGGL(rmsnorm_final_k, dim3(MROWS), blk, 0, stream,
                       ZP, PSTR, XS, normf_w, (float*)d_out);
}

// Round 5
// 328.458 us; speedup vs baseline: 6.8501x; 1.0841x over previous
//
#include <hip/hip_runtime.h>
#include <math.h>

typedef unsigned short ushortT;
typedef short short8 __attribute__((ext_vector_type(8)));
typedef float f32x4 __attribute__((ext_vector_type(4)));

#define D_STATE 16
#define D_INNER 1800
#define DT_RANK 57
#define SEQ_L 900
#define MROWS 1800            // 2*900
#define MP 1920               // padded rows
#define KP_DM 960             // K=900 pad
#define KP_DI 1856            // K=1800 pad
#define KP_DT 64              // K=57 pad
#define NCHUNK 45
#define CLEN 20

__device__ __forceinline__ ushortT f2bf(float f) {
    unsigned u = __float_as_uint(f);
    unsigned r = (u + 0x7FFFu + ((u >> 16) & 1u)) >> 16;
    return (ushortT)r;
}
__device__ __forceinline__ float bf2f(ushortT h) {
    return __uint_as_float((unsigned)h << 16);
}
__device__ __forceinline__ float silu_f(float x) { return x / (1.f + __expf(-x)); }

__device__ __forceinline__ void gload_lds16(const ushortT* g, ushortT* l) {
    __builtin_amdgcn_global_load_lds((const __attribute__((address_space(1))) unsigned int*)g,
                                     (__attribute__((address_space(3))) unsigned int*)l,
                                     16, 0, 0);
}

// ---------------- all fp32->bf16 pad conversions in ONE kernel ----------------
__global__ __launch_bounds__(256)
void cvt_all_k(const float* __restrict__ s0, ushortT* __restrict__ d0,   // inp 1800x900
               const float* __restrict__ s1, ushortT* __restrict__ d1,   // W_emb 900x900
               const float* __restrict__ s2, ushortT* __restrict__ d2,   // W_in 3600x900
               const float* __restrict__ s3, ushortT* __restrict__ d3,   // W_xp 89x1800
               const float* __restrict__ s4, ushortT* __restrict__ d4,   // W_dt 1800x57
               const float* __restrict__ s5, ushortT* __restrict__ d5)   // W_out 900x1800
{
    const float* src; ushortT* dst; int M, K, Mp, Kp;
    switch (blockIdx.y) {
      case 0: src=s0; dst=d0; M=1800; K=900;  Mp=1920; Kp=960;  break;
      case 1: src=s1; dst=d1; M=900;  K=900;  Mp=1024; Kp=960;  break;
      case 2: src=s2; dst=d2; M=3600; K=900;  Mp=3712; Kp=960;  break;
      case 3: src=s3; dst=d3; M=89;   K=1800; Mp=128;  Kp=1856; break;
      case 4: src=s4; dst=d4; M=1800; K=57;   Mp=1920; Kp=64;   break;
      default:src=s5; dst=d5; M=900;  K=1800; Mp=1024; Kp=1856; break;
    }
    int t = blockIdx.x * 256 + threadIdx.x;
    int K4 = Kp >> 2;
    if (t >= Mp * K4) return;
    int r = t / K4, c4 = (t - r * K4) * 4;
    ushortT o[4];
#pragma unroll
    for (int e = 0; e < 4; ++e) {
        int c = c4 + e;
        float v = (r < M && c < K) ? src[(size_t)r * K + c] : 0.f;
        o[e] = f2bf(v);
    }
    uint2 pk;
    pk.x = (unsigned)o[0] | ((unsigned)o[1] << 16);
    pk.y = (unsigned)o[2] | ((unsigned)o[3] << 16);
    *(uint2*)(dst + (size_t)r * Kp + c4) = pk;
}

// ---------------- bf16 MFMA GEMM, swapped-operand epilogue, K-split ----------------
// z: dir = z/split, s = z%split.
// mode 0: raw f32 -> C (+s*cstride), dwordx4
// mode 1: raw bf16 -> Xo (+s*xstride), cvt_pk + dwordx2
// mode 3: softplus(acc+bias) f32 -> C
__global__ __launch_bounds__(256)
void gemm_mfma_k(const ushortT* __restrict__ A0, const ushortT* __restrict__ A1, int lda,
                 const ushortT* __restrict__ Bw, int ldb, int nkTotal, int split,
                 float* __restrict__ C0, float* __restrict__ C1, int ldc, size_t cstride,
                 ushortT* __restrict__ X0, ushortT* __restrict__ X1, int ldx, size_t xstride,
                 int M, int N, const float* __restrict__ bias, int mode)
{
    __shared__ ushortT As[128 * 64];
    __shared__ ushortT Bs[128 * 64];
    int z = blockIdx.z;
    int dir = z / split, s = z % split;
    int per = (nkTotal + split - 1) / split;
    int kt0 = s * per;
    int kcnt = nkTotal - kt0; if (kcnt > per) kcnt = per;

    const ushortT* A = dir ? A1 : A0;
    float* C = (dir ? C1 : C0);
    ushortT* Xo = (dir ? X1 : X0);
    if (C)  C  += (size_t)s * cstride;
    if (Xo) Xo += (size_t)s * xstride;

    int tid = threadIdx.x;
    int lane = tid & 63, wave = tid >> 6;
    int wr = wave >> 1, wc = wave & 1;
    int m0 = blockIdx.y * 128, n0 = blockIdx.x * 128;

    f32x4 acc[4][4] = {};

    for (int kt = kt0; kt < kt0 + kcnt; ++kt) {
#pragma unroll
        for (int r = 0; r < 4; ++r) {
            int idx = r * 256 + tid;
            int row = idx >> 3, c8 = (idx & 7) << 3;
            gload_lds16(A + (size_t)(m0 + row) * lda + kt * 64 + c8, As + idx * 8);
        }
#pragma unroll
        for (int r = 0; r < 4; ++r) {
            int idx = r * 256 + tid;
            int row = idx >> 3, c8 = (idx & 7) << 3;
            gload_lds16(Bw + (size_t)(n0 + row) * ldb + kt * 64 + c8, Bs + idx * 8);
        }
        __syncthreads();
#pragma unroll
        for (int ks = 0; ks < 2; ++ks) {
            short8 av[4], bv[4];
            int kcol = ks * 32 + (lane >> 4) * 8;
#pragma unroll
            for (int i = 0; i < 4; ++i)
                av[i] = *(const short8*)(As + (wr * 64 + i * 16 + (lane & 15)) * 64 + kcol);
#pragma unroll
            for (int j = 0; j < 4; ++j)
                bv[j] = *(const short8*)(Bs + (wc * 64 + j * 16 + (lane & 15)) * 64 + kcol);
            // swapped operands: output reg-axis = N (4 consecutive cols per lane)
#pragma unroll
            for (int i = 0; i < 4; ++i)
#pragma unroll
                for (int j = 0; j < 4; ++j)
                    acc[i][j] = __builtin_amdgcn_mfma_f32_16x16x32_bf16(bv[j], av[i], acc[i][j], 0, 0, 0);
        }
        __syncthreads();
    }

#pragma unroll
    for (int i = 0; i < 4; ++i) {
        int m = m0 + wr * 64 + i * 16 + (lane & 15);
        if (m >= M) continue;
#pragma unroll
        for (int j = 0; j < 4; ++j) {
            int nb = n0 + wc * 64 + j * 16 + (lane >> 4) * 4;
            if (nb >= N) continue;     // N and nb are multiples of 4
            f32x4 v = acc[i][j];
            if (mode == 1) {
                unsigned lo, hi;
                asm("v_cvt_pk_bf16_f32 %0, %1, %2" : "=v"(lo) : "v"(v[0]), "v"(v[1]));
                asm("v_cvt_pk_bf16_f32 %0, %1, %2" : "=v"(hi) : "v"(v[2]), "v"(v[3]));
                uint2 pk; pk.x = lo; pk.y = hi;
                *(uint2*)(Xo + (size_t)m * ldx + nb) = pk;
            } else {
                if (mode == 3) {
#pragma unroll
                    for (int e = 0; e < 4; ++e) {
                        float o = v[e] + bias[nb + e];
                        v[e] = (o > 20.f) ? o : log1pf(expf(o));
                    }
                }
                *(f32x4*)(C + (size_t)m * ldc + nb) = v;
            }
        }
    }
}

// ---------------- emb epilogue + rmsnorm (sums 4 bf16 partials) ----------------
__global__ __launch_bounds__(256)
void rmsnorm_emb_k(const ushortT* __restrict__ P, size_t pstride,
                   const float* __restrict__ b_emb, const float* __restrict__ pe,
                   const float* __restrict__ norm_w,
                   float* __restrict__ XS, ushortT* __restrict__ XN, int ldxn)
{
    int row = blockIdx.x;
    int l = (row >= SEQ_L) ? row - SEQ_L : row;
    float vv[4];
    float ssum = 0.f;
#pragma unroll
    for (int k = 0; k < 4; ++k) {
        int c = threadIdx.x + k * 256;
        if (c < 900) {
            size_t i = (size_t)row * 900 + c;
            float a = bf2f(P[i]) + bf2f(P[i + pstride]) + bf2f(P[i + 2 * pstride]) + bf2f(P[i + 3 * pstride]);
            float v = 30.f * (a + b_emb[c]) + pe[(size_t)l * 900 + c];
            vv[k] = v;
            ssum += v * v;
        } else vv[k] = 0.f;
    }
#pragma unroll
    for (int off = 32; off; off >>= 1) ssum += __shfl_down(ssum, off, 64);
    __shared__ float red[4];
    int wv = threadIdx.x >> 6;
    if ((threadIdx.x & 63) == 0) red[wv] = ssum;
    __syncthreads();
    float tot = red[0] + red[1] + red[2] + red[3];
    float scale = rsqrtf(tot / 900.f + 1e-5f);
#pragma unroll
    for (int k = 0; k < 4; ++k) {
        int c = threadIdx.x + k * 256;
        if (c < 900) {
            XS[(size_t)row * 900 + c] = vv[k];
            XN[(size_t)row * ldxn + c] = f2bf(vv[k] * scale * norm_w[c]);
        }
    }
}

// ---------------- final: 4 bf16 partials + residual -> rmsnorm -> out ----------------
__global__ __launch_bounds__(256)
void rmsnorm_final_k(const ushortT* __restrict__ ZP, size_t zstride,
                     const float* __restrict__ XS, const float* __restrict__ w,
                     float* __restrict__ out)
{
    int row = blockIdx.x;
    float vv[4];
    float ssum = 0.f;
#pragma unroll
    for (int k = 0; k < 4; ++k) {
        int c = threadIdx.x + k * 256;
        if (c < 900) {
            size_t i = (size_t)row * 900 + c;
            float v = bf2f(ZP[i]) + bf2f(ZP[i + zstride]) + bf2f(ZP[i + 2 * zstride]) + bf2f(ZP[i + 3 * zstride]) + XS[i];
            vv[k] = v;
            ssum += v * v;
        } else vv[k] = 0.f;
    }
#pragma unroll
    for (int off = 32; off; off >>= 1) ssum += __shfl_down(ssum, off, 64);
    __shared__ float red[4];
    int wv = threadIdx.x >> 6;
    if ((threadIdx.x & 63) == 0) red[wv] = ssum;
    __syncthreads();
    float tot = red[0] + red[1] + red[2] + red[3];
    float scale = rsqrtf(tot / 900.f + 1e-5f);
#pragma unroll
    for (int k = 0; k < 4; ++k) {
        int c = threadIdx.x + k * 256;
        if (c < 900) out[(size_t)row * 900 + c] = vv[k] * scale * w[c];
    }
}

// ---------------- conv (2 channels/thread, sums 2 partials) + silu + G ----------------
__global__ __launch_bounds__(256)
void conv_silu_k(const ushortT* __restrict__ xr0, const ushortT* __restrict__ xr1,
                 const float* __restrict__ w, const float* __restrict__ cb,
                 ushortT* __restrict__ xmc, ushortT* __restrict__ xbc,
                 ushortT* __restrict__ gout)
{
    int t = blockIdx.x * 256 + threadIdx.x;
    if (t >= MROWS * (D_INNER / 2)) return;
    int d0 = (t % (D_INNER / 2)) * 2;
    int row = t / (D_INNER / 2);
    int l = row % SEQ_L;
    float w0[4], w1[4];
#pragma unroll
    for (int k = 0; k < 4; ++k) { w0[k] = w[d0 * 4 + k]; w1[k] = w[d0 * 4 + 4 + k]; }
    int rdp = 1798 - d0;   // pair covers rev-channels for (d0+1, d0)
    float sf0 = cb[d0], sf1 = cb[d0 + 1];
    float sb0 = sf0, sb1 = sf1;
#pragma unroll
    for (int k = 0; k < 4; ++k) {
        int ll = l - 3 + k;
        if (ll < 0) continue;
        size_t ro = (size_t)(row - l + ll) * 3600;
        unsigned f0 = *(const unsigned*)(xr0 + ro + d0);
        unsigned f1 = *(const unsigned*)(xr1 + ro + d0);
        float a0 = bf2f((ushortT)f0) + bf2f((ushortT)f1);
        float a1 = bf2f((ushortT)(f0 >> 16)) + bf2f((ushortT)(f1 >> 16));
        sf0 = fmaf(w0[k], a0, sf0);
        sf1 = fmaf(w1[k], a1, sf1);
        unsigned r0 = *(const unsigned*)(xr0 + ro + rdp);
        unsigned r1 = *(const unsigned*)(xr1 + ro + rdp);
        float b0 = bf2f((ushortT)(r0 >> 16)) + bf2f((ushortT)(r1 >> 16));  // channel rdp+1 = 1799-d0
        float b1 = bf2f((ushortT)r0) + bf2f((ushortT)r1);                  // channel rdp = 1799-(d0+1)
        sb0 = fmaf(w0[k], b0, sb0);
        sb1 = fmaf(w1[k], b1, sb1);
    }
    unsigned om = (unsigned)f2bf(silu_f(sf0)) | ((unsigned)f2bf(silu_f(sf1)) << 16);
    unsigned ob = (unsigned)f2bf(silu_f(sb0)) | ((unsigned)f2bf(silu_f(sb1)) << 16);
    *(unsigned*)(xmc + (size_t)row * KP_DI + d0) = om;
    *(unsigned*)(xbc + (size_t)row * KP_DI + d0) = ob;
    size_t rr = (size_t)row * 3600 + D_INNER + d0;
    unsigned g0 = *(const unsigned*)(xr0 + rr);
    unsigned g1 = *(const unsigned*)(xr1 + rr);
    float ga = silu_f(bf2f((ushortT)g0) + bf2f((ushortT)g1));
    float gb = silu_f(bf2f((ushortT)(g0 >> 16)) + bf2f((ushortT)(g1 >> 16)));
    *(unsigned*)(gout + (size_t)row * D_INNER + d0) = (unsigned)f2bf(ga) | ((unsigned)f2bf(gb) << 16);
}

// ---------------- xp reduce: 8 f32 partials -> compact BC f32 + bf16 dt-input ----------------
__global__ __launch_bounds__(256)
void xp_reduce_k(const float* __restrict__ XPp, size_t pstride,
                 float* __restrict__ XDC, ushortT* __restrict__ XDMb, ushortT* __restrict__ XDBb)
{
    int t = blockIdx.x * 256 + threadIdx.x;
    if (t >= 2 * MROWS * 96) return;
    int dir = t / (MROWS * 96);
    int rem = t - dir * (MROWS * 96);
    int row = rem / 96, c = rem - row * 96;
    const float* basep = XPp + (size_t)dir * 8 * pstride + (size_t)row * 96 + c;
    float s = 0.f;
#pragma unroll
    for (int p = 0; p < 8; ++p) s += basep[p * pstride];
    ushortT* xdb = dir ? XDBb : XDMb;
    if (c < DT_RANK)           xdb[(size_t)row * KP_DT + c] = f2bf(s);
    else if (c < KP_DT)        xdb[(size_t)row * KP_DT + c] = 0;
    if (c >= DT_RANK && c < DT_RANK + 2 * D_STATE)
        XDC[((size_t)dir * MROWS + row) * 32 + (c - DT_RANK)] = s;
}

// ---------------- scan level 1 ----------------
__global__ __launch_bounds__(256)
void scan_l1_k(const float* __restrict__ DM, const float* __restrict__ DB,
               const ushortT* __restrict__ Um, const ushortT* __restrict__ Ub,
               const float* __restrict__ XDC, const float* __restrict__ A_log,
               float* __restrict__ HL, float* __restrict__ SD)
{
    int d = blockIdx.x * 256 + threadIdx.x;
    if (d >= D_INNER) return;
    int c = blockIdx.y, zz = blockIdx.z;
    int b = zz >> 1, dir = zz & 1;
    const float* DL = dir ? DB : DM;
    const ushortT* U = dir ? Ub : Um;
    const float* XD = XDC + (size_t)dir * MROWS * 32;
    float Aa[D_STATE];
#pragma unroll
    for (int n = 0; n < D_STATE; ++n) Aa[n] = -__expf(A_log[d * D_STATE + n]);
    float h[D_STATE] = {};
    float S = 0.f;
    int l0 = c * CLEN;
    for (int i = 0; i < CLEN; ++i) {
        size_t rowi = (size_t)b * SEQ_L + l0 + i;
        float delta = DL[rowi * D_INNER + d];
        float u = bf2f(U[rowi * KP_DI + d]);
        const float* bc = XD + rowi * 32;
        float du = delta * u;
        S += delta;
#pragma unroll
        for (int n = 0; n < D_STATE; ++n)
            h[n] = fmaf(__expf(delta * Aa[n]), h[n], du * bc[n]);
    }
    float* hp = HL + ((size_t)(zz * NCHUNK + c) * D_INNER + d) * D_STATE;
#pragma unroll
    for (int q = 0; q < 4; ++q)
        *(f32x4*)(hp + q * 4) = f32x4{h[q*4], h[q*4+1], h[q*4+2], h[q*4+3]};
    SD[(size_t)(zz * NCHUNK + c) * D_INNER + d] = S;
}

// ---------------- scan level 2: chunk combine (in place: HL[c] <- incoming h0) ----------------
__global__ __launch_bounds__(256)
void scan_l2_k(float* __restrict__ HL, const float* __restrict__ SD,
               const float* __restrict__ A_log)
{
    int t = blockIdx.x * 256 + threadIdx.x;
    if (t >= 4 * D_INNER * D_STATE) return;
    int n = t & 15;
    int d = (t >> 4) % D_INNER;
    int zz = t / (D_INNER * D_STATE);
    float Aa = -__expf(A_log[d * D_STATE + n]);
    float h0 = 0.f;
    for (int c = 0; c < NCHUNK; ++c) {
        size_t ih = ((size_t)(zz * NCHUNK + c) * D_INNER + d) * D_STATE + n;
        float hl = HL[ih];
        float T = __expf(Aa * SD[(size_t)(zz * NCHUNK + c) * D_INNER + d]);
        HL[ih] = h0;
        h0 = fmaf(T, h0, hl);
    }
}

// ---------------- scan level 3 + gate fused: both dirs per thread, writes YC bf16 ----------------
__global__ __launch_bounds__(256)
void scan3_gate_k(const float* __restrict__ DM, const float* __restrict__ DB,
                  const ushortT* __restrict__ Um, const ushortT* __restrict__ Ub,
                  const float* __restrict__ XDC, const float* __restrict__ A_log,
                  const float* __restrict__ Dv, const float* __restrict__ HL,
                  const ushortT* __restrict__ G, ushortT* __restrict__ YC)
{
    int d = blockIdx.x * 256 + threadIdx.x;
    if (d >= D_INNER) return;
    int c = blockIdx.y, b = blockIdx.z;
    int rd = D_INNER - 1 - d;
    float Aa0[D_STATE], Aa1[D_STATE], h0[D_STATE], h1[D_STATE];
#pragma unroll
    for (int n = 0; n < D_STATE; ++n) Aa0[n] = -__expf(A_log[d * D_STATE + n]);
#pragma unroll
    for (int n = 0; n < D_STATE; ++n) Aa1[n] = -__expf(A_log[rd * D_STATE + n]);
    const float* hp0 = HL + ((size_t)((b * 2) * NCHUNK + c) * D_INNER + d) * D_STATE;
    const float* hp1 = HL + ((size_t)((b * 2 + 1) * NCHUNK + c) * D_INNER + rd) * D_STATE;
#pragma unroll
    for (int q = 0; q < 4; ++q) {
        f32x4 t0 = *(const f32x4*)(hp0 + q * 4);
        f32x4 t1 = *(const f32x4*)(hp1 + q * 4);
        h0[q*4] = t0[0]; h0[q*4+1] = t0[1]; h0[q*4+2] = t0[2]; h0[q*4+3] = t0[3];
        h1[q*4] = t1[0]; h1[q*4+1] = t1[1]; h1[q*4+2] = t1[2]; h1[q*4+3] = t1[3];
    }
    float Dd0 = Dv[d], Dd1 = Dv[rd];
    const float* XD0 = XDC;
    const float* XD1 = XDC + (size_t)MROWS * 32;
    int l0 = c * CLEN;
    for (int i = 0; i < CLEN; ++i) {
        size_t rowi = (size_t)b * SEQ_L + l0 + i;
        float delta0 = DM[rowi * D_INNER + d];
        float u0 = bf2f(Um[rowi * KP_DI + d]);
        const float* bc0 = XD0 + rowi * 32;
        float du0 = delta0 * u0;
        float acc0 = u0 * Dd0;
#pragma unroll
        for (int n = 0; n < D_STATE; ++n) {
            h0[n] = fmaf(__expf(delta0 * Aa0[n]), h0[n], du0 * bc0[n]);
            acc0 = fmaf(h0[n], bc0[D_STATE + n], acc0);
        }
        float delta1 = DB[rowi * D_INNER + rd];
        float u1 = bf2f(Ub[rowi * KP_DI + rd]);
        const float* bc1 = XD1 + rowi * 32;
        float du1 = delta1 * u1;
        float acc1 = u1 * Dd1;
#pragma unroll
        for (int n = 0; n < D_STATE; ++n) {
            h1[n] = fmaf(__expf(delta1 * Aa1[n]), h1[n], du1 * bc1[n]);
            acc1 = fmaf(h1[n], bc1[D_STATE + n], acc1);
        }
        float g = bf2f(G[rowi * D_INNER + d]);
        YC[rowi * KP_DI + d] = f2bf((acc0 + acc1) * g);
    }
}

extern "C" void kernel_launch(void* const* d_in, const int* in_sizes, int n_in,
                              void* d_out, int out_size, void* d_ws, size_t ws_size,
                              hipStream_t stream)
{
    const float* inp    = (const float*)d_in[0];
    const float* W_emb  = (const float*)d_in[1];
    const float* b_emb  = (const float*)d_in[2];
    const float* norm_w = (const float*)d_in[3];
    const float* W_in   = (const float*)d_in[4];
    const float* conv_w = (const float*)d_in[5];
    const float* conv_b = (const float*)d_in[6];
    const float* W_xp   = (const float*)d_in[7];
    const float* W_dt   = (const float*)d_in[8];
    const float* b_dt   = (const float*)d_in[9];
    const float* A_log  = (const float*)d_in[10];
    const float* Dv     = (const float*)d_in[11];
    const float* W_out  = (const float*)d_in[12];
    const float* normf_w= (const float*)d_in[13];
    const float* pe     = (const float*)d_in[14];

    char* base = (char*)d_ws;
    size_t off = 0;
    auto alloc = [&](size_t bytes) { char* p = base + off; off += (bytes + 255) & ~(size_t)255; return p; };

    float*   XS      = (float*)alloc(6480000);        // residual f32, lives to end
    // arena1: XPp (11.06MB, xp partials) -> HL(20.736MB)+SD(1.296MB)
    char*    arena1  = alloc(22032000);
    float*   XPp     = (float*)arena1;
    float*   HL      = (float*)arena1;
    float*   SD      = (float*)(arena1 + 20736000);
    ushortT* inp_bf  = (ushortT*)alloc(3686400);      // 1920x960; later start of YC
    ushortT* XN_bf   = (ushortT*)alloc(3686400);      // contiguous after inp_bf (YC spillover)
    ushortT* Wemb_bf = (ushortT*)alloc(1966080);      // 1024x960; after emb: XDC+XDM_bf+XDB_bf
    ushortT* Win_bf  = (ushortT*)alloc(7127040);      // 3712x960; after in-proj: XMC_bf (1920x1856)
    ushortT* Wxp_bf  = (ushortT*)alloc(475136);       // 128x1856
    ushortT* Wdt_bf  = (ushortT*)alloc(245760);       // 1920x64
    ushortT* Wout_bf = (ushortT*)alloc(3801088);      // 1024x1856
    ushortT* XBC_bf  = (ushortT*)alloc(7127040);      // 1920x1856
    // arena2 (25.92MB): Pemb(bf16 x4) -> XR0/XR1 -> DM/DB -> ZP(bf16 x4)
    char*    arena2  = alloc(25920000);
    ushortT* Pemb    = (ushortT*)arena2;
    ushortT* XR0     = (ushortT*)arena2;
    ushortT* XR1     = XR0 + (size_t)MROWS * 3600;
    float*   DM      = (float*)arena2;
    float*   DB      = DM + (size_t)MROWS * D_INNER;
    ushortT* ZP      = (ushortT*)arena2;
    ushortT* G_bf    = (ushortT*)alloc(6480000);      // 1800x1800 bf16

    // aliases into dead regions
    float*   XDC     = (float*)Wemb_bf;               // 2x1800x32 f32 = 460800 B
    ushortT* XDM_bf  = (ushortT*)((char*)Wemb_bf + 460800);   // 1920x64 bf16
    ushortT* XDB_bf  = (ushortT*)((char*)Wemb_bf + 706560);
    ushortT* XMC_bf  = Win_bf;                        // 1920x1856 bf16, exact fit
    ushortT* YC_bf   = inp_bf;                        // 1920x1856 spans inp_bf+XN_bf (7.13<=7.37MB)

    dim3 blk(256);
    auto cdiv = [](int a, int b) { return (a + b - 1) / b; };
    const size_t PSTR  = 1620000;   // 1800*900 elements (bf16 partial stride)
    const size_t XPSTR = 172800;    // 1800*96 f32 partial stride
    const size_t XRSTR = (size_t)MROWS * 3600;

    // 0) all conversions
    hipLaunchKernelGGL(cvt_all_k, dim3(3480, 6), blk, 0, stream,
                       inp, inp_bf, W_emb, Wemb_bf, W_in, Win_bf,
                       W_xp, Wxp_bf, W_dt, Wdt_bf, W_out, Wout_bf);
    // 1) embedding GEMM split-4 -> Pemb (bf16 partials)
    hipLaunchKernelGGL(gemm_mfma_k, dim3(8, 15, 4), blk, 0, stream,
                       inp_bf, inp_bf, KP_DM, Wemb_bf, KP_DM, KP_DM/64, 4,
                       (float*)nullptr, (float*)nullptr, 0, (size_t)0,
                       Pemb, Pemb, 900, PSTR,
                       MROWS, 900, (const float*)nullptr, 1);
    // 2) emb epilogue + rmsnorm -> XS, XN_bf
    hipLaunchKernelGGL(rmsnorm_emb_k, dim3(MROWS), blk, 0, stream,
                       Pemb, PSTR, b_emb, pe, norm_w, XS, XN_bf, KP_DM);
    // 3) in-proj split-2 -> XR0/XR1 (bf16 partials)
    hipLaunchKernelGGL(gemm_mfma_k, dim3(29, 15, 2), blk, 0, stream,
                       XN_bf, XN_bf, KP_DM, Win_bf, KP_DM, KP_DM/64, 2,
                       (float*)nullptr, (float*)nullptr, 0, (size_t)0,
                       XR0, XR0, 3600, XRSTR,
                       MROWS, 3600, (const float*)nullptr, 1);
    // 4) conv + silu + G
    hipLaunchKernelGGL(conv_silu_k, dim3(cdiv(MROWS * (D_INNER/2), 256)), blk, 0, stream,
                       XR0, XR1, conv_w, conv_b, XMC_bf, XBC_bf, G_bf);
    // 5) x-proj split-8 both dirs -> XPp (f32 partials)
    hipLaunchKernelGGL(gemm_mfma_k, dim3(1, 15, 16), blk, 0, stream,
                       XMC_bf, XBC_bf, KP_DI, Wxp_bf, KP_DI, KP_DI/64, 8,
                       XPp, XPp + 8 * XPSTR, 96, XPSTR,
                       (ushortT*)nullptr, (ushortT*)nullptr, 0, (size_t)0,
                       MROWS, 96, (const float*)nullptr, 0);
    // 5b) xp reduce -> XDC (compact BC) + bf16 dt inputs
    hipLaunchKernelGGL(xp_reduce_k, dim3(cdiv(2 * MROWS * 96, 256)), blk, 0, stream,
                       XPp, XPSTR, XDC, XDM_bf, XDB_bf);
    // 6) dt GEMM both dirs + softplus -> DM, DB (f32)
    hipLaunchKernelGGL(gemm_mfma_k, dim3(15, 15, 2), blk, 0, stream,
                       XDM_bf, XDB_bf, KP_DT, Wdt_bf, KP_DT, 1, 1,
                       DM, DB, D_INNER, (size_t)0,
                       (ushortT*)nullptr, (ushortT*)nullptr, 0, (size_t)0,
                       MROWS, D_INNER, b_dt, 3);
    // 7) chunked scan
    hipLaunchKernelGGL(scan_l1_k, dim3(cdiv(D_INNER, 256), NCHUNK, 4), blk, 0, stream,
                       DM, DB, XMC_bf, XBC_bf, XDC, A_log, HL, SD);
    hipLaunchKernelGGL(scan_l2_k, dim3(cdiv(4 * D_INNER * D_STATE, 256)), blk, 0, stream, HL, SD, A_log);
    // 7c) level 3 + gate fused -> YC bf16
    hipLaunchKernelGGL(scan3_gate_k, dim3(cdiv(D_INNER, 256), NCHUNK, 2), blk, 0, stream,
                       DM, DB, XMC_bf, XBC_bf, XDC, A_log, Dv, HL, G_bf, YC_bf);
    // 9) out-proj split-4 -> ZP (bf16 partials)
    hipLaunchKernelGGL(gemm_mfma_k, dim3(8, 15, 4), blk, 0, stream,
                       YC_bf, YC_bf, KP_DI, Wout_bf, KP_DI, KP_DI/64, 4,
                       (float*)nullptr, (float*)nullptr, 0, (size_t)0,
                       ZP, ZP, 900, PSTR,
                       MROWS, 900, (const float*)nullptr, 1);
    // 10) final reduce + residual + rmsnorm -> d_out
    hipLaunchKernelGGL(rmsnorm_final_k, dim3(MROWS), blk, 0, stream,
                       ZP, PSTR, XS, normf_w, (float*)d_out);
}

// Round 6
// 299.920 us; speedup vs baseline: 7.5018x; 1.0952x over previous
//
#include <hip/hip_runtime.h>
#include <math.h>

typedef unsigned short ushortT;
typedef short short8 __attribute__((ext_vector_type(8)));
typedef float f32x4 __attribute__((ext_vector_type(4)));

#define D_STATE 16
#define D_INNER 1800
#define DT_RANK 57
#define SEQ_L 900
#define MROWS 1800            // 2*900
#define MP 1920               // padded rows
#define KP_DM 960             // K=900 pad
#define KP_DI 1856            // K=1800 pad
#define KP_DT 64              // K=57 pad
#define NCHUNK 45
#define CLEN 20

__device__ __forceinline__ ushortT f2bf(float f) {
    unsigned u = __float_as_uint(f);
    unsigned r = (u + 0x7FFFu + ((u >> 16) & 1u)) >> 16;
    return (ushortT)r;
}
__device__ __forceinline__ float bf2f(ushortT h) {
    return __uint_as_float((unsigned)h << 16);
}
__device__ __forceinline__ float silu_f(float x) { return x / (1.f + __expf(-x)); }
// fast stable softplus: ~8 VALU ops (v_exp_f32 + v_log_f32), vs libm log1pf(expf) slow path
__device__ __forceinline__ float softplus_f(float x) {
    return fmaxf(x, 0.f) + __logf(1.f + __expf(-fabsf(x)));
}

__device__ __forceinline__ void gload_lds16(const ushortT* g, ushortT* l) {
    __builtin_amdgcn_global_load_lds((const __attribute__((address_space(1))) unsigned int*)g,
                                     (__attribute__((address_space(3))) unsigned int*)l,
                                     16, 0, 0);
}

// ---------------- all fp32->bf16 pad conversions in ONE kernel ----------------
__global__ __launch_bounds__(256)
void cvt_all_k(const float* __restrict__ s0, ushortT* __restrict__ d0,   // inp 1800x900
               const float* __restrict__ s1, ushortT* __restrict__ d1,   // W_emb 900x900
               const float* __restrict__ s2, ushortT* __restrict__ d2,   // W_in 3600x900
               const float* __restrict__ s3, ushortT* __restrict__ d3,   // W_xp 89x1800
               const float* __restrict__ s4, ushortT* __restrict__ d4,   // W_dt 1800x57
               const float* __restrict__ s5, ushortT* __restrict__ d5)   // W_out 900x1800
{
    const float* src; ushortT* dst; int M, K, Mp, Kp;
    switch (blockIdx.y) {
      case 0: src=s0; dst=d0; M=1800; K=900;  Mp=1920; Kp=960;  break;
      case 1: src=s1; dst=d1; M=900;  K=900;  Mp=1024; Kp=960;  break;
      case 2: src=s2; dst=d2; M=3600; K=900;  Mp=3712; Kp=960;  break;
      case 3: src=s3; dst=d3; M=89;   K=1800; Mp=128;  Kp=1856; break;
      case 4: src=s4; dst=d4; M=1800; K=57;   Mp=1920; Kp=64;   break;
      default:src=s5; dst=d5; M=900;  K=1800; Mp=1024; Kp=1856; break;
    }
    int t = blockIdx.x * 256 + threadIdx.x;
    int K4 = Kp >> 2;
    if (t >= Mp * K4) return;
    int r = t / K4, c4 = (t - r * K4) * 4;
    ushortT o[4];
#pragma unroll
    for (int e = 0; e < 4; ++e) {
        int c = c4 + e;
        float v = (r < M && c < K) ? src[(size_t)r * K + c] : 0.f;
        o[e] = f2bf(v);
    }
    uint2 pk;
    pk.x = (unsigned)o[0] | ((unsigned)o[1] << 16);
    pk.y = (unsigned)o[2] | ((unsigned)o[3] << 16);
    *(uint2*)(dst + (size_t)r * Kp + c4) = pk;
}

// ---------------- bf16 MFMA GEMM, swapped-operand epilogue, K-split ----------------
// z: dir = z/split, s = z%split.
// mode 0: raw f32 -> C (+s*cstride), dwordx4
// mode 1: raw bf16 -> Xo (+s*xstride), cvt_pk + dwordx2
// mode 5: softplus(acc+bias) -> bf16 -> Xo
__global__ __launch_bounds__(256)
void gemm_mfma_k(const ushortT* __restrict__ A0, const ushortT* __restrict__ A1, int lda,
                 const ushortT* __restrict__ Bw, int ldb, int nkTotal, int split,
                 float* __restrict__ C0, float* __restrict__ C1, int ldc, size_t cstride,
                 ushortT* __restrict__ X0, ushortT* __restrict__ X1, int ldx, size_t xstride,
                 int M, int N, const float* __restrict__ bias, int mode)
{
    __shared__ ushortT As[128 * 64];
    __shared__ ushortT Bs[128 * 64];
    int z = blockIdx.z;
    int dir = z / split, s = z % split;
    int per = (nkTotal + split - 1) / split;
    int kt0 = s * per;
    int kcnt = nkTotal - kt0; if (kcnt > per) kcnt = per;

    const ushortT* A = dir ? A1 : A0;
    float* C = (dir ? C1 : C0);
    ushortT* Xo = (dir ? X1 : X0);
    if (C)  C  += (size_t)s * cstride;
    if (Xo) Xo += (size_t)s * xstride;

    int tid = threadIdx.x;
    int lane = tid & 63, wave = tid >> 6;
    int wr = wave >> 1, wc = wave & 1;
    int m0 = blockIdx.y * 128, n0 = blockIdx.x * 128;

    f32x4 acc[4][4] = {};

    for (int kt = kt0; kt < kt0 + kcnt; ++kt) {
#pragma unroll
        for (int r = 0; r < 4; ++r) {
            int idx = r * 256 + tid;
            int row = idx >> 3, c8 = (idx & 7) << 3;
            gload_lds16(A + (size_t)(m0 + row) * lda + kt * 64 + c8, As + idx * 8);
        }
#pragma unroll
        for (int r = 0; r < 4; ++r) {
            int idx = r * 256 + tid;
            int row = idx >> 3, c8 = (idx & 7) << 3;
            gload_lds16(Bw + (size_t)(n0 + row) * ldb + kt * 64 + c8, Bs + idx * 8);
        }
        __syncthreads();
#pragma unroll
        for (int ks = 0; ks < 2; ++ks) {
            short8 av[4], bv[4];
            int kcol = ks * 32 + (lane >> 4) * 8;
#pragma unroll
            for (int i = 0; i < 4; ++i)
                av[i] = *(const short8*)(As + (wr * 64 + i * 16 + (lane & 15)) * 64 + kcol);
#pragma unroll
            for (int j = 0; j < 4; ++j)
                bv[j] = *(const short8*)(Bs + (wc * 64 + j * 16 + (lane & 15)) * 64 + kcol);
            // swapped operands: output reg-axis = N (4 consecutive cols per lane)
#pragma unroll
            for (int i = 0; i < 4; ++i)
#pragma unroll
                for (int j = 0; j < 4; ++j)
                    acc[i][j] = __builtin_amdgcn_mfma_f32_16x16x32_bf16(bv[j], av[i], acc[i][j], 0, 0, 0);
        }
        __syncthreads();
    }

#pragma unroll
    for (int i = 0; i < 4; ++i) {
        int m = m0 + wr * 64 + i * 16 + (lane & 15);
        if (m >= M) continue;
#pragma unroll
        for (int j = 0; j < 4; ++j) {
            int nb = n0 + wc * 64 + j * 16 + (lane >> 4) * 4;
            if (nb >= N) continue;     // N and nb are multiples of 4
            f32x4 v = acc[i][j];
            if (mode == 5) {
#pragma unroll
                for (int e = 0; e < 4; ++e)
                    v[e] = softplus_f(v[e] + bias[nb + e]);
            }
            if (mode == 1 || mode == 5) {
                unsigned lo, hi;
                asm("v_cvt_pk_bf16_f32 %0, %1, %2" : "=v"(lo) : "v"(v[0]), "v"(v[1]));
                asm("v_cvt_pk_bf16_f32 %0, %1, %2" : "=v"(hi) : "v"(v[2]), "v"(v[3]));
                uint2 pk; pk.x = lo; pk.y = hi;
                *(uint2*)(Xo + (size_t)m * ldx + nb) = pk;
            } else {
                *(f32x4*)(C + (size_t)m * ldc + nb) = v;
            }
        }
    }
}

// ---------------- emb epilogue + rmsnorm (sums 4 bf16 partials) ----------------
__global__ __launch_bounds__(256)
void rmsnorm_emb_k(const ushortT* __restrict__ P, size_t pstride,
                   const float* __restrict__ b_emb, const float* __restrict__ pe,
                   const float* __restrict__ norm_w,
                   float* __restrict__ XS, ushortT* __restrict__ XN, int ldxn)
{
    int row = blockIdx.x;
    int l = (row >= SEQ_L) ? row - SEQ_L : row;
    float vv[4];
    float ssum = 0.f;
#pragma unroll
    for (int k = 0; k < 4; ++k) {
        int c = threadIdx.x + k * 256;
        if (c < 900) {
            size_t i = (size_t)row * 900 + c;
            float a = bf2f(P[i]) + bf2f(P[i + pstride]) + bf2f(P[i + 2 * pstride]) + bf2f(P[i + 3 * pstride]);
            float v = 30.f * (a + b_emb[c]) + pe[(size_t)l * 900 + c];
            vv[k] = v;
            ssum += v * v;
        } else vv[k] = 0.f;
    }
#pragma unroll
    for (int off = 32; off; off >>= 1) ssum += __shfl_down(ssum, off, 64);
    __shared__ float red[4];
    int wv = threadIdx.x >> 6;
    if ((threadIdx.x & 63) == 0) red[wv] = ssum;
    __syncthreads();
    float tot = red[0] + red[1] + red[2] + red[3];
    float scale = rsqrtf(tot / 900.f + 1e-5f);
#pragma unroll
    for (int k = 0; k < 4; ++k) {
        int c = threadIdx.x + k * 256;
        if (c < 900) {
            XS[(size_t)row * 900 + c] = vv[k];
            XN[(size_t)row * ldxn + c] = f2bf(vv[k] * scale * norm_w[c]);
        }
    }
}

// ---------------- final: 4 bf16 partials + residual -> rmsnorm -> out ----------------
__global__ __launch_bounds__(256)
void rmsnorm_final_k(const ushortT* __restrict__ ZP, size_t zstride,
                     const float* __restrict__ XS, const float* __restrict__ w,
                     float* __restrict__ out)
{
    int row = blockIdx.x;
    float vv[4];
    float ssum = 0.f;
#pragma unroll
    for (int k = 0; k < 4; ++k) {
        int c = threadIdx.x + k * 256;
        if (c < 900) {
            size_t i = (size_t)row * 900 + c;
            float v = bf2f(ZP[i]) + bf2f(ZP[i + zstride]) + bf2f(ZP[i + 2 * zstride]) + bf2f(ZP[i + 3 * zstride]) + XS[i];
            vv[k] = v;
            ssum += v * v;
        } else vv[k] = 0.f;
    }
#pragma unroll
    for (int off = 32; off; off >>= 1) ssum += __shfl_down(ssum, off, 64);
    __shared__ float red[4];
    int wv = threadIdx.x >> 6;
    if ((threadIdx.x & 63) == 0) red[wv] = ssum;
    __syncthreads();
    float tot = red[0] + red[1] + red[2] + red[3];
    float scale = rsqrtf(tot / 900.f + 1e-5f);
#pragma unroll
    for (int k = 0; k < 4; ++k) {
        int c = threadIdx.x + k * 256;
        if (c < 900) out[(size_t)row * 900 + c] = vv[k] * scale * w[c];
    }
}

// ---------------- conv (2 channels/thread, sums 2 partials) + silu + G ----------------
__global__ __launch_bounds__(256)
void conv_silu_k(const ushortT* __restrict__ xr0, const ushortT* __restrict__ xr1,
                 const float* __restrict__ w, const float* __restrict__ cb,
                 ushortT* __restrict__ xmc, ushortT* __restrict__ xbc,
                 ushortT* __restrict__ gout)
{
    int t = blockIdx.x * 256 + threadIdx.x;
    if (t >= MROWS * (D_INNER / 2)) return;
    int d0 = (t % (D_INNER / 2)) * 2;
    int row = t / (D_INNER / 2);
    int l = row % SEQ_L;
    float w0[4], w1[4];
#pragma unroll
    for (int k = 0; k < 4; ++k) { w0[k] = w[d0 * 4 + k]; w1[k] = w[d0 * 4 + 4 + k]; }
    int rdp = 1798 - d0;   // pair covers rev-channels for (d0+1, d0)
    float sf0 = cb[d0], sf1 = cb[d0 + 1];
    float sb0 = sf0, sb1 = sf1;
#pragma unroll
    for (int k = 0; k < 4; ++k) {
        int ll = l - 3 + k;
        if (ll < 0) continue;
        size_t ro = (size_t)(row - l + ll) * 3600;
        unsigned f0 = *(const unsigned*)(xr0 + ro + d0);
        unsigned f1 = *(const unsigned*)(xr1 + ro + d0);
        float a0 = bf2f((ushortT)f0) + bf2f((ushortT)f1);
        float a1 = bf2f((ushortT)(f0 >> 16)) + bf2f((ushortT)(f1 >> 16));
        sf0 = fmaf(w0[k], a0, sf0);
        sf1 = fmaf(w1[k], a1, sf1);
        unsigned r0 = *(const unsigned*)(xr0 + ro + rdp);
        unsigned r1 = *(const unsigned*)(xr1 + ro + rdp);
        float b0 = bf2f((ushortT)(r0 >> 16)) + bf2f((ushortT)(r1 >> 16));  // channel rdp+1 = 1799-d0
        float b1 = bf2f((ushortT)r0) + bf2f((ushortT)r1);                  // channel rdp = 1799-(d0+1)
        sb0 = fmaf(w0[k], b0, sb0);
        sb1 = fmaf(w1[k], b1, sb1);
    }
    unsigned om = (unsigned)f2bf(silu_f(sf0)) | ((unsigned)f2bf(silu_f(sf1)) << 16);
    unsigned ob = (unsigned)f2bf(silu_f(sb0)) | ((unsigned)f2bf(silu_f(sb1)) << 16);
    *(unsigned*)(xmc + (size_t)row * KP_DI + d0) = om;
    *(unsigned*)(xbc + (size_t)row * KP_DI + d0) = ob;
    size_t rr = (size_t)row * 3600 + D_INNER + d0;
    unsigned g0 = *(const unsigned*)(xr0 + rr);
    unsigned g1 = *(const unsigned*)(xr1 + rr);
    float ga = silu_f(bf2f((ushortT)g0) + bf2f((ushortT)g1));
    float gb = silu_f(bf2f((ushortT)(g0 >> 16)) + bf2f((ushortT)(g1 >> 16)));
    *(unsigned*)(gout + (size_t)row * D_INNER + d0) = (unsigned)f2bf(ga) | ((unsigned)f2bf(gb) << 16);
}

// ---------------- xp reduce: 8 f32 partials -> compact BC f32 + bf16 dt-input ----------------
__global__ __launch_bounds__(256)
void xp_reduce_k(const float* __restrict__ XPp, size_t pstride,
                 float* __restrict__ XDC, ushortT* __restrict__ XDMb, ushortT* __restrict__ XDBb)
{
    int t = blockIdx.x * 256 + threadIdx.x;
    if (t >= 2 * MROWS * 96) return;
    int dir = t / (MROWS * 96);
    int rem = t - dir * (MROWS * 96);
    int row = rem / 96, c = rem - row * 96;
    const float* basep = XPp + (size_t)dir * 8 * pstride + (size_t)row * 96 + c;
    float s = 0.f;
#pragma unroll
    for (int p = 0; p < 8; ++p) s += basep[p * pstride];
    ushortT* xdb = dir ? XDBb : XDMb;
    if (c < DT_RANK)           xdb[(size_t)row * KP_DT + c] = f2bf(s);
    else if (c < KP_DT)        xdb[(size_t)row * KP_DT + c] = 0;
    if (c >= DT_RANK && c < DT_RANK + 2 * D_STATE)
        XDC[((size_t)dir * MROWS + row) * 32 + (c - DT_RANK)] = s;
}

// ---------------- scan level 1 (delta in bf16) ----------------
__global__ __launch_bounds__(256)
void scan_l1_k(const ushortT* __restrict__ DMb, const ushortT* __restrict__ DBb,
               const ushortT* __restrict__ Um, const ushortT* __restrict__ Ub,
               const float* __restrict__ XDC, const float* __restrict__ A_log,
               float* __restrict__ HL, float* __restrict__ SD)
{
    int d = blockIdx.x * 256 + threadIdx.x;
    if (d >= D_INNER) return;
    int c = blockIdx.y, zz = blockIdx.z;
    int b = zz >> 1, dir = zz & 1;
    const ushortT* DL = dir ? DBb : DMb;
    const ushortT* U = dir ? Ub : Um;
    const float* XD = XDC + (size_t)dir * MROWS * 32;
    float Aa[D_STATE];
#pragma unroll
    for (int n = 0; n < D_STATE; ++n) Aa[n] = -__expf(A_log[d * D_STATE + n]);
    float h[D_STATE] = {};
    float S = 0.f;
    int l0 = c * CLEN;
    for (int i = 0; i < CLEN; ++i) {
        size_t rowi = (size_t)b * SEQ_L + l0 + i;
        float delta = bf2f(DL[rowi * D_INNER + d]);
        float u = bf2f(U[rowi * KP_DI + d]);
        const float* bc = XD + rowi * 32;
        float du = delta * u;
        S += delta;
#pragma unroll
        for (int n = 0; n < D_STATE; ++n)
            h[n] = fmaf(__expf(delta * Aa[n]), h[n], du * bc[n]);
    }
    float* hp = HL + ((size_t)(zz * NCHUNK + c) * D_INNER + d) * D_STATE;
#pragma unroll
    for (int q = 0; q < 4; ++q)
        *(f32x4*)(hp + q * 4) = f32x4{h[q*4], h[q*4+1], h[q*4+2], h[q*4+3]};
    SD[(size_t)(zz * NCHUNK + c) * D_INNER + d] = S;
}

// ---------------- scan level 2: chunk combine (in place: HL[c] <- incoming h0) ----------------
__global__ __launch_bounds__(256)
void scan_l2_k(float* __restrict__ HL, const float* __restrict__ SD,
               const float* __restrict__ A_log)
{
    int t = blockIdx.x * 256 + threadIdx.x;
    if (t >= 4 * D_INNER * D_STATE) return;
    int n = t & 15;
    int d = (t >> 4) % D_INNER;
    int zz = t / (D_INNER * D_STATE);
    float Aa = -__expf(A_log[d * D_STATE + n]);
    float h0 = 0.f;
    for (int c = 0; c < NCHUNK; ++c) {
        size_t ih = ((size_t)(zz * NCHUNK + c) * D_INNER + d) * D_STATE + n;
        float hl = HL[ih];
        float T = __expf(Aa * SD[(size_t)(zz * NCHUNK + c) * D_INNER + d]);
        HL[ih] = h0;
        h0 = fmaf(T, h0, hl);
    }
}

// ---------------- scan level 3 + gate fused: both dirs per thread, writes YC bf16 ----------------
__global__ __launch_bounds__(256)
void scan3_gate_k(const ushortT* __restrict__ DMb, const ushortT* __restrict__ DBb,
                  const ushortT* __restrict__ Um, const ushortT* __restrict__ Ub,
                  const float* __restrict__ XDC, const float* __restrict__ A_log,
                  const float* __restrict__ Dv, const float* __restrict__ HL,
                  const ushortT* __restrict__ G, ushortT* __restrict__ YC)
{
    int d = blockIdx.x * 256 + threadIdx.x;
    if (d >= D_INNER) return;
    int c = blockIdx.y, b = blockIdx.z;
    int rd = D_INNER - 1 - d;
    float Aa0[D_STATE], Aa1[D_STATE], h0[D_STATE], h1[D_STATE];
#pragma unroll
    for (int n = 0; n < D_STATE; ++n) Aa0[n] = -__expf(A_log[d * D_STATE + n]);
#pragma unroll
    for (int n = 0; n < D_STATE; ++n) Aa1[n] = -__expf(A_log[rd * D_STATE + n]);
    const float* hp0 = HL + ((size_t)((b * 2) * NCHUNK + c) * D_INNER + d) * D_STATE;
    const float* hp1 = HL + ((size_t)((b * 2 + 1) * NCHUNK + c) * D_INNER + rd) * D_STATE;
#pragma unroll
    for (int q = 0; q < 4; ++q) {
        f32x4 t0 = *(const f32x4*)(hp0 + q * 4);
        f32x4 t1 = *(const f32x4*)(hp1 + q * 4);
        h0[q*4] = t0[0]; h0[q*4+1] = t0[1]; h0[q*4+2] = t0[2]; h0[q*4+3] = t0[3];
        h1[q*4] = t1[0]; h1[q*4+1] = t1[1]; h1[q*4+2] = t1[2]; h1[q*4+3] = t1[3];
    }
    float Dd0 = Dv[d], Dd1 = Dv[rd];
    const float* XD0 = XDC;
    const float* XD1 = XDC + (size_t)MROWS * 32;
    int l0 = c * CLEN;
    for (int i = 0; i < CLEN; ++i) {
        size_t rowi = (size_t)b * SEQ_L + l0 + i;
        float delta0 = bf2f(DMb[rowi * D_INNER + d]);
        float u0 = bf2f(Um[rowi * KP_DI + d]);
        const float* bc0 = XD0 + rowi * 32;
        float du0 = delta0 * u0;
        float acc0 = u0 * Dd0;
#pragma unroll
        for (int n = 0; n < D_STATE; ++n) {
            h0[n] = fmaf(__expf(delta0 * Aa0[n]), h0[n], du0 * bc0[n]);
            acc0 = fmaf(h0[n], bc0[D_STATE + n], acc0);
        }
        float delta1 = bf2f(DBb[rowi * D_INNER + rd]);
        float u1 = bf2f(Ub[rowi * KP_DI + rd]);
        const float* bc1 = XD1 + rowi * 32;
        float du1 = delta1 * u1;
        float acc1 = u1 * Dd1;
#pragma unroll
        for (int n = 0; n < D_STATE; ++n) {
            h1[n] = fmaf(__expf(delta1 * Aa1[n]), h1[n], du1 * bc1[n]);
            acc1 = fmaf(h1[n], bc1[D_STATE + n], acc1);
        }
        float g = bf2f(G[rowi * D_INNER + d]);
        YC[rowi * KP_DI + d] = f2bf((acc0 + acc1) * g);
    }
}

extern "C" void kernel_launch(void* const* d_in, const int* in_sizes, int n_in,
                              void* d_out, int out_size, void* d_ws, size_t ws_size,
                              hipStream_t stream)
{
    const float* inp    = (const float*)d_in[0];
    const float* W_emb  = (const float*)d_in[1];
    const float* b_emb  = (const float*)d_in[2];
    const float* norm_w = (const float*)d_in[3];
    const float* W_in   = (const float*)d_in[4];
    const float* conv_w = (const float*)d_in[5];
    const float* conv_b = (const float*)d_in[6];
    const float* W_xp   = (const float*)d_in[7];
    const float* W_dt   = (const float*)d_in[8];
    const float* b_dt   = (const float*)d_in[9];
    const float* A_log  = (const float*)d_in[10];
    const float* Dv     = (const float*)d_in[11];
    const float* W_out  = (const float*)d_in[12];
    const float* normf_w= (const float*)d_in[13];
    const float* pe     = (const float*)d_in[14];

    char* base = (char*)d_ws;
    size_t off = 0;
    auto alloc = [&](size_t bytes) { char* p = base + off; off += (bytes + 255) & ~(size_t)255; return p; };

    float*   XS      = (float*)alloc(6480000);        // residual f32, lives to end
    // arena1: XPp (11.06MB, xp partials) -> HL(20.736MB)+SD(1.296MB)
    char*    arena1  = alloc(22032000);
    float*   XPp     = (float*)arena1;
    float*   HL      = (float*)arena1;
    float*   SD      = (float*)(arena1 + 20736000);
    ushortT* inp_bf  = (ushortT*)alloc(3686400);      // 1920x960; later start of YC
    ushortT* XN_bf   = (ushortT*)alloc(3686400);      // contiguous after inp_bf (YC spillover)
    ushortT* Wemb_bf = (ushortT*)alloc(1966080);      // 1024x960; after emb: XDC+XDM_bf+XDB_bf
    ushortT* Win_bf  = (ushortT*)alloc(7127040);      // 3712x960; after in-proj: XMC_bf (1920x1856)
    ushortT* Wxp_bf  = (ushortT*)alloc(475136);       // 128x1856
    ushortT* Wdt_bf  = (ushortT*)alloc(245760);       // 1920x64
    ushortT* Wout_bf = (ushortT*)alloc(3801088);      // 1024x1856
    ushortT* XBC_bf  = (ushortT*)alloc(7127040);      // 1920x1856
    // arena2 (25.92MB): Pemb(bf16 x4) -> XR0/XR1 -> DMb/DBb(bf16) -> ZP(bf16 x4)
    char*    arena2  = alloc(25920000);
    ushortT* Pemb    = (ushortT*)arena2;
    ushortT* XR0     = (ushortT*)arena2;
    ushortT* XR1     = XR0 + (size_t)MROWS * 3600;
    ushortT* DMb     = (ushortT*)arena2;
    ushortT* DBb     = DMb + (size_t)MROWS * D_INNER;
    ushortT* ZP      = (ushortT*)arena2;
    ushortT* G_bf    = (ushortT*)alloc(6480000);      // 1800x1800 bf16

    // aliases into dead regions
    float*   XDC     = (float*)Wemb_bf;               // 2x1800x32 f32 = 460800 B
    ushortT* XDM_bf  = (ushortT*)((char*)Wemb_bf + 460800);   // 1920x64 bf16
    ushortT* XDB_bf  = (ushortT*)((char*)Wemb_bf + 706560);
    ushortT* XMC_bf  = Win_bf;                        // 1920x1856 bf16, exact fit
    ushortT* YC_bf   = inp_bf;                        // 1920x1856 spans inp_bf+XN_bf (7.13<=7.37MB)

    dim3 blk(256);
    auto cdiv = [](int a, int b) { return (a + b - 1) / b; };
    const size_t PSTR  = 1620000;   // 1800*900 elements (bf16 partial stride)
    const size_t XPSTR = 172800;    // 1800*96 f32 partial stride
    const size_t XRSTR = (size_t)MROWS * 3600;

    // 0) all conversions
    hipLaunchKernelGGL(cvt_all_k, dim3(3480, 6), blk, 0, stream,
                       inp, inp_bf, W_emb, Wemb_bf, W_in, Win_bf,
                       W_xp, Wxp_bf, W_dt, Wdt_bf, W_out, Wout_bf);
    // 1) embedding GEMM split-4 -> Pemb (bf16 partials)
    hipLaunchKernelGGL(gemm_mfma_k, dim3(8, 15, 4), blk, 0, stream,
                       inp_bf, inp_bf, KP_DM, Wemb_bf, KP_DM, KP_DM/64, 4,
                       (float*)nullptr, (float*)nullptr, 0, (size_t)0,
                       Pemb, Pemb, 900, PSTR,
                       MROWS, 900, (const float*)nullptr, 1);
    // 2) emb epilogue + rmsnorm -> XS, XN_bf
    hipLaunchKernelGGL(rmsnorm_emb_k, dim3(MROWS), blk, 0, stream,
                       Pemb, PSTR, b_emb, pe, norm_w, XS, XN_bf, KP_DM);
    // 3) in-proj split-2 -> XR0/XR1 (bf16 partials)
    hipLaunchKernelGGL(gemm_mfma_k, dim3(29, 15, 2), blk, 0, stream,
                       XN_bf, XN_bf, KP_DM, Win_bf, KP_DM, KP_DM/64, 2,
                       (float*)nullptr, (float*)nullptr, 0, (size_t)0,
                       XR0, XR0, 3600, XRSTR,
                       MROWS, 3600, (const float*)nullptr, 1);
    // 4) conv + silu + G
    hipLaunchKernelGGL(conv_silu_k, dim3(cdiv(MROWS * (D_INNER/2), 256)), blk, 0, stream,
                       XR0, XR1, conv_w, conv_b, XMC_bf, XBC_bf, G_bf);
    // 5) x-proj split-8 both dirs -> XPp (f32 partials)
    hipLaunchKernelGGL(gemm_mfma_k, dim3(1, 15, 16), blk, 0, stream,
                       XMC_bf, XBC_bf, KP_DI, Wxp_bf, KP_DI, KP_DI/64, 8,
                       XPp, XPp + 8 * XPSTR, 96, XPSTR,
                       (ushortT*)nullptr, (ushortT*)nullptr, 0, (size_t)0,
                       MROWS, 96, (const float*)nullptr, 0);
    // 5b) xp reduce -> XDC (compact BC) + bf16 dt inputs
    hipLaunchKernelGGL(xp_reduce_k, dim3(cdiv(2 * MROWS * 96, 256)), blk, 0, stream,
                       XPp, XPSTR, XDC, XDM_bf, XDB_bf);
    // 6) dt GEMM both dirs + fast-softplus -> DMb, DBb (bf16)
    hipLaunchKernelGGL(gemm_mfma_k, dim3(15, 15, 2), blk, 0, stream,
                       XDM_bf, XDB_bf, KP_DT, Wdt_bf, KP_DT, 1, 1,
                       (float*)nullptr, (float*)nullptr, 0, (size_t)0,
                       DMb, DBb, D_INNER, (size_t)0,
                       MROWS, D_INNER, b_dt, 5);
    // 7) chunked scan
    hipLaunchKernelGGL(scan_l1_k, dim3(cdiv(D_INNER, 256), NCHUNK, 4), blk, 0, stream,
                       DMb, DBb, XMC_bf, XBC_bf, XDC, A_log, HL, SD);
    hipLaunchKernelGGL(scan_l2_k, dim3(cdiv(4 * D_INNER * D_STATE, 256)), blk, 0, stream, HL, SD, A_log);
    // 7c) level 3 + gate fused -> YC bf16
    hipLaunchKernelGGL(scan3_gate_k, dim3(cdiv(D_INNER, 256), NCHUNK, 2), blk, 0, stream,
                       DMb, DBb, XMC_bf, XBC_bf, XDC, A_log, Dv, HL, G_bf, YC_bf);
    // 9) out-proj split-4 -> ZP (bf16 partials)
    hipLaunchKernelGGL(gemm_mfma_k, dim3(8, 15, 4), blk, 0, stream,
                       YC_bf, YC_bf, KP_DI, Wout_bf, KP_DI, KP_DI/64, 4,
                       (float*)nullptr, (float*)nullptr, 0, (size_t)0,
                       ZP, ZP, 900, PSTR,
                       MROWS, 900, (const float*)nullptr, 1);
    // 10) final reduce + residual + rmsnorm -> d_out
    hipLaunchKernelGGL(rmsnorm_final_k, dim3(MROWS), blk, 0, stream,
                       ZP, PSTR, XS, normf_w, (float*)d_out);
}

// Round 7
// 295.335 us; speedup vs baseline: 7.6183x; 1.0155x over previous
//
#include <hip/hip_runtime.h>
#include <math.h>

typedef unsigned short ushortT;
typedef short short8 __attribute__((ext_vector_type(8)));
typedef float f32x4 __attribute__((ext_vector_type(4)));

#define D_STATE 16
#define D_INNER 1800
#define DT_RANK 57
#define SEQ_L 900
#define MROWS 1800            // 2*900
#define MP 1920               // padded rows
#define KP_DM 960             // K=900 pad
#define KP_DI 1856            // K=1800 pad
#define KP_DT 64              // K=57 pad
#define NCHUNK 45
#define CLEN 20

__device__ __forceinline__ ushortT f2bf(float f) {
    unsigned u = __float_as_uint(f);
    unsigned r = (u + 0x7FFFu + ((u >> 16) & 1u)) >> 16;
    return (ushortT)r;
}
__device__ __forceinline__ float bf2f(ushortT h) {
    return __uint_as_float((unsigned)h << 16);
}
__device__ __forceinline__ float silu_f(float x) { return x / (1.f + __expf(-x)); }
__device__ __forceinline__ float softplus_f(float x) {
    return fmaxf(x, 0.f) + __logf(1.f + __expf(-fabsf(x)));
}

__device__ __forceinline__ void gload_lds16(const ushortT* g, ushortT* l) {
    __builtin_amdgcn_global_load_lds((const __attribute__((address_space(1))) unsigned int*)g,
                                     (__attribute__((address_space(3))) unsigned int*)l,
                                     16, 0, 0);
}

// ---------------- all fp32->bf16 pad conversions in ONE kernel ----------------
__global__ __launch_bounds__(256)
void cvt_all_k(const float* __restrict__ s0, ushortT* __restrict__ d0,   // inp 1800x900
               const float* __restrict__ s1, ushortT* __restrict__ d1,   // W_emb 900x900
               const float* __restrict__ s2, ushortT* __restrict__ d2,   // W_in 3600x900
               const float* __restrict__ s3, ushortT* __restrict__ d3,   // W_xp 89x1800
               const float* __restrict__ s4, ushortT* __restrict__ d4,   // W_dt 1800x57
               const float* __restrict__ s5, ushortT* __restrict__ d5)   // W_out 900x1800
{
    const float* src; ushortT* dst; int M, K, Mp, Kp;
    switch (blockIdx.y) {
      case 0: src=s0; dst=d0; M=1800; K=900;  Mp=1920; Kp=960;  break;
      case 1: src=s1; dst=d1; M=900;  K=900;  Mp=1024; Kp=960;  break;
      case 2: src=s2; dst=d2; M=3600; K=900;  Mp=3712; Kp=960;  break;
      case 3: src=s3; dst=d3; M=89;   K=1800; Mp=128;  Kp=1856; break;
      case 4: src=s4; dst=d4; M=1800; K=57;   Mp=1920; Kp=64;   break;
      default:src=s5; dst=d5; M=900;  K=1800; Mp=1024; Kp=1856; break;
    }
    int t = blockIdx.x * 256 + threadIdx.x;
    int K4 = Kp >> 2;
    if (t >= Mp * K4) return;
    int r = t / K4, c4 = (t - r * K4) * 4;
    ushortT o[4];
#pragma unroll
    for (int e = 0; e < 4; ++e) {
        int c = c4 + e;
        float v = (r < M && c < K) ? src[(size_t)r * K + c] : 0.f;
        o[e] = f2bf(v);
    }
    uint2 pk;
    pk.x = (unsigned)o[0] | ((unsigned)o[1] << 16);
    pk.y = (unsigned)o[2] | ((unsigned)o[3] << 16);
    *(uint2*)(dst + (size_t)r * Kp + c4) = pk;
}

// ---------------- bf16 MFMA GEMM: dbuf LDS + prefetch + counted vmcnt ----------------
// z: dir = z/split, s = z%split.
// mode 0: raw f32 -> C (+s*cstride)
// mode 1: raw bf16 -> Xo (+s*xstride)
// mode 5: softplus(acc+bias) -> bf16 -> Xo
__global__ __launch_bounds__(256)
void gemm_mfma_k(const ushortT* __restrict__ A0, const ushortT* __restrict__ A1, int lda,
                 const ushortT* __restrict__ Bw, int ldb, int nkTotal, int split,
                 float* __restrict__ C0, float* __restrict__ C1, int ldc, size_t cstride,
                 ushortT* __restrict__ X0, ushortT* __restrict__ X1, int ldx, size_t xstride,
                 int M, int N, const float* __restrict__ bias, int mode)
{
    __shared__ ushortT As[2][128 * 64];
    __shared__ ushortT Bs[2][128 * 64];
    int z = blockIdx.z;
    int dir = z / split, s = z % split;
    int per = (nkTotal + split - 1) / split;
    int kt0 = s * per;
    int kcnt = nkTotal - kt0; if (kcnt > per) kcnt = per;
    int ktEnd = kt0 + kcnt;

    const ushortT* A = dir ? A1 : A0;
    float* C = (dir ? C1 : C0);
    ushortT* Xo = (dir ? X1 : X0);
    if (C)  C  += (size_t)s * cstride;
    if (Xo) Xo += (size_t)s * xstride;

    int tid = threadIdx.x;
    int lane = tid & 63, wave = tid >> 6;
    int wr = wave >> 1, wc = wave & 1;
    int m0 = blockIdx.y * 128, n0 = blockIdx.x * 128;

    // per-thread staging coordinates (4 chunks of A, 4 of B; 16B each)
    auto stage = [&](int sb, int kt) {
#pragma unroll
        for (int r = 0; r < 4; ++r) {
            int idx = r * 256 + tid;
            int row = idx >> 3, c8 = (idx & 7) << 3;
            gload_lds16(A + (size_t)(m0 + row) * lda + kt * 64 + c8, &As[sb][idx * 8]);
        }
#pragma unroll
        for (int r = 0; r < 4; ++r) {
            int idx = r * 256 + tid;
            int row = idx >> 3, c8 = (idx & 7) << 3;
            gload_lds16(Bw + (size_t)(n0 + row) * ldb + kt * 64 + c8, &Bs[sb][idx * 8]);
        }
    };

    f32x4 acc[4][4] = {};

    stage(0, kt0);
    for (int t = kt0; t < ktEnd; ++t) {
        int cur = (t - kt0) & 1;
        if (t + 1 < ktEnd) {
            stage(cur ^ 1, t + 1);
            asm volatile("s_waitcnt vmcnt(8)" ::: "memory");   // cur's 8 loads done; next's 8 in flight
        } else {
            asm volatile("s_waitcnt vmcnt(0)" ::: "memory");
        }
        __builtin_amdgcn_s_barrier();
        __builtin_amdgcn_sched_barrier(0);
#pragma unroll
        for (int ks = 0; ks < 2; ++ks) {
            short8 av[4], bv[4];
            int kcol = ks * 32 + (lane >> 4) * 8;
#pragma unroll
            for (int i = 0; i < 4; ++i)
                av[i] = *(const short8*)(&As[cur][(wr * 64 + i * 16 + (lane & 15)) * 64 + kcol]);
#pragma unroll
            for (int j = 0; j < 4; ++j)
                bv[j] = *(const short8*)(&Bs[cur][(wc * 64 + j * 16 + (lane & 15)) * 64 + kcol]);
            // swapped operands: output reg-axis = N (4 consecutive cols per lane)
#pragma unroll
            for (int i = 0; i < 4; ++i)
#pragma unroll
                for (int j = 0; j < 4; ++j)
                    acc[i][j] = __builtin_amdgcn_mfma_f32_16x16x32_bf16(bv[j], av[i], acc[i][j], 0, 0, 0);
        }
        __builtin_amdgcn_sched_barrier(0);
        __builtin_amdgcn_s_barrier();     // all waves done reading cur before it is overwritten
        __builtin_amdgcn_sched_barrier(0);
    }

#pragma unroll
    for (int i = 0; i < 4; ++i) {
        int m = m0 + wr * 64 + i * 16 + (lane & 15);
        if (m >= M) continue;
#pragma unroll
        for (int j = 0; j < 4; ++j) {
            int nb = n0 + wc * 64 + j * 16 + (lane >> 4) * 4;
            if (nb >= N) continue;     // N and nb are multiples of 4
            f32x4 v = acc[i][j];
            if (mode == 5) {
#pragma unroll
                for (int e = 0; e < 4; ++e)
                    v[e] = softplus_f(v[e] + bias[nb + e]);
            }
            if (mode == 1 || mode == 5) {
                unsigned lo, hi;
                asm("v_cvt_pk_bf16_f32 %0, %1, %2" : "=v"(lo) : "v"(v[0]), "v"(v[1]));
                asm("v_cvt_pk_bf16_f32 %0, %1, %2" : "=v"(hi) : "v"(v[2]), "v"(v[3]));
                uint2 pk; pk.x = lo; pk.y = hi;
                *(uint2*)(Xo + (size_t)m * ldx + nb) = pk;
            } else {
                *(f32x4*)(C + (size_t)m * ldc + nb) = v;
            }
        }
    }
}

// ---------------- emb epilogue + rmsnorm (sums 4 bf16 partials) ----------------
__global__ __launch_bounds__(256)
void rmsnorm_emb_k(const ushortT* __restrict__ P, size_t pstride,
                   const float* __restrict__ b_emb, const float* __restrict__ pe,
                   const float* __restrict__ norm_w,
                   float* __restrict__ XS, ushortT* __restrict__ XN, int ldxn)
{
    int row = blockIdx.x;
    int l = (row >= SEQ_L) ? row - SEQ_L : row;
    float vv[4];
    float ssum = 0.f;
#pragma unroll
    for (int k = 0; k < 4; ++k) {
        int c = threadIdx.x + k * 256;
        if (c < 900) {
            size_t i = (size_t)row * 900 + c;
            float a = bf2f(P[i]) + bf2f(P[i + pstride]) + bf2f(P[i + 2 * pstride]) + bf2f(P[i + 3 * pstride]);
            float v = 30.f * (a + b_emb[c]) + pe[(size_t)l * 900 + c];
            vv[k] = v;
            ssum += v * v;
        } else vv[k] = 0.f;
    }
#pragma unroll
    for (int off = 32; off; off >>= 1) ssum += __shfl_down(ssum, off, 64);
    __shared__ float red[4];
    int wv = threadIdx.x >> 6;
    if ((threadIdx.x & 63) == 0) red[wv] = ssum;
    __syncthreads();
    float tot = red[0] + red[1] + red[2] + red[3];
    float scale = rsqrtf(tot / 900.f + 1e-5f);
#pragma unroll
    for (int k = 0; k < 4; ++k) {
        int c = threadIdx.x + k * 256;
        if (c < 900) {
            XS[(size_t)row * 900 + c] = vv[k];
            XN[(size_t)row * ldxn + c] = f2bf(vv[k] * scale * norm_w[c]);
        }
    }
}

// ---------------- final: 4 bf16 partials + residual -> rmsnorm -> out ----------------
__global__ __launch_bounds__(256)
void rmsnorm_final_k(const ushortT* __restrict__ ZP, size_t zstride,
                     const float* __restrict__ XS, const float* __restrict__ w,
                     float* __restrict__ out)
{
    int row = blockIdx.x;
    float vv[4];
    float ssum = 0.f;
#pragma unroll
    for (int k = 0; k < 4; ++k) {
        int c = threadIdx.x + k * 256;
        if (c < 900) {
            size_t i = (size_t)row * 900 + c;
            float v = bf2f(ZP[i]) + bf2f(ZP[i + zstride]) + bf2f(ZP[i + 2 * zstride]) + bf2f(ZP[i + 3 * zstride]) + XS[i];
            vv[k] = v;
            ssum += v * v;
        } else vv[k] = 0.f;
    }
#pragma unroll
    for (int off = 32; off; off >>= 1) ssum += __shfl_down(ssum, off, 64);
    __shared__ float red[4];
    int wv = threadIdx.x >> 6;
    if ((threadIdx.x & 63) == 0) red[wv] = ssum;
    __syncthreads();
    float tot = red[0] + red[1] + red[2] + red[3];
    float scale = rsqrtf(tot / 900.f + 1e-5f);
#pragma unroll
    for (int k = 0; k < 4; ++k) {
        int c = threadIdx.x + k * 256;
        if (c < 900) out[(size_t)row * 900 + c] = vv[k] * scale * w[c];
    }
}

// ---------------- conv (2 channels/thread, sums 2 partials) + silu + G ----------------
__global__ __launch_bounds__(256)
void conv_silu_k(const ushortT* __restrict__ xr0, const ushortT* __restrict__ xr1,
                 const float* __restrict__ w, const float* __restrict__ cb,
                 ushortT* __restrict__ xmc, ushortT* __restrict__ xbc,
                 ushortT* __restrict__ gout)
{
    int t = blockIdx.x * 256 + threadIdx.x;
    if (t >= MROWS * (D_INNER / 2)) return;
    int d0 = (t % (D_INNER / 2)) * 2;
    int row = t / (D_INNER / 2);
    int l = row % SEQ_L;
    float w0[4], w1[4];
#pragma unroll
    for (int k = 0; k < 4; ++k) { w0[k] = w[d0 * 4 + k]; w1[k] = w[d0 * 4 + 4 + k]; }
    int rdp = 1798 - d0;   // pair covers rev-channels for (d0+1, d0)
    float sf0 = cb[d0], sf1 = cb[d0 + 1];
    float sb0 = sf0, sb1 = sf1;
#pragma unroll
    for (int k = 0; k < 4; ++k) {
        int ll = l - 3 + k;
        if (ll < 0) continue;
        size_t ro = (size_t)(row - l + ll) * 3600;
        unsigned f0 = *(const unsigned*)(xr0 + ro + d0);
        unsigned f1 = *(const unsigned*)(xr1 + ro + d0);
        float a0 = bf2f((ushortT)f0) + bf2f((ushortT)f1);
        float a1 = bf2f((ushortT)(f0 >> 16)) + bf2f((ushortT)(f1 >> 16));
        sf0 = fmaf(w0[k], a0, sf0);
        sf1 = fmaf(w1[k], a1, sf1);
        unsigned r0 = *(const unsigned*)(xr0 + ro + rdp);
        unsigned r1 = *(const unsigned*)(xr1 + ro + rdp);
        float b0 = bf2f((ushortT)(r0 >> 16)) + bf2f((ushortT)(r1 >> 16));
        float b1 = bf2f((ushortT)r0) + bf2f((ushortT)r1);
        sb0 = fmaf(w0[k], b0, sb0);
        sb1 = fmaf(w1[k], b1, sb1);
    }
    unsigned om = (unsigned)f2bf(silu_f(sf0)) | ((unsigned)f2bf(silu_f(sf1)) << 16);
    unsigned ob = (unsigned)f2bf(silu_f(sb0)) | ((unsigned)f2bf(silu_f(sb1)) << 16);
    *(unsigned*)(xmc + (size_t)row * KP_DI + d0) = om;
    *(unsigned*)(xbc + (size_t)row * KP_DI + d0) = ob;
    size_t rr = (size_t)row * 3600 + D_INNER + d0;
    unsigned g0 = *(const unsigned*)(xr0 + rr);
    unsigned g1 = *(const unsigned*)(xr1 + rr);
    float ga = silu_f(bf2f((ushortT)g0) + bf2f((ushortT)g1));
    float gb = silu_f(bf2f((ushortT)(g0 >> 16)) + bf2f((ushortT)(g1 >> 16)));
    *(unsigned*)(gout + (size_t)row * D_INNER + d0) = (unsigned)f2bf(ga) | ((unsigned)f2bf(gb) << 16);
}

// ---------------- xp reduce: 8 f32 partials -> compact BC f32 + bf16 dt-input ----------------
__global__ __launch_bounds__(256)
void xp_reduce_k(const float* __restrict__ XPp, size_t pstride,
                 float* __restrict__ XDC, ushortT* __restrict__ XDMb, ushortT* __restrict__ XDBb)
{
    int t = blockIdx.x * 256 + threadIdx.x;
    if (t >= 2 * MROWS * 96) return;
    int dir = t / (MROWS * 96);
    int rem = t - dir * (MROWS * 96);
    int row = rem / 96, c = rem - row * 96;
    const float* basep = XPp + (size_t)dir * 8 * pstride + (size_t)row * 96 + c;
    float s = 0.f;
#pragma unroll
    for (int p = 0; p < 8; ++p) s += basep[p * pstride];
    ushortT* xdb = dir ? XDBb : XDMb;
    if (c < DT_RANK)           xdb[(size_t)row * KP_DT + c] = f2bf(s);
    else if (c < KP_DT)        xdb[(size_t)row * KP_DT + c] = 0;
    if (c >= DT_RANK && c < DT_RANK + 2 * D_STATE)
        XDC[((size_t)dir * MROWS + row) * 32 + (c - DT_RANK)] = s;
}

// ---------------- scan level 1 (delta bf16 in, HL bf16 out) ----------------
__global__ __launch_bounds__(256)
void scan_l1_k(const ushortT* __restrict__ DMb, const ushortT* __restrict__ DBb,
               const ushortT* __restrict__ Um, const ushortT* __restrict__ Ub,
               const float* __restrict__ XDC, const float* __restrict__ A_log,
               ushortT* __restrict__ HL, float* __restrict__ SD)
{
    int d = blockIdx.x * 256 + threadIdx.x;
    if (d >= D_INNER) return;
    int c = blockIdx.y, zz = blockIdx.z;
    int b = zz >> 1, dir = zz & 1;
    const ushortT* DL = dir ? DBb : DMb;
    const ushortT* U = dir ? Ub : Um;
    const float* XD = XDC + (size_t)dir * MROWS * 32;
    float Aa[D_STATE];
#pragma unroll
    for (int n = 0; n < D_STATE; ++n) Aa[n] = -__expf(A_log[d * D_STATE + n]);
    float h[D_STATE] = {};
    float S = 0.f;
    int l0 = c * CLEN;
    for (int i = 0; i < CLEN; ++i) {
        size_t rowi = (size_t)b * SEQ_L + l0 + i;
        float delta = bf2f(DL[rowi * D_INNER + d]);
        float u = bf2f(U[rowi * KP_DI + d]);
        const float* bc = XD + rowi * 32;
        float du = delta * u;
        S += delta;
#pragma unroll
        for (int n = 0; n < D_STATE; ++n)
            h[n] = fmaf(__expf(delta * Aa[n]), h[n], du * bc[n]);
    }
    ushortT* hp = HL + ((size_t)(zz * NCHUNK + c) * D_INNER + d) * D_STATE;
    unsigned pk[8];
#pragma unroll
    for (int q = 0; q < 8; ++q)
        asm("v_cvt_pk_bf16_f32 %0, %1, %2" : "=v"(pk[q]) : "v"(h[2*q]), "v"(h[2*q+1]));
    uint4 lo4; lo4.x = pk[0]; lo4.y = pk[1]; lo4.z = pk[2]; lo4.w = pk[3];
    uint4 hi4; hi4.x = pk[4]; hi4.y = pk[5]; hi4.z = pk[6]; hi4.w = pk[7];
    *(uint4*)(hp) = lo4;
    *(uint4*)(hp + 8) = hi4;
    SD[(size_t)(zz * NCHUNK + c) * D_INNER + d] = S;
}

// ---------------- scan level 2: chunk combine (in place: HL[c] <- incoming h0) ----------------
__global__ __launch_bounds__(256)
void scan_l2_k(ushortT* __restrict__ HL, const float* __restrict__ SD,
               const float* __restrict__ A_log)
{
    int t = blockIdx.x * 256 + threadIdx.x;
    if (t >= 4 * D_INNER * D_STATE) return;
    int n = t & 15;
    int d = (t >> 4) % D_INNER;
    int zz = t / (D_INNER * D_STATE);
    float Aa = -__expf(A_log[d * D_STATE + n]);
    float h0 = 0.f;
    for (int c = 0; c < NCHUNK; ++c) {
        size_t ih = ((size_t)(zz * NCHUNK + c) * D_INNER + d) * D_STATE + n;
        float hl = bf2f(HL[ih]);
        float T = __expf(Aa * SD[(size_t)(zz * NCHUNK + c) * D_INNER + d]);
        HL[ih] = f2bf(h0);
        h0 = fmaf(T, h0, hl);
    }
}

// ---------------- scan level 3 + gate fused: both dirs per thread, writes YC bf16 ----------------
__global__ __launch_bounds__(256)
void scan3_gate_k(const ushortT* __restrict__ DMb, const ushortT* __restrict__ DBb,
                  const ushortT* __restrict__ Um, const ushortT* __restrict__ Ub,
                  const float* __restrict__ XDC, const float* __restrict__ A_log,
                  const float* __restrict__ Dv, const ushortT* __restrict__ HL,
                  const ushortT* __restrict__ G, ushortT* __restrict__ YC)
{
    int d = blockIdx.x * 256 + threadIdx.x;
    if (d >= D_INNER) return;
    int c = blockIdx.y, b = blockIdx.z;
    int rd = D_INNER - 1 - d;
    float Aa0[D_STATE], Aa1[D_STATE], h0[D_STATE], h1[D_STATE];
#pragma unroll
    for (int n = 0; n < D_STATE; ++n) Aa0[n] = -__expf(A_log[d * D_STATE + n]);
#pragma unroll
    for (int n = 0; n < D_STATE; ++n) Aa1[n] = -__expf(A_log[rd * D_STATE + n]);
    const ushortT* hp0 = HL + ((size_t)((b * 2) * NCHUNK + c) * D_INNER + d) * D_STATE;
    const ushortT* hp1 = HL + ((size_t)((b * 2 + 1) * NCHUNK + c) * D_INNER + rd) * D_STATE;
    {
        uint4 a0 = *(const uint4*)(hp0);
        uint4 a1 = *(const uint4*)(hp0 + 8);
        unsigned ww[8] = {a0.x, a0.y, a0.z, a0.w, a1.x, a1.y, a1.z, a1.w};
#pragma unroll
        for (int q = 0; q < 8; ++q) {
            h0[2*q]   = bf2f((ushortT)ww[q]);
            h0[2*q+1] = bf2f((ushortT)(ww[q] >> 16));
        }
        uint4 b0 = *(const uint4*)(hp1);
        uint4 b1 = *(const uint4*)(hp1 + 8);
        unsigned vv[8] = {b0.x, b0.y, b0.z, b0.w, b1.x, b1.y, b1.z, b1.w};
#pragma unroll
        for (int q = 0; q < 8; ++q) {
            h1[2*q]   = bf2f((ushortT)vv[q]);
            h1[2*q+1] = bf2f((ushortT)(vv[q] >> 16));
        }
    }
    float Dd0 = Dv[d], Dd1 = Dv[rd];
    const float* XD0 = XDC;
    const float* XD1 = XDC + (size_t)MROWS * 32;
    int l0 = c * CLEN;
    for (int i = 0; i < CLEN; ++i) {
        size_t rowi = (size_t)b * SEQ_L + l0 + i;
        float delta0 = bf2f(DMb[rowi * D_INNER + d]);
        float u0 = bf2f(Um[rowi * KP_DI + d]);
        const float* bc0 = XD0 + rowi * 32;
        float du0 = delta0 * u0;
        float acc0 = u0 * Dd0;
#pragma unroll
        for (int n = 0; n < D_STATE; ++n) {
            h0[n] = fmaf(__expf(delta0 * Aa0[n]), h0[n], du0 * bc0[n]);
            acc0 = fmaf(h0[n], bc0[D_STATE + n], acc0);
        }
        float delta1 = bf2f(DBb[rowi * D_INNER + rd]);
        float u1 = bf2f(Ub[rowi * KP_DI + rd]);
        const float* bc1 = XD1 + rowi * 32;
        float du1 = delta1 * u1;
        float acc1 = u1 * Dd1;
#pragma unroll
        for (int n = 0; n < D_STATE; ++n) {
            h1[n] = fmaf(__expf(delta1 * Aa1[n]), h1[n], du1 * bc1[n]);
            acc1 = fmaf(h1[n], bc1[D_STATE + n], acc1);
        }
        float g = bf2f(G[rowi * D_INNER + d]);
        YC[rowi * KP_DI + d] = f2bf((acc0 + acc1) * g);
    }
}

extern "C" void kernel_launch(void* const* d_in, const int* in_sizes, int n_in,
                              void* d_out, int out_size, void* d_ws, size_t ws_size,
                              hipStream_t stream)
{
    const float* inp    = (const float*)d_in[0];
    const float* W_emb  = (const float*)d_in[1];
    const float* b_emb  = (const float*)d_in[2];
    const float* norm_w = (const float*)d_in[3];
    const float* W_in   = (const float*)d_in[4];
    const float* conv_w = (const float*)d_in[5];
    const float* conv_b = (const float*)d_in[6];
    const float* W_xp   = (const float*)d_in[7];
    const float* W_dt   = (const float*)d_in[8];
    const float* b_dt   = (const float*)d_in[9];
    const float* A_log  = (const float*)d_in[10];
    const float* Dv     = (const float*)d_in[11];
    const float* W_out  = (const float*)d_in[12];
    const float* normf_w= (const float*)d_in[13];
    const float* pe     = (const float*)d_in[14];

    char* base = (char*)d_ws;
    size_t off = 0;
    auto alloc = [&](size_t bytes) { char* p = base + off; off += (bytes + 255) & ~(size_t)255; return p; };

    float*   XS      = (float*)alloc(6480000);        // residual f32, lives to end
    // arena1: XPp (11.06MB, xp partials) -> HL bf16 (10.37MB)+SD(1.296MB) -> Wout overlaps HL after scan
    char*    arena1  = alloc(22032000);
    float*   XPp     = (float*)arena1;
    ushortT* HL      = (ushortT*)arena1;              // 4 x 45 x 1800 x 16 bf16 = 10.368 MB
    float*   SD      = (float*)(arena1 + 10368000);   // 4 x 45 x 1800 f32 = 1.296 MB
    ushortT* inp_bf  = (ushortT*)alloc(3686400);      // 1920x960; later start of YC
    ushortT* XN_bf   = (ushortT*)alloc(3686400);      // contiguous after inp_bf (YC spillover)
    ushortT* Wemb_bf = (ushortT*)alloc(1966080);      // 1024x960; after emb: XDC+XDM_bf+XDB_bf
    ushortT* Win_bf  = (ushortT*)alloc(7127040);      // 3712x960; after in-proj: XMC_bf (1920x1856)
    ushortT* Wxp_bf  = (ushortT*)alloc(475136);       // 128x1856
    ushortT* Wdt_bf  = (ushortT*)alloc(245760);       // 1920x64
    ushortT* Wout_bf = (ushortT*)alloc(3801088);      // 1024x1856
    ushortT* XBC_bf  = (ushortT*)alloc(7127040);      // 1920x1856
    // arena2 (25.92MB): Pemb(bf16 x4) -> XR0/XR1 -> DMb/DBb(bf16) -> ZP(bf16 x4)
    char*    arena2  = alloc(25920000);
    ushortT* Pemb    = (ushortT*)arena2;
    ushortT* XR0     = (ushortT*)arena2;
    ushortT* XR1     = XR0 + (size_t)MROWS * 3600;
    ushortT* DMb     = (ushortT*)arena2;
    ushortT* DBb     = DMb + (size_t)MROWS * D_INNER;
    ushortT* ZP      = (ushortT*)arena2;
    ushortT* G_bf    = (ushortT*)alloc(6480000);      // 1800x1800 bf16

    // aliases into dead regions
    float*   XDC     = (float*)Wemb_bf;               // 2x1800x32 f32 = 460800 B
    ushortT* XDM_bf  = (ushortT*)((char*)Wemb_bf + 460800);   // 1920x64 bf16
    ushortT* XDB_bf  = (ushortT*)((char*)Wemb_bf + 706560);
    ushortT* XMC_bf  = Win_bf;                        // 1920x1856 bf16, exact fit
    ushortT* YC_bf   = inp_bf;                        // 1920x1856 spans inp_bf+XN_bf (7.13<=7.37MB)

    dim3 blk(256);
    auto cdiv = [](int a, int b) { return (a + b - 1) / b; };
    const size_t PSTR  = 1620000;   // 1800*900 elements (bf16 partial stride)
    const size_t XPSTR = 172800;    // 1800*96 f32 partial stride
    const size_t XRSTR = (size_t)MROWS * 3600;

    // 0) all conversions
    hipLaunchKernelGGL(cvt_all_k, dim3(3480, 6), blk, 0, stream,
                       inp, inp_bf, W_emb, Wemb_bf, W_in, Win_bf,
                       W_xp, Wxp_bf, W_dt, Wdt_bf, W_out, Wout_bf);
    // 1) embedding GEMM split-4 -> Pemb (bf16 partials)
    hipLaunchKernelGGL(gemm_mfma_k, dim3(8, 15, 4), blk, 0, stream,
                       inp_bf, inp_bf, KP_DM, Wemb_bf, KP_DM, KP_DM/64, 4,
                       (float*)nullptr, (float*)nullptr, 0, (size_t)0,
                       Pemb, Pemb, 900, PSTR,
                       MROWS, 900, (const float*)nullptr, 1);
    // 2) emb epilogue + rmsnorm -> XS, XN_bf
    hipLaunchKernelGGL(rmsnorm_emb_k, dim3(MROWS), blk, 0, stream,
                       Pemb, PSTR, b_emb, pe, norm_w, XS, XN_bf, KP_DM);
    // 3) in-proj split-2 -> XR0/XR1 (bf16 partials)
    hipLaunchKernelGGL(gemm_mfma_k, dim3(29, 15, 2), blk, 0, stream,
                       XN_bf, XN_bf, KP_DM, Win_bf, KP_DM, KP_DM/64, 2,
                       (float*)nullptr, (float*)nullptr, 0, (size_t)0,
                       XR0, XR0, 3600, XRSTR,
                       MROWS, 3600, (const float*)nullptr, 1);
    // 4) conv + silu + G
    hipLaunchKernelGGL(conv_silu_k, dim3(cdiv(MROWS * (D_INNER/2), 256)), blk, 0, stream,
                       XR0, XR1, conv_w, conv_b, XMC_bf, XBC_bf, G_bf);
    // 5) x-proj split-8 both dirs -> XPp (f32 partials)
    hipLaunchKernelGGL(gemm_mfma_k, dim3(1, 15, 16), blk, 0, stream,
                       XMC_bf, XBC_bf, KP_DI, Wxp_bf, KP_DI, KP_DI/64, 8,
                       XPp, XPp + 8 * XPSTR, 96, XPSTR,
                       (ushortT*)nullptr, (ushortT*)nullptr, 0, (size_t)0,
                       MROWS, 96, (const float*)nullptr, 0);
    // 5b) xp reduce -> XDC (compact BC) + bf16 dt inputs
    hipLaunchKernelGGL(xp_reduce_k, dim3(cdiv(2 * MROWS * 96, 256)), blk, 0, stream,
                       XPp, XPSTR, XDC, XDM_bf, XDB_bf);
    // 6) dt GEMM both dirs + fast-softplus -> DMb, DBb (bf16)
    hipLaunchKernelGGL(gemm_mfma_k, dim3(15, 15, 2), blk, 0, stream,
                       XDM_bf, XDB_bf, KP_DT, Wdt_bf, KP_DT, 1, 1,
                       (float*)nullptr, (float*)nullptr, 0, (size_t)0,
                       DMb, DBb, D_INNER, (size_t)0,
                       MROWS, D_INNER, b_dt, 5);
    // 7) chunked scan (HL bf16)
    hipLaunchKernelGGL(scan_l1_k, dim3(cdiv(D_INNER, 256), NCHUNK, 4), blk, 0, stream,
                       DMb, DBb, XMC_bf, XBC_bf, XDC, A_log, HL, SD);
    hipLaunchKernelGGL(scan_l2_k, dim3(cdiv(4 * D_INNER * D_STATE, 256)), blk, 0, stream, HL, SD, A_log);
    // 7c) level 3 + gate fused -> YC bf16
    hipLaunchKernelGGL(scan3_gate_k, dim3(cdiv(D_INNER, 256), NCHUNK, 2), blk, 0, stream,
                       DMb, DBb, XMC_bf, XBC_bf, XDC, A_log, Dv, HL, G_bf, YC_bf);
    // 9) out-proj split-4 -> ZP (bf16 partials)
    hipLaunchKernelGGL(gemm_mfma_k, dim3(8, 15, 4), blk, 0, stream,
                       YC_bf, YC_bf, KP_DI, Wout_bf, KP_DI, KP_DI/64, 4,
                       (float*)nullptr, (float*)nullptr, 0, (size_t)0,
                       ZP, ZP, 900, PSTR,
                       MROWS, 900, (const float*)nullptr, 1);
    // 10) final reduce + residual + rmsnorm -> d_out
    hipLaunchKernelGGL(rmsnorm_final_k, dim3(MROWS), blk, 0, stream,
                       ZP, PSTR, XS, normf_w, (float*)d_out);
}

// Round 8
// 284.652 us; speedup vs baseline: 7.9042x; 1.0375x over previous
//
#include <hip/hip_runtime.h>
#include <math.h>

typedef unsigned short ushortT;
typedef short short8 __attribute__((ext_vector_type(8)));
typedef float f32x4 __attribute__((ext_vector_type(4)));

#define D_STATE 16
#define D_INNER 1800
#define DT_RANK 57
#define SEQ_L 900
#define MROWS 1800            // 2*900
#define MP 1920               // padded rows
#define KP_DM 960             // K=900 pad
#define KP_DI 1856            // K=1800 pad
#define KP_DT 64              // K=57 pad
#define NCHUNK 45
#define CLEN 20

__device__ __forceinline__ ushortT f2bf(float f) {
    unsigned u = __float_as_uint(f);
    unsigned r = (u + 0x7FFFu + ((u >> 16) & 1u)) >> 16;
    return (ushortT)r;
}
__device__ __forceinline__ float bf2f(ushortT h) {
    return __uint_as_float((unsigned)h << 16);
}
__device__ __forceinline__ float silu_f(float x) { return x / (1.f + __expf(-x)); }
__device__ __forceinline__ float softplus_f(float x) {
    return fmaxf(x, 0.f) + __logf(1.f + __expf(-fabsf(x)));
}

__device__ __forceinline__ void gload_lds16(const ushortT* g, ushortT* l) {
    __builtin_amdgcn_global_load_lds((const __attribute__((address_space(1))) unsigned int*)g,
                                     (__attribute__((address_space(3))) unsigned int*)l,
                                     16, 0, 0);
}

// ---------------- all fp32->bf16 pad conversions in ONE kernel ----------------
__global__ __launch_bounds__(256)
void cvt_all_k(const float* __restrict__ s0, ushortT* __restrict__ d0,   // inp 1800x900
               const float* __restrict__ s1, ushortT* __restrict__ d1,   // W_emb 900x900
               const float* __restrict__ s2, ushortT* __restrict__ d2,   // W_in 3600x900
               const float* __restrict__ s3, ushortT* __restrict__ d3,   // W_xp 89x1800
               const float* __restrict__ s4, ushortT* __restrict__ d4,   // W_dt 1800x57
               const float* __restrict__ s5, ushortT* __restrict__ d5)   // W_out 900x1800
{
    const float* src; ushortT* dst; int M, K, Mp, Kp;
    switch (blockIdx.y) {
      case 0: src=s0; dst=d0; M=1800; K=900;  Mp=1920; Kp=960;  break;
      case 1: src=s1; dst=d1; M=900;  K=900;  Mp=1024; Kp=960;  break;
      case 2: src=s2; dst=d2; M=3600; K=900;  Mp=3712; Kp=960;  break;
      case 3: src=s3; dst=d3; M=89;   K=1800; Mp=128;  Kp=1856; break;
      case 4: src=s4; dst=d4; M=1800; K=57;   Mp=1920; Kp=64;   break;
      default:src=s5; dst=d5; M=900;  K=1800; Mp=1024; Kp=1856; break;
    }
    int t = blockIdx.x * 256 + threadIdx.x;
    int K4 = Kp >> 2;
    if (t >= Mp * K4) return;
    int r = t / K4, c4 = (t - r * K4) * 4;
    ushortT o[4];
#pragma unroll
    for (int e = 0; e < 4; ++e) {
        int c = c4 + e;
        float v = (r < M && c < K) ? src[(size_t)r * K + c] : 0.f;
        o[e] = f2bf(v);
    }
    uint2 pk;
    pk.x = (unsigned)o[0] | ((unsigned)o[1] << 16);
    pk.y = (unsigned)o[2] | ((unsigned)o[3] << 16);
    *(uint2*)(dst + (size_t)r * Kp + c4) = pk;
}

// ---------------- bf16 MFMA GEMM: dbuf + prefetch + counted vmcnt + T1/T2 swizzles ----------------
// z: dir = z/split, s = z%split.
// mode 0: raw f32 -> C (+s*cstride)
// mode 1: raw bf16 -> Xo (+s*xstride)
// mode 5: softplus(acc+bias) -> bf16 -> Xo
__global__ __launch_bounds__(256)
void gemm_mfma_k(const ushortT* __restrict__ A0, const ushortT* __restrict__ A1, int lda,
                 const ushortT* __restrict__ Bw, int ldb, int nkTotal, int split,
                 float* __restrict__ C0, float* __restrict__ C1, int ldc, size_t cstride,
                 ushortT* __restrict__ X0, ushortT* __restrict__ X1, int ldx, size_t xstride,
                 int M, int N, const float* __restrict__ bias, int mode)
{
    __shared__ ushortT As[2][128 * 64];
    __shared__ ushortT Bs[2][128 * 64];

    // T1: bijective XCD-aware remap (m204) of the flattened block id.
    int gx = gridDim.x, gy = gridDim.y;
    int nwg = gx * gy * gridDim.z;
    int orig = (blockIdx.z * gy + blockIdx.y) * gx + blockIdx.x;
    int q8 = nwg >> 3, r8 = nwg & 7;
    int xcd = orig & 7, i8 = orig >> 3;
    int wg = (xcd < r8 ? xcd * (q8 + 1) : r8 * (q8 + 1) + (xcd - r8) * q8) + i8;
    int bx = wg % gx; int tmp = wg / gx; int by = tmp % gy; int bz = tmp / gy;

    int dir = bz / split, s = bz % split;
    int per = (nkTotal + split - 1) / split;
    int kt0 = s * per;
    int kcnt = nkTotal - kt0; if (kcnt > per) kcnt = per;
    int ktEnd = kt0 + kcnt;

    const ushortT* A = dir ? A1 : A0;
    float* C = (dir ? C1 : C0);
    ushortT* Xo = (dir ? X1 : X0);
    if (C)  C  += (size_t)s * cstride;
    if (Xo) Xo += (size_t)s * xstride;

    int tid = threadIdx.x;
    int lane = tid & 63, wave = tid >> 6;
    int wr = wave >> 1, wc = wave & 1;
    int m0 = by * 128, n0 = bx * 128;

    // T2: pre-swizzled global source column. LDS stays linear (rule #21);
    // LDS slot (row, c8) receives global column c8 ^ ((row&7)<<3).
    // row&7 == (tid>>3)&7 and c8 == (tid&7)<<3 are r-invariant -> csw is thread-constant.
    int csw = ((((tid >> 3) & 7) ^ (tid & 7)) << 3);
    auto stage = [&](int sb, int kt) {
#pragma unroll
        for (int r = 0; r < 4; ++r) {
            int idx = r * 256 + tid;
            int row = idx >> 3;
            gload_lds16(A + (size_t)(m0 + row) * lda + kt * 64 + csw, &As[sb][idx * 8]);
        }
#pragma unroll
        for (int r = 0; r < 4; ++r) {
            int idx = r * 256 + tid;
            int row = idx >> 3;
            gload_lds16(Bw + (size_t)(n0 + row) * ldb + kt * 64 + csw, &Bs[sb][idx * 8]);
        }
    };

    f32x4 acc[4][4] = {};
    // read-side swizzle mask: rows used are wr*64+i*16+(lane&15) -> row&7 == lane&7
    int rmask = (lane & 7) << 3;

    stage(0, kt0);
    for (int t = kt0; t < ktEnd; ++t) {
        int cur = (t - kt0) & 1;
        if (t + 1 < ktEnd) {
            stage(cur ^ 1, t + 1);
            asm volatile("s_waitcnt vmcnt(8)" ::: "memory");   // cur's 8 loads done; next's in flight
        } else {
            asm volatile("s_waitcnt vmcnt(0)" ::: "memory");
        }
        __builtin_amdgcn_s_barrier();
        __builtin_amdgcn_sched_barrier(0);
#pragma unroll
        for (int ks = 0; ks < 2; ++ks) {
            short8 av[4], bv[4];
            int kcol = (ks * 32 + (lane >> 4) * 8) ^ rmask;
#pragma unroll
            for (int i = 0; i < 4; ++i)
                av[i] = *(const short8*)(&As[cur][(wr * 64 + i * 16 + (lane & 15)) * 64 + kcol]);
#pragma unroll
            for (int j = 0; j < 4; ++j)
                bv[j] = *(const short8*)(&Bs[cur][(wc * 64 + j * 16 + (lane & 15)) * 64 + kcol]);
            // swapped operands: output reg-axis = N (4 consecutive cols per lane)
#pragma unroll
            for (int i = 0; i < 4; ++i)
#pragma unroll
                for (int j = 0; j < 4; ++j)
                    acc[i][j] = __builtin_amdgcn_mfma_f32_16x16x32_bf16(bv[j], av[i], acc[i][j], 0, 0, 0);
        }
        __builtin_amdgcn_sched_barrier(0);
        __builtin_amdgcn_s_barrier();     // all waves done reading cur before overwrite
        __builtin_amdgcn_sched_barrier(0);
    }

#pragma unroll
    for (int i = 0; i < 4; ++i) {
        int m = m0 + wr * 64 + i * 16 + (lane & 15);
        if (m >= M) continue;
#pragma unroll
        for (int j = 0; j < 4; ++j) {
            int nb = n0 + wc * 64 + j * 16 + (lane >> 4) * 4;
            if (nb >= N) continue;     // N and nb are multiples of 4
            f32x4 v = acc[i][j];
            if (mode == 5) {
#pragma unroll
                for (int e = 0; e < 4; ++e)
                    v[e] = softplus_f(v[e] + bias[nb + e]);
            }
            if (mode == 1 || mode == 5) {
                unsigned lo, hi;
                asm("v_cvt_pk_bf16_f32 %0, %1, %2" : "=v"(lo) : "v"(v[0]), "v"(v[1]));
                asm("v_cvt_pk_bf16_f32 %0, %1, %2" : "=v"(hi) : "v"(v[2]), "v"(v[3]));
                uint2 pk; pk.x = lo; pk.y = hi;
                *(uint2*)(Xo + (size_t)m * ldx + nb) = pk;
            } else {
                *(f32x4*)(C + (size_t)m * ldc + nb) = v;
            }
        }
    }
}

// ---------------- emb epilogue + rmsnorm (sums 4 bf16 partials) ----------------
__global__ __launch_bounds__(256)
void rmsnorm_emb_k(const ushortT* __restrict__ P, size_t pstride,
                   const float* __restrict__ b_emb, const float* __restrict__ pe,
                   const float* __restrict__ norm_w,
                   float* __restrict__ XS, ushortT* __restrict__ XN, int ldxn)
{
    int row = blockIdx.x;
    int l = (row >= SEQ_L) ? row - SEQ_L : row;
    float vv[4];
    float ssum = 0.f;
#pragma unroll
    for (int k = 0; k < 4; ++k) {
        int c = threadIdx.x + k * 256;
        if (c < 900) {
            size_t i = (size_t)row * 900 + c;
            float a = bf2f(P[i]) + bf2f(P[i + pstride]) + bf2f(P[i + 2 * pstride]) + bf2f(P[i + 3 * pstride]);
            float v = 30.f * (a + b_emb[c]) + pe[(size_t)l * 900 + c];
            vv[k] = v;
            ssum += v * v;
        } else vv[k] = 0.f;
    }
#pragma unroll
    for (int off = 32; off; off >>= 1) ssum += __shfl_down(ssum, off, 64);
    __shared__ float red[4];
    int wv = threadIdx.x >> 6;
    if ((threadIdx.x & 63) == 0) red[wv] = ssum;
    __syncthreads();
    float tot = red[0] + red[1] + red[2] + red[3];
    float scale = rsqrtf(tot / 900.f + 1e-5f);
#pragma unroll
    for (int k = 0; k < 4; ++k) {
        int c = threadIdx.x + k * 256;
        if (c < 900) {
            XS[(size_t)row * 900 + c] = vv[k];
            XN[(size_t)row * ldxn + c] = f2bf(vv[k] * scale * norm_w[c]);
        }
    }
}

// ---------------- final: 4 bf16 partials + residual -> rmsnorm -> out ----------------
__global__ __launch_bounds__(256)
void rmsnorm_final_k(const ushortT* __restrict__ ZP, size_t zstride,
                     const float* __restrict__ XS, const float* __restrict__ w,
                     float* __restrict__ out)
{
    int row = blockIdx.x;
    float vv[4];
    float ssum = 0.f;
#pragma unroll
    for (int k = 0; k < 4; ++k) {
        int c = threadIdx.x + k * 256;
        if (c < 900) {
            size_t i = (size_t)row * 900 + c;
            float v = bf2f(ZP[i]) + bf2f(ZP[i + zstride]) + bf2f(ZP[i + 2 * zstride]) + bf2f(ZP[i + 3 * zstride]) + XS[i];
            vv[k] = v;
            ssum += v * v;
        } else vv[k] = 0.f;
    }
#pragma unroll
    for (int off = 32; off; off >>= 1) ssum += __shfl_down(ssum, off, 64);
    __shared__ float red[4];
    int wv = threadIdx.x >> 6;
    if ((threadIdx.x & 63) == 0) red[wv] = ssum;
    __syncthreads();
    float tot = red[0] + red[1] + red[2] + red[3];
    float scale = rsqrtf(tot / 900.f + 1e-5f);
#pragma unroll
    for (int k = 0; k < 4; ++k) {
        int c = threadIdx.x + k * 256;
        if (c < 900) out[(size_t)row * 900 + c] = vv[k] * scale * w[c];
    }
}

// ---------------- conv (2 channels/thread, sums 2 partials) + silu + G ----------------
__global__ __launch_bounds__(256)
void conv_silu_k(const ushortT* __restrict__ xr0, const ushortT* __restrict__ xr1,
                 const float* __restrict__ w, const float* __restrict__ cb,
                 ushortT* __restrict__ xmc, ushortT* __restrict__ xbc,
                 ushortT* __restrict__ gout)
{
    int t = blockIdx.x * 256 + threadIdx.x;
    if (t >= MROWS * (D_INNER / 2)) return;
    int d0 = (t % (D_INNER / 2)) * 2;
    int row = t / (D_INNER / 2);
    int l = row % SEQ_L;
    float w0[4], w1[4];
#pragma unroll
    for (int k = 0; k < 4; ++k) { w0[k] = w[d0 * 4 + k]; w1[k] = w[d0 * 4 + 4 + k]; }
    int rdp = 1798 - d0;   // pair covers rev-channels for (d0+1, d0)
    float sf0 = cb[d0], sf1 = cb[d0 + 1];
    float sb0 = sf0, sb1 = sf1;
#pragma unroll
    for (int k = 0; k < 4; ++k) {
        int ll = l - 3 + k;
        if (ll < 0) continue;
        size_t ro = (size_t)(row - l + ll) * 3600;
        unsigned f0 = *(const unsigned*)(xr0 + ro + d0);
        unsigned f1 = *(const unsigned*)(xr1 + ro + d0);
        float a0 = bf2f((ushortT)f0) + bf2f((ushortT)f1);
        float a1 = bf2f((ushortT)(f0 >> 16)) + bf2f((ushortT)(f1 >> 16));
        sf0 = fmaf(w0[k], a0, sf0);
        sf1 = fmaf(w1[k], a1, sf1);
        unsigned r0 = *(const unsigned*)(xr0 + ro + rdp);
        unsigned r1 = *(const unsigned*)(xr1 + ro + rdp);
        float b0 = bf2f((ushortT)(r0 >> 16)) + bf2f((ushortT)(r1 >> 16));
        float b1 = bf2f((ushortT)r0) + bf2f((ushortT)r1);
        sb0 = fmaf(w0[k], b0, sb0);
        sb1 = fmaf(w1[k], b1, sb1);
    }
    unsigned om = (unsigned)f2bf(silu_f(sf0)) | ((unsigned)f2bf(silu_f(sf1)) << 16);
    unsigned ob = (unsigned)f2bf(silu_f(sb0)) | ((unsigned)f2bf(silu_f(sb1)) << 16);
    *(unsigned*)(xmc + (size_t)row * KP_DI + d0) = om;
    *(unsigned*)(xbc + (size_t)row * KP_DI + d0) = ob;
    size_t rr = (size_t)row * 3600 + D_INNER + d0;
    unsigned g0 = *(const unsigned*)(xr0 + rr);
    unsigned g1 = *(const unsigned*)(xr1 + rr);
    float ga = silu_f(bf2f((ushortT)g0) + bf2f((ushortT)g1));
    float gb = silu_f(bf2f((ushortT)(g0 >> 16)) + bf2f((ushortT)(g1 >> 16)));
    *(unsigned*)(gout + (size_t)row * D_INNER + d0) = (unsigned)f2bf(ga) | ((unsigned)f2bf(gb) << 16);
}

// ---------------- xp reduce: 8 f32 partials -> compact BC f32 + bf16 dt-input ----------------
__global__ __launch_bounds__(256)
void xp_reduce_k(const float* __restrict__ XPp, size_t pstride,
                 float* __restrict__ XDC, ushortT* __restrict__ XDMb, ushortT* __restrict__ XDBb)
{
    int t = blockIdx.x * 256 + threadIdx.x;
    if (t >= 2 * MROWS * 96) return;
    int dir = t / (MROWS * 96);
    int rem = t - dir * (MROWS * 96);
    int row = rem / 96, c = rem - row * 96;
    const float* basep = XPp + (size_t)dir * 8 * pstride + (size_t)row * 96 + c;
    float s = 0.f;
#pragma unroll
    for (int p = 0; p < 8; ++p) s += basep[p * pstride];
    ushortT* xdb = dir ? XDBb : XDMb;
    if (c < DT_RANK)           xdb[(size_t)row * KP_DT + c] = f2bf(s);
    else if (c < KP_DT)        xdb[(size_t)row * KP_DT + c] = 0;
    if (c >= DT_RANK && c < DT_RANK + 2 * D_STATE)
        XDC[((size_t)dir * MROWS + row) * 32 + (c - DT_RANK)] = s;
}

// ---------------- scan level 1 (delta bf16 in, HL bf16 out) ----------------
__global__ __launch_bounds__(256)
void scan_l1_k(const ushortT* __restrict__ DMb, const ushortT* __restrict__ DBb,
               const ushortT* __restrict__ Um, const ushortT* __restrict__ Ub,
               const float* __restrict__ XDC, const float* __restrict__ A_log,
               ushortT* __restrict__ HL, float* __restrict__ SD)
{
    int d = blockIdx.x * 256 + threadIdx.x;
    if (d >= D_INNER) return;
    int c = blockIdx.y, zz = blockIdx.z;
    int b = zz >> 1, dir = zz & 1;
    const ushortT* DL = dir ? DBb : DMb;
    const ushortT* U = dir ? Ub : Um;
    const float* XD = XDC + (size_t)dir * MROWS * 32;
    float Aa[D_STATE];
#pragma unroll
    for (int n = 0; n < D_STATE; ++n) Aa[n] = -__expf(A_log[d * D_STATE + n]);
    float h[D_STATE] = {};
    float S = 0.f;
    int l0 = c * CLEN;
    for (int i = 0; i < CLEN; ++i) {
        size_t rowi = (size_t)b * SEQ_L + l0 + i;
        float delta = bf2f(DL[rowi * D_INNER + d]);
        float u = bf2f(U[rowi * KP_DI + d]);
        const float* bc = XD + rowi * 32;
        float du = delta * u;
        S += delta;
#pragma unroll
        for (int n = 0; n < D_STATE; ++n)
            h[n] = fmaf(__expf(delta * Aa[n]), h[n], du * bc[n]);
    }
    ushortT* hp = HL + ((size_t)(zz * NCHUNK + c) * D_INNER + d) * D_STATE;
    unsigned pk[8];
#pragma unroll
    for (int q = 0; q < 8; ++q)
        asm("v_cvt_pk_bf16_f32 %0, %1, %2" : "=v"(pk[q]) : "v"(h[2*q]), "v"(h[2*q+1]));
    uint4 lo4; lo4.x = pk[0]; lo4.y = pk[1]; lo4.z = pk[2]; lo4.w = pk[3];
    uint4 hi4; hi4.x = pk[4]; hi4.y = pk[5]; hi4.z = pk[6]; hi4.w = pk[7];
    *(uint4*)(hp) = lo4;
    *(uint4*)(hp + 8) = hi4;
    SD[(size_t)(zz * NCHUNK + c) * D_INNER + d] = S;
}

// ---------------- scan level 2: chunk combine (in place: HL[c] <- incoming h0) ----------------
__global__ __launch_bounds__(256)
void scan_l2_k(ushortT* __restrict__ HL, const float* __restrict__ SD,
               const float* __restrict__ A_log)
{
    int t = blockIdx.x * 256 + threadIdx.x;
    if (t >= 4 * D_INNER * D_STATE) return;
    int n = t & 15;
    int d = (t >> 4) % D_INNER;
    int zz = t / (D_INNER * D_STATE);
    float Aa = -__expf(A_log[d * D_STATE + n]);
    float h0 = 0.f;
    for (int c = 0; c < NCHUNK; ++c) {
        size_t ih = ((size_t)(zz * NCHUNK + c) * D_INNER + d) * D_STATE + n;
        float hl = bf2f(HL[ih]);
        float T = __expf(Aa * SD[(size_t)(zz * NCHUNK + c) * D_INNER + d]);
        HL[ih] = f2bf(h0);
        h0 = fmaf(T, h0, hl);
    }
}

// ---------------- scan level 3 + gate fused: both dirs per thread, writes YC bf16 ----------------
__global__ __launch_bounds__(256)
void scan3_gate_k(const ushortT* __restrict__ DMb, const ushortT* __restrict__ DBb,
                  const ushortT* __restrict__ Um, const ushortT* __restrict__ Ub,
                  const float* __restrict__ XDC, const float* __restrict__ A_log,
                  const float* __restrict__ Dv, const ushortT* __restrict__ HL,
                  const ushortT* __restrict__ G, ushortT* __restrict__ YC)
{
    int d = blockIdx.x * 256 + threadIdx.x;
    if (d >= D_INNER) return;
    int c = blockIdx.y, b = blockIdx.z;
    int rd = D_INNER - 1 - d;
    float Aa0[D_STATE], Aa1[D_STATE], h0[D_STATE], h1[D_STATE];
#pragma unroll
    for (int n = 0; n < D_STATE; ++n) Aa0[n] = -__expf(A_log[d * D_STATE + n]);
#pragma unroll
    for (int n = 0; n < D_STATE; ++n) Aa1[n] = -__expf(A_log[rd * D_STATE + n]);
    const ushortT* hp0 = HL + ((size_t)((b * 2) * NCHUNK + c) * D_INNER + d) * D_STATE;
    const ushortT* hp1 = HL + ((size_t)((b * 2 + 1) * NCHUNK + c) * D_INNER + rd) * D_STATE;
    {
        uint4 a0 = *(const uint4*)(hp0);
        uint4 a1 = *(const uint4*)(hp0 + 8);
        unsigned ww[8] = {a0.x, a0.y, a0.z, a0.w, a1.x, a1.y, a1.z, a1.w};
#pragma unroll
        for (int q = 0; q < 8; ++q) {
            h0[2*q]   = bf2f((ushortT)ww[q]);
            h0[2*q+1] = bf2f((ushortT)(ww[q] >> 16));
        }
        uint4 b0 = *(const uint4*)(hp1);
        uint4 b1 = *(const uint4*)(hp1 + 8);
        unsigned vv[8] = {b0.x, b0.y, b0.z, b0.w, b1.x, b1.y, b1.z, b1.w};
#pragma unroll
        for (int q = 0; q < 8; ++q) {
            h1[2*q]   = bf2f((ushortT)vv[q]);
            h1[2*q+1] = bf2f((ushortT)(vv[q] >> 16));
        }
    }
    float Dd0 = Dv[d], Dd1 = Dv[rd];
    const float* XD0 = XDC;
    const float* XD1 = XDC + (size_t)MROWS * 32;
    int l0 = c * CLEN;
    for (int i = 0; i < CLEN; ++i) {
        size_t rowi = (size_t)b * SEQ_L + l0 + i;
        float delta0 = bf2f(DMb[rowi * D_INNER + d]);
        float u0 = bf2f(Um[rowi * KP_DI + d]);
        const float* bc0 = XD0 + rowi * 32;
        float du0 = delta0 * u0;
        float acc0 = u0 * Dd0;
#pragma unroll
        for (int n = 0; n < D_STATE; ++n) {
            h0[n] = fmaf(__expf(delta0 * Aa0[n]), h0[n], du0 * bc0[n]);
            acc0 = fmaf(h0[n], bc0[D_STATE + n], acc0);
        }
        float delta1 = bf2f(DBb[rowi * D_INNER + rd]);
        float u1 = bf2f(Ub[rowi * KP_DI + rd]);
        const float* bc1 = XD1 + rowi * 32;
        float du1 = delta1 * u1;
        float acc1 = u1 * Dd1;
#pragma unroll
        for (int n = 0; n < D_STATE; ++n) {
            h1[n] = fmaf(__expf(delta1 * Aa1[n]), h1[n], du1 * bc1[n]);
            acc1 = fmaf(h1[n], bc1[D_STATE + n], acc1);
        }
        float g = bf2f(G[rowi * D_INNER + d]);
        YC[rowi * KP_DI + d] = f2bf((acc0 + acc1) * g);
    }
}

extern "C" void kernel_launch(void* const* d_in, const int* in_sizes, int n_in,
                              void* d_out, int out_size, void* d_ws, size_t ws_size,
                              hipStream_t stream)
{
    const float* inp    = (const float*)d_in[0];
    const float* W_emb  = (const float*)d_in[1];
    const float* b_emb  = (const float*)d_in[2];
    const float* norm_w = (const float*)d_in[3];
    const float* W_in   = (const float*)d_in[4];
    const float* conv_w = (const float*)d_in[5];
    const float* conv_b = (const float*)d_in[6];
    const float* W_xp   = (const float*)d_in[7];
    const float* W_dt   = (const float*)d_in[8];
    const float* b_dt   = (const float*)d_in[9];
    const float* A_log  = (const float*)d_in[10];
    const float* Dv     = (const float*)d_in[11];
    const float* W_out  = (const float*)d_in[12];
    const float* normf_w= (const float*)d_in[13];
    const float* pe     = (const float*)d_in[14];

    char* base = (char*)d_ws;
    size_t off = 0;
    auto alloc = [&](size_t bytes) { char* p = base + off; off += (bytes + 255) & ~(size_t)255; return p; };

    float*   XS      = (float*)alloc(6480000);        // residual f32, lives to end
    // arena1: XPp (11.06MB, xp partials) -> HL bf16 (10.37MB)+SD(1.296MB)
    char*    arena1  = alloc(22032000);
    float*   XPp     = (float*)arena1;
    ushortT* HL      = (ushortT*)arena1;              // 4 x 45 x 1800 x 16 bf16 = 10.368 MB
    float*   SD      = (float*)(arena1 + 10368000);   // 4 x 45 x 1800 f32 = 1.296 MB
    ushortT* inp_bf  = (ushortT*)alloc(3686400);      // 1920x960; later start of YC
    ushortT* XN_bf   = (ushortT*)alloc(3686400);      // contiguous after inp_bf (YC spillover)
    ushortT* Wemb_bf = (ushortT*)alloc(1966080);      // 1024x960; after emb: XDC+XDM_bf+XDB_bf
    ushortT* Win_bf  = (ushortT*)alloc(7127040);      // 3712x960; after in-proj: XMC_bf (1920x1856)
    ushortT* Wxp_bf  = (ushortT*)alloc(475136);       // 128x1856
    ushortT* Wdt_bf  = (ushortT*)alloc(245760);       // 1920x64
    ushortT* Wout_bf = (ushortT*)alloc(3801088);      // 1024x1856
    ushortT* XBC_bf  = (ushortT*)alloc(7127040);      // 1920x1856
    // arena2 (25.92MB): Pemb(bf16 x4) -> XR0/XR1 -> DMb/DBb(bf16) -> ZP(bf16 x4)
    char*    arena2  = alloc(25920000);
    ushortT* Pemb    = (ushortT*)arena2;
    ushortT* XR0     = (ushortT*)arena2;
    ushortT* XR1     = XR0 + (size_t)MROWS * 3600;
    ushortT* DMb     = (ushortT*)arena2;
    ushortT* DBb     = DMb + (size_t)MROWS * D_INNER;
    ushortT* ZP      = (ushortT*)arena2;
    ushortT* G_bf    = (ushortT*)alloc(6480000);      // 1800x1800 bf16

    // aliases into dead regions
    float*   XDC     = (float*)Wemb_bf;               // 2x1800x32 f32 = 460800 B
    ushortT* XDM_bf  = (ushortT*)((char*)Wemb_bf + 460800);   // 1920x64 bf16
    ushortT* XDB_bf  = (ushortT*)((char*)Wemb_bf + 706560);
    ushortT* XMC_bf  = Win_bf;                        // 1920x1856 bf16, exact fit
    ushortT* YC_bf   = inp_bf;                        // 1920x1856 spans inp_bf+XN_bf (7.13<=7.37MB)

    dim3 blk(256);
    auto cdiv = [](int a, int b) { return (a + b - 1) / b; };
    const size_t PSTR  = 1620000;   // 1800*900 elements (bf16 partial stride)
    const size_t XPSTR = 172800;    // 1800*96 f32 partial stride
    const size_t XRSTR = (size_t)MROWS * 3600;

    // 0) all conversions
    hipLaunchKernelGGL(cvt_all_k, dim3(3480, 6), blk, 0, stream,
                       inp, inp_bf, W_emb, Wemb_bf, W_in, Win_bf,
                       W_xp, Wxp_bf, W_dt, Wdt_bf, W_out, Wout_bf);
    // 1) embedding GEMM split-4 -> Pemb (bf16 partials)
    hipLaunchKernelGGL(gemm_mfma_k, dim3(8, 15, 4), blk, 0, stream,
                       inp_bf, inp_bf, KP_DM, Wemb_bf, KP_DM, KP_DM/64, 4,
                       (float*)nullptr, (float*)nullptr, 0, (size_t)0,
                       Pemb, Pemb, 900, PSTR,
                       MROWS, 900, (const float*)nullptr, 1);
    // 2) emb epilogue + rmsnorm -> XS, XN_bf
    hipLaunchKernelGGL(rmsnorm_emb_k, dim3(MROWS), blk, 0, stream,
                       Pemb, PSTR, b_emb, pe, norm_w, XS, XN_bf, KP_DM);
    // 3) in-proj split-2 -> XR0/XR1 (bf16 partials)
    hipLaunchKernelGGL(gemm_mfma_k, dim3(29, 15, 2), blk, 0, stream,
                       XN_bf, XN_bf, KP_DM, Win_bf, KP_DM, KP_DM/64, 2,
                       (float*)nullptr, (float*)nullptr, 0, (size_t)0,
                       XR0, XR0, 3600, XRSTR,
                       MROWS, 3600, (const float*)nullptr, 1);
    // 4) conv + silu + G
    hipLaunchKernelGGL(conv_silu_k, dim3(cdiv(MROWS * (D_INNER/2), 256)), blk, 0, stream,
                       XR0, XR1, conv_w, conv_b, XMC_bf, XBC_bf, G_bf);
    // 5) x-proj split-8 both dirs -> XPp (f32 partials)
    hipLaunchKernelGGL(gemm_mfma_k, dim3(1, 15, 16), blk, 0, stream,
                       XMC_bf, XBC_bf, KP_DI, Wxp_bf, KP_DI, KP_DI/64, 8,
                       XPp, XPp + 8 * XPSTR, 96, XPSTR,
                       (ushortT*)nullptr, (ushortT*)nullptr, 0, (size_t)0,
                       MROWS, 96, (const float*)nullptr, 0);
    // 5b) xp reduce -> XDC (compact BC) + bf16 dt inputs
    hipLaunchKernelGGL(xp_reduce_k, dim3(cdiv(2 * MROWS * 96, 256)), blk, 0, stream,
                       XPp, XPSTR, XDC, XDM_bf, XDB_bf);
    // 6) dt GEMM both dirs + fast-softplus -> DMb, DBb (bf16)
    hipLaunchKernelGGL(gemm_mfma_k, dim3(15, 15, 2), blk, 0, stream,
                       XDM_bf, XDB_bf, KP_DT, Wdt_bf, KP_DT, 1, 1,
                       (float*)nullptr, (float*)nullptr, 0, (size_t)0,
                       DMb, DBb, D_INNER, (size_t)0,
                       MROWS, D_INNER, b_dt, 5);
    // 7) chunked scan (HL bf16)
    hipLaunchKernelGGL(scan_l1_k, dim3(cdiv(D_INNER, 256), NCHUNK, 4), blk, 0, stream,
                       DMb, DBb, XMC_bf, XBC_bf, XDC, A_log, HL, SD);
    hipLaunchKernelGGL(scan_l2_k, dim3(cdiv(4 * D_INNER * D_STATE, 256)), blk, 0, stream, HL, SD, A_log);
    // 7c) level 3 + gate fused -> YC bf16
    hipLaunchKernelGGL(scan3_gate_k, dim3(cdiv(D_INNER, 256), NCHUNK, 2), blk, 0, stream,
                       DMb, DBb, XMC_bf, XBC_bf, XDC, A_log, Dv, HL, G_bf, YC_bf);
    // 9) out-proj split-4 -> ZP (bf16 partials)
    hipLaunchKernelGGL(gemm_mfma_k, dim3(8, 15, 4), blk, 0, stream,
                       YC_bf, YC_bf, KP_DI, Wout_bf, KP_DI, KP_DI/64, 4,
                       (float*)nullptr, (float*)nullptr, 0, (size_t)0,
                       ZP, ZP, 900, PSTR,
                       MROWS, 900, (const float*)nullptr, 1);
    // 10) final reduce + residual + rmsnorm -> d_out
    hipLaunchKernelGGL(rmsnorm_final_k, dim3(MROWS), blk, 0, stream,
                       ZP, PSTR, XS, normf_w, (float*)d_out);
}

// Round 9
// 276.728 us; speedup vs baseline: 8.1306x; 1.0286x over previous
//
#include <hip/hip_runtime.h>
#include <math.h>

typedef unsigned short ushortT;
typedef short short8 __attribute__((ext_vector_type(8)));
typedef float f32x4 __attribute__((ext_vector_type(4)));

#define D_STATE 16
#define D_INNER 1800
#define DT_RANK 57
#define SEQ_L 900
#define MROWS 1800            // 2*900
#define MP 1920               // padded rows
#define KP_DM 960             // K=900 pad
#define KP_DI 1856            // K=1800 pad
#define KP_DT 64              // K=57 pad
#define NCHUNK 45
#define CLEN 20

__device__ __forceinline__ ushortT f2bf(float f) {
    unsigned u = __float_as_uint(f);
    unsigned r = (u + 0x7FFFu + ((u >> 16) & 1u)) >> 16;
    return (ushortT)r;
}
__device__ __forceinline__ float bf2f(ushortT h) {
    return __uint_as_float((unsigned)h << 16);
}
__device__ __forceinline__ float silu_f(float x) { return x / (1.f + __expf(-x)); }
__device__ __forceinline__ float softplus_f(float x) {
    return fmaxf(x, 0.f) + __logf(1.f + __expf(-fabsf(x)));
}

__device__ __forceinline__ void gload_lds16(const ushortT* g, ushortT* l) {
    __builtin_amdgcn_global_load_lds((const __attribute__((address_space(1))) unsigned int*)g,
                                     (__attribute__((address_space(3))) unsigned int*)l,
                                     16, 0, 0);
}

// ---------------- all fp32->bf16 pad conversions in ONE kernel (8 cols/thread) ----------------
__global__ __launch_bounds__(256)
void cvt_all_k(const float* __restrict__ s0, ushortT* __restrict__ d0,   // inp 1800x900
               const float* __restrict__ s1, ushortT* __restrict__ d1,   // W_emb 900x900
               const float* __restrict__ s2, ushortT* __restrict__ d2,   // W_in 3600x900
               const float* __restrict__ s3, ushortT* __restrict__ d3,   // W_xp 89x1800
               const float* __restrict__ s4, ushortT* __restrict__ d4,   // W_dt 1800x57
               const float* __restrict__ s5, ushortT* __restrict__ d5)   // W_out 900x1800
{
    const float* src; ushortT* dst; int M, K, Mp, Kp;
    switch (blockIdx.y) {
      case 0: src=s0; dst=d0; M=1800; K=900;  Mp=1920; Kp=960;  break;
      case 1: src=s1; dst=d1; M=900;  K=900;  Mp=1024; Kp=960;  break;
      case 2: src=s2; dst=d2; M=3600; K=900;  Mp=3712; Kp=960;  break;
      case 3: src=s3; dst=d3; M=89;   K=1800; Mp=128;  Kp=1856; break;
      case 4: src=s4; dst=d4; M=1800; K=57;   Mp=1920; Kp=64;   break;
      default:src=s5; dst=d5; M=900;  K=1800; Mp=1024; Kp=1856; break;
    }
    int t = blockIdx.x * 256 + threadIdx.x;
    int K8 = Kp >> 3;
    if (t >= Mp * K8) return;
    int r = t / K8, c8 = (t - r * K8) * 8;
    unsigned pk[4];
#pragma unroll
    for (int q = 0; q < 4; ++q) {
        int ca = c8 + 2 * q, cb = ca + 1;
        float va = (r < M && ca < K) ? src[(size_t)r * K + ca] : 0.f;
        float vb = (r < M && cb < K) ? src[(size_t)r * K + cb] : 0.f;
        pk[q] = (unsigned)f2bf(va) | ((unsigned)f2bf(vb) << 16);
    }
    uint4 o; o.x = pk[0]; o.y = pk[1]; o.z = pk[2]; o.w = pk[3];
    *(uint4*)(dst + (size_t)r * Kp + c8) = o;
}

// ---------------- bf16 MFMA GEMM: dbuf + prefetch + counted vmcnt + T1/T2 swizzles ----------------
// z: dir = z/split, s = z%split.
// mode 0: raw f32 -> C (+s*cstride)
// mode 1: raw bf16 -> Xo (+s*xstride)
// mode 5: softplus(acc+bias) -> bf16 -> Xo
// mode 6: in-proj fused: col<1800 -> bf16 Xo (ld=ldx); col>=1800 -> silu -> bf16 G (=C0 cast, ld=1800)
__global__ __launch_bounds__(256)
void gemm_mfma_k(const ushortT* __restrict__ A0, const ushortT* __restrict__ A1, int lda,
                 const ushortT* __restrict__ Bw, int ldb, int nkTotal, int split,
                 float* __restrict__ C0, float* __restrict__ C1, int ldc, size_t cstride,
                 ushortT* __restrict__ X0, ushortT* __restrict__ X1, int ldx, size_t xstride,
                 int M, int N, const float* __restrict__ bias, int mode)
{
    __shared__ ushortT As[2][128 * 64];
    __shared__ ushortT Bs[2][128 * 64];

    // T1: bijective XCD-aware remap (m204) of the flattened block id.
    int gx = gridDim.x, gy = gridDim.y;
    int nwg = gx * gy * gridDim.z;
    int orig = (blockIdx.z * gy + blockIdx.y) * gx + blockIdx.x;
    int q8 = nwg >> 3, r8 = nwg & 7;
    int xcd = orig & 7, i8 = orig >> 3;
    int wg = (xcd < r8 ? xcd * (q8 + 1) : r8 * (q8 + 1) + (xcd - r8) * q8) + i8;
    int bx = wg % gx; int tmp = wg / gx; int by = tmp % gy; int bz = tmp / gy;

    int dir = bz / split, s = bz % split;
    int per = (nkTotal + split - 1) / split;
    int kt0 = s * per;
    int kcnt = nkTotal - kt0; if (kcnt > per) kcnt = per;
    int ktEnd = kt0 + kcnt;

    const ushortT* A = dir ? A1 : A0;
    float* C = (dir ? C1 : C0);
    ushortT* Xo = (dir ? X1 : X0);
    if (C && mode != 6)  C  += (size_t)s * cstride;
    if (Xo) Xo += (size_t)s * xstride;

    int tid = threadIdx.x;
    int lane = tid & 63, wave = tid >> 6;
    int wr = wave >> 1, wc = wave & 1;
    int m0 = by * 128, n0 = bx * 128;

    // T2: pre-swizzled global source column; LDS stays linear (rule #21).
    int csw = ((((tid >> 3) & 7) ^ (tid & 7)) << 3);
    auto stage = [&](int sb, int kt) {
#pragma unroll
        for (int r = 0; r < 4; ++r) {
            int idx = r * 256 + tid;
            int row = idx >> 3;
            gload_lds16(A + (size_t)(m0 + row) * lda + kt * 64 + csw, &As[sb][idx * 8]);
        }
#pragma unroll
        for (int r = 0; r < 4; ++r) {
            int idx = r * 256 + tid;
            int row = idx >> 3;
            gload_lds16(Bw + (size_t)(n0 + row) * ldb + kt * 64 + csw, &Bs[sb][idx * 8]);
        }
    };

    f32x4 acc[4][4] = {};
    int rmask = (lane & 7) << 3;

    stage(0, kt0);
    for (int t = kt0; t < ktEnd; ++t) {
        int cur = (t - kt0) & 1;
        if (t + 1 < ktEnd) {
            stage(cur ^ 1, t + 1);
            asm volatile("s_waitcnt vmcnt(8)" ::: "memory");
        } else {
            asm volatile("s_waitcnt vmcnt(0)" ::: "memory");
        }
        __builtin_amdgcn_s_barrier();
        __builtin_amdgcn_sched_barrier(0);
#pragma unroll
        for (int ks = 0; ks < 2; ++ks) {
            short8 av[4], bv[4];
            int kcol = (ks * 32 + (lane >> 4) * 8) ^ rmask;
#pragma unroll
            for (int i = 0; i < 4; ++i)
                av[i] = *(const short8*)(&As[cur][(wr * 64 + i * 16 + (lane & 15)) * 64 + kcol]);
#pragma unroll
            for (int j = 0; j < 4; ++j)
                bv[j] = *(const short8*)(&Bs[cur][(wc * 64 + j * 16 + (lane & 15)) * 64 + kcol]);
#pragma unroll
            for (int i = 0; i < 4; ++i)
#pragma unroll
                for (int j = 0; j < 4; ++j)
                    acc[i][j] = __builtin_amdgcn_mfma_f32_16x16x32_bf16(bv[j], av[i], acc[i][j], 0, 0, 0);
        }
        __builtin_amdgcn_sched_barrier(0);
        __builtin_amdgcn_s_barrier();
        __builtin_amdgcn_sched_barrier(0);
    }

#pragma unroll
    for (int i = 0; i < 4; ++i) {
        int m = m0 + wr * 64 + i * 16 + (lane & 15);
        if (m >= M) continue;
#pragma unroll
        for (int j = 0; j < 4; ++j) {
            int nb = n0 + wc * 64 + j * 16 + (lane >> 4) * 4;
            if (nb >= N) continue;     // N and nb are multiples of 4
            f32x4 v = acc[i][j];
            if (mode == 5) {
#pragma unroll
                for (int e = 0; e < 4; ++e)
                    v[e] = softplus_f(v[e] + bias[nb + e]);
            }
            if (mode == 6) {
                if (nb < D_INNER) {
                    unsigned lo, hi;
                    asm("v_cvt_pk_bf16_f32 %0, %1, %2" : "=v"(lo) : "v"(v[0]), "v"(v[1]));
                    asm("v_cvt_pk_bf16_f32 %0, %1, %2" : "=v"(hi) : "v"(v[2]), "v"(v[3]));
                    uint2 pk; pk.x = lo; pk.y = hi;
                    *(uint2*)(Xo + (size_t)m * ldx + nb) = pk;
                } else {
                    ushortT* G = (ushortT*)C;
#pragma unroll
                    for (int e = 0; e < 4; ++e) v[e] = silu_f(v[e]);
                    unsigned lo, hi;
                    asm("v_cvt_pk_bf16_f32 %0, %1, %2" : "=v"(lo) : "v"(v[0]), "v"(v[1]));
                    asm("v_cvt_pk_bf16_f32 %0, %1, %2" : "=v"(hi) : "v"(v[2]), "v"(v[3]));
                    uint2 pk; pk.x = lo; pk.y = hi;
                    *(uint2*)(G + (size_t)m * D_INNER + (nb - D_INNER)) = pk;
                }
            } else if (mode == 1 || mode == 5) {
                unsigned lo, hi;
                asm("v_cvt_pk_bf16_f32 %0, %1, %2" : "=v"(lo) : "v"(v[0]), "v"(v[1]));
                asm("v_cvt_pk_bf16_f32 %0, %1, %2" : "=v"(hi) : "v"(v[2]), "v"(v[3]));
                uint2 pk; pk.x = lo; pk.y = hi;
                *(uint2*)(Xo + (size_t)m * ldx + nb) = pk;
            } else {
                *(f32x4*)(C + (size_t)m * ldc + nb) = v;
            }
        }
    }
}

// ---------------- emb epilogue + rmsnorm (sums 4 bf16 partials) ----------------
__global__ __launch_bounds__(256)
void rmsnorm_emb_k(const ushortT* __restrict__ P, size_t pstride,
                   const float* __restrict__ b_emb, const float* __restrict__ pe,
                   const float* __restrict__ norm_w,
                   float* __restrict__ XS, ushortT* __restrict__ XN, int ldxn)
{
    int row = blockIdx.x;
    int l = (row >= SEQ_L) ? row - SEQ_L : row;
    float vv[4];
    float ssum = 0.f;
#pragma unroll
    for (int k = 0; k < 4; ++k) {
        int c = threadIdx.x + k * 256;
        if (c < 900) {
            size_t i = (size_t)row * 900 + c;
            float a = bf2f(P[i]) + bf2f(P[i + pstride]) + bf2f(P[i + 2 * pstride]) + bf2f(P[i + 3 * pstride]);
            float v = 30.f * (a + b_emb[c]) + pe[(size_t)l * 900 + c];
            vv[k] = v;
            ssum += v * v;
        } else vv[k] = 0.f;
    }
#pragma unroll
    for (int off = 32; off; off >>= 1) ssum += __shfl_down(ssum, off, 64);
    __shared__ float red[4];
    int wv = threadIdx.x >> 6;
    if ((threadIdx.x & 63) == 0) red[wv] = ssum;
    __syncthreads();
    float tot = red[0] + red[1] + red[2] + red[3];
    float scale = rsqrtf(tot / 900.f + 1e-5f);
#pragma unroll
    for (int k = 0; k < 4; ++k) {
        int c = threadIdx.x + k * 256;
        if (c < 900) {
            XS[(size_t)row * 900 + c] = vv[k];
            XN[(size_t)row * ldxn + c] = f2bf(vv[k] * scale * norm_w[c]);
        }
    }
}

// ---------------- final: 4 bf16 partials + residual -> rmsnorm -> out ----------------
__global__ __launch_bounds__(256)
void rmsnorm_final_k(const ushortT* __restrict__ ZP, size_t zstride,
                     const float* __restrict__ XS, const float* __restrict__ w,
                     float* __restrict__ out)
{
    int row = blockIdx.x;
    float vv[4];
    float ssum = 0.f;
#pragma unroll
    for (int k = 0; k < 4; ++k) {
        int c = threadIdx.x + k * 256;
        if (c < 900) {
            size_t i = (size_t)row * 900 + c;
            float v = bf2f(ZP[i]) + bf2f(ZP[i + zstride]) + bf2f(ZP[i + 2 * zstride]) + bf2f(ZP[i + 3 * zstride]) + XS[i];
            vv[k] = v;
            ssum += v * v;
        } else vv[k] = 0.f;
    }
#pragma unroll
    for (int off = 32; off; off >>= 1) ssum += __shfl_down(ssum, off, 64);
    __shared__ float red[4];
    int wv = threadIdx.x >> 6;
    if ((threadIdx.x & 63) == 0) red[wv] = ssum;
    __syncthreads();
    float tot = red[0] + red[1] + red[2] + red[3];
    float scale = rsqrtf(tot / 900.f + 1e-5f);
#pragma unroll
    for (int k = 0; k < 4; ++k) {
        int c = threadIdx.x + k * 256;
        if (c < 900) out[(size_t)row * 900 + c] = vv[k] * scale * w[c];
    }
}

// ---------------- conv: 4 channels/thread, single XR (xm half only), uint2 loads ----------------
__global__ __launch_bounds__(256)
void conv_silu_k(const ushortT* __restrict__ xr,   // [1800][1800] bf16 (xm half)
                 const float* __restrict__ w, const float* __restrict__ cb,
                 ushortT* __restrict__ xmc, ushortT* __restrict__ xbc)
{
    int t = blockIdx.x * 256 + threadIdx.x;
    if (t >= MROWS * (D_INNER / 4)) return;
    int d0 = (t % (D_INNER / 4)) * 4;
    int row = t / (D_INNER / 4);
    int l = row % SEQ_L;
    float wv[4][4], sf[4], sb[4];
#pragma unroll
    for (int ch = 0; ch < 4; ++ch) {
        f32x4 wl = *(const f32x4*)(w + (d0 + ch) * 4);
        wv[ch][0] = wl[0]; wv[ch][1] = wl[1]; wv[ch][2] = wl[2]; wv[ch][3] = wl[3];
        float b = cb[d0 + ch];
        sf[ch] = b; sb[ch] = b;
    }
    int rdp = 1796 - d0;   // loads rev-channels rdp..rdp+3; output ch d0+ch uses rev-ch rdp+3-ch
#pragma unroll
    for (int k = 0; k < 4; ++k) {
        int ll = l - 3 + k;
        if (ll < 0) continue;
        const ushortT* rp = xr + (size_t)(row - l + ll) * D_INNER;
        uint2 f = *(const uint2*)(rp + d0);
        float a0 = bf2f((ushortT)f.x), a1 = bf2f((ushortT)(f.x >> 16));
        float a2 = bf2f((ushortT)f.y), a3 = bf2f((ushortT)(f.y >> 16));
        sf[0] = fmaf(wv[0][k], a0, sf[0]);
        sf[1] = fmaf(wv[1][k], a1, sf[1]);
        sf[2] = fmaf(wv[2][k], a2, sf[2]);
        sf[3] = fmaf(wv[3][k], a3, sf[3]);
        uint2 rv = *(const uint2*)(rp + rdp);
        float b0 = bf2f((ushortT)rv.x), b1 = bf2f((ushortT)(rv.x >> 16));
        float b2 = bf2f((ushortT)rv.y), b3 = bf2f((ushortT)(rv.y >> 16));
        sb[0] = fmaf(wv[0][k], b3, sb[0]);   // rev-ch rdp+3 = 1799-d0
        sb[1] = fmaf(wv[1][k], b2, sb[1]);
        sb[2] = fmaf(wv[2][k], b1, sb[2]);
        sb[3] = fmaf(wv[3][k], b0, sb[3]);
    }
    uint2 om, ob;
    om.x = (unsigned)f2bf(silu_f(sf[0])) | ((unsigned)f2bf(silu_f(sf[1])) << 16);
    om.y = (unsigned)f2bf(silu_f(sf[2])) | ((unsigned)f2bf(silu_f(sf[3])) << 16);
    ob.x = (unsigned)f2bf(silu_f(sb[0])) | ((unsigned)f2bf(silu_f(sb[1])) << 16);
    ob.y = (unsigned)f2bf(silu_f(sb[2])) | ((unsigned)f2bf(silu_f(sb[3])) << 16);
    *(uint2*)(xmc + (size_t)row * KP_DI + d0) = om;
    *(uint2*)(xbc + (size_t)row * KP_DI + d0) = ob;
}

// ---------------- xp reduce: 8 f32 partials -> compact BC f32 + bf16 dt-input ----------------
__global__ __launch_bounds__(256)
void xp_reduce_k(const float* __restrict__ XPp, size_t pstride,
                 float* __restrict__ XDC, ushortT* __restrict__ XDMb, ushortT* __restrict__ XDBb)
{
    int t = blockIdx.x * 256 + threadIdx.x;
    if (t >= 2 * MROWS * 96) return;
    int dir = t / (MROWS * 96);
    int rem = t - dir * (MROWS * 96);
    int row = rem / 96, c = rem - row * 96;
    const float* basep = XPp + (size_t)dir * 8 * pstride + (size_t)row * 96 + c;
    float s = 0.f;
#pragma unroll
    for (int p = 0; p < 8; ++p) s += basep[p * pstride];
    ushortT* xdb = dir ? XDBb : XDMb;
    if (c < DT_RANK)           xdb[(size_t)row * KP_DT + c] = f2bf(s);
    else if (c < KP_DT)        xdb[(size_t)row * KP_DT + c] = 0;
    if (c >= DT_RANK && c < DT_RANK + 2 * D_STATE)
        XDC[((size_t)dir * MROWS + row) * 32 + (c - DT_RANK)] = s;
}

// ---------------- scan level 1 (delta bf16 in, HL bf16 out) ----------------
__global__ __launch_bounds__(256)
void scan_l1_k(const ushortT* __restrict__ DMb, const ushortT* __restrict__ DBb,
               const ushortT* __restrict__ Um, const ushortT* __restrict__ Ub,
               const float* __restrict__ XDC, const float* __restrict__ A_log,
               ushortT* __restrict__ HL, float* __restrict__ SD)
{
    int d = blockIdx.x * 256 + threadIdx.x;
    if (d >= D_INNER) return;
    int c = blockIdx.y, zz = blockIdx.z;
    int b = zz >> 1, dir = zz & 1;
    const ushortT* DL = dir ? DBb : DMb;
    const ushortT* U = dir ? Ub : Um;
    const float* XD = XDC + (size_t)dir * MROWS * 32;
    float Aa[D_STATE];
#pragma unroll
    for (int n = 0; n < D_STATE; ++n) Aa[n] = -__expf(A_log[d * D_STATE + n]);
    float h[D_STATE] = {};
    float S = 0.f;
    int l0 = c * CLEN;
    for (int i = 0; i < CLEN; ++i) {
        size_t rowi = (size_t)b * SEQ_L + l0 + i;
        float delta = bf2f(DL[rowi * D_INNER + d]);
        float u = bf2f(U[rowi * KP_DI + d]);
        const float* bc = XD + rowi * 32;
        float du = delta * u;
        S += delta;
#pragma unroll
        for (int n = 0; n < D_STATE; ++n)
            h[n] = fmaf(__expf(delta * Aa[n]), h[n], du * bc[n]);
    }
    ushortT* hp = HL + ((size_t)(zz * NCHUNK + c) * D_INNER + d) * D_STATE;
    unsigned pk[8];
#pragma unroll
    for (int q = 0; q < 8; ++q)
        asm("v_cvt_pk_bf16_f32 %0, %1, %2" : "=v"(pk[q]) : "v"(h[2*q]), "v"(h[2*q+1]));
    uint4 lo4; lo4.x = pk[0]; lo4.y = pk[1]; lo4.z = pk[2]; lo4.w = pk[3];
    uint4 hi4; hi4.x = pk[4]; hi4.y = pk[5]; hi4.z = pk[6]; hi4.w = pk[7];
    *(uint4*)(hp) = lo4;
    *(uint4*)(hp + 8) = hi4;
    SD[(size_t)(zz * NCHUNK + c) * D_INNER + d] = S;
}

// ---------------- scan level 2: chunk combine (in place: HL[c] <- incoming h0) ----------------
__global__ __launch_bounds__(256)
void scan_l2_k(ushortT* __restrict__ HL, const float* __restrict__ SD,
               const float* __restrict__ A_log)
{
    int t = blockIdx.x * 256 + threadIdx.x;
    if (t >= 4 * D_INNER * D_STATE) return;
    int n = t & 15;
    int d = (t >> 4) % D_INNER;
    int zz = t / (D_INNER * D_STATE);
    float Aa = -__expf(A_log[d * D_STATE + n]);
    float h0 = 0.f;
    for (int c = 0; c < NCHUNK; ++c) {
        size_t ih = ((size_t)(zz * NCHUNK + c) * D_INNER + d) * D_STATE + n;
        float hl = bf2f(HL[ih]);
        float T = __expf(Aa * SD[(size_t)(zz * NCHUNK + c) * D_INNER + d]);
        HL[ih] = f2bf(h0);
        h0 = fmaf(T, h0, hl);
    }
}

// ---------------- scan level 3 + gate fused: both dirs per thread, writes YC bf16 ----------------
__global__ __launch_bounds__(256)
void scan3_gate_k(const ushortT* __restrict__ DMb, const ushortT* __restrict__ DBb,
                  const ushortT* __restrict__ Um, const ushortT* __restrict__ Ub,
                  const float* __restrict__ XDC, const float* __restrict__ A_log,
                  const float* __restrict__ Dv, const ushortT* __restrict__ HL,
                  const ushortT* __restrict__ G, ushortT* __restrict__ YC)
{
    int d = blockIdx.x * 256 + threadIdx.x;
    if (d >= D_INNER) return;
    int c = blockIdx.y, b = blockIdx.z;
    int rd = D_INNER - 1 - d;
    float Aa0[D_STATE], Aa1[D_STATE], h0[D_STATE], h1[D_STATE];
#pragma unroll
    for (int n = 0; n < D_STATE; ++n) Aa0[n] = -__expf(A_log[d * D_STATE + n]);
#pragma unroll
    for (int n = 0; n < D_STATE; ++n) Aa1[n] = -__expf(A_log[rd * D_STATE + n]);
    const ushortT* hp0 = HL + ((size_t)((b * 2) * NCHUNK + c) * D_INNER + d) * D_STATE;
    const ushortT* hp1 = HL + ((size_t)((b * 2 + 1) * NCHUNK + c) * D_INNER + rd) * D_STATE;
    {
        uint4 a0 = *(const uint4*)(hp0);
        uint4 a1 = *(const uint4*)(hp0 + 8);
        unsigned ww[8] = {a0.x, a0.y, a0.z, a0.w, a1.x, a1.y, a1.z, a1.w};
#pragma unroll
        for (int q = 0; q < 8; ++q) {
            h0[2*q]   = bf2f((ushortT)ww[q]);
            h0[2*q+1] = bf2f((ushortT)(ww[q] >> 16));
        }
        uint4 b0 = *(const uint4*)(hp1);
        uint4 b1 = *(const uint4*)(hp1 + 8);
        unsigned vv[8] = {b0.x, b0.y, b0.z, b0.w, b1.x, b1.y, b1.z, b1.w};
#pragma unroll
        for (int q = 0; q < 8; ++q) {
            h1[2*q]   = bf2f((ushortT)vv[q]);
            h1[2*q+1] = bf2f((ushortT)(vv[q] >> 16));
        }
    }
    float Dd0 = Dv[d], Dd1 = Dv[rd];
    const float* XD0 = XDC;
    const float* XD1 = XDC + (size_t)MROWS * 32;
    int l0 = c * CLEN;
    for (int i = 0; i < CLEN; ++i) {
        size_t rowi = (size_t)b * SEQ_L + l0 + i;
        float delta0 = bf2f(DMb[rowi * D_INNER + d]);
        float u0 = bf2f(Um[rowi * KP_DI + d]);
        const float* bc0 = XD0 + rowi * 32;
        float du0 = delta0 * u0;
        float acc0 = u0 * Dd0;
#pragma unroll
        for (int n = 0; n < D_STATE; ++n) {
            h0[n] = fmaf(__expf(delta0 * Aa0[n]), h0[n], du0 * bc0[n]);
            acc0 = fmaf(h0[n], bc0[D_STATE + n], acc0);
        }
        float delta1 = bf2f(DBb[rowi * D_INNER + rd]);
        float u1 = bf2f(Ub[rowi * KP_DI + rd]);
        const float* bc1 = XD1 + rowi * 32;
        float du1 = delta1 * u1;
        float acc1 = u1 * Dd1;
#pragma unroll
        for (int n = 0; n < D_STATE; ++n) {
            h1[n] = fmaf(__expf(delta1 * Aa1[n]), h1[n], du1 * bc1[n]);
            acc1 = fmaf(h1[n], bc1[D_STATE + n], acc1);
        }
        float g = bf2f(G[rowi * D_INNER + d]);
        YC[rowi * KP_DI + d] = f2bf((acc0 + acc1) * g);
    }
}

extern "C" void kernel_launch(void* const* d_in, const int* in_sizes, int n_in,
                              void* d_out, int out_size, void* d_ws, size_t ws_size,
                              hipStream_t stream)
{
    const float* inp    = (const float*)d_in[0];
    const float* W_emb  = (const float*)d_in[1];
    const float* b_emb  = (const float*)d_in[2];
    const float* norm_w = (const float*)d_in[3];
    const float* W_in   = (const float*)d_in[4];
    const float* conv_w = (const float*)d_in[5];
    const float* conv_b = (const float*)d_in[6];
    const float* W_xp   = (const float*)d_in[7];
    const float* W_dt   = (const float*)d_in[8];
    const float* b_dt   = (const float*)d_in[9];
    const float* A_log  = (const float*)d_in[10];
    const float* Dv     = (const float*)d_in[11];
    const float* W_out  = (const float*)d_in[12];
    const float* normf_w= (const float*)d_in[13];
    const float* pe     = (const float*)d_in[14];

    char* base = (char*)d_ws;
    size_t off = 0;
    auto alloc = [&](size_t bytes) { char* p = base + off; off += (bytes + 255) & ~(size_t)255; return p; };

    float*   XS      = (float*)alloc(6480000);        // residual f32, lives to end
    // arena1: XPp (11.06MB, xp partials) -> HL bf16 (10.37MB)+SD(1.296MB)
    char*    arena1  = alloc(22032000);
    float*   XPp     = (float*)arena1;
    ushortT* HL      = (ushortT*)arena1;              // 4 x 45 x 1800 x 16 bf16 = 10.368 MB
    float*   SD      = (float*)(arena1 + 10368000);   // 4 x 45 x 1800 f32 = 1.296 MB
    ushortT* inp_bf  = (ushortT*)alloc(3686400);      // 1920x960; later start of YC
    ushortT* XN_bf   = (ushortT*)alloc(3686400);      // contiguous after inp_bf (YC spillover)
    ushortT* Wemb_bf = (ushortT*)alloc(1966080);      // 1024x960; after emb: XDC+XDM_bf+XDB_bf
    ushortT* Win_bf  = (ushortT*)alloc(7127040);      // 3712x960; after in-proj: XMC_bf (1920x1856)
    ushortT* Wxp_bf  = (ushortT*)alloc(475136);       // 128x1856
    ushortT* Wdt_bf  = (ushortT*)alloc(245760);       // 1920x64
    ushortT* Wout_bf = (ushortT*)alloc(3801088);      // 1024x1856
    ushortT* XBC_bf  = (ushortT*)alloc(7127040);      // 1920x1856
    // arena2 (25.92MB): Pemb(bf16 x4) -> XR (1800x1800 bf16) -> DMb/DBb(bf16) -> ZP(bf16 x4)
    char*    arena2  = alloc(25920000);
    ushortT* Pemb    = (ushortT*)arena2;
    ushortT* XR      = (ushortT*)arena2;              // 1800x1800 bf16 (xm half only)
    ushortT* DMb     = (ushortT*)arena2;
    ushortT* DBb     = DMb + (size_t)MROWS * D_INNER;
    ushortT* ZP      = (ushortT*)arena2;
    ushortT* G_bf    = (ushortT*)alloc(6480000);      // 1800x1800 bf16 (written by in-proj GEMM)

    // aliases into dead regions
    float*   XDC     = (float*)Wemb_bf;               // 2x1800x32 f32 = 460800 B
    ushortT* XDM_bf  = (ushortT*)((char*)Wemb_bf + 460800);   // 1920x64 bf16
    ushortT* XDB_bf  = (ushortT*)((char*)Wemb_bf + 706560);
    ushortT* XMC_bf  = Win_bf;                        // 1920x1856 bf16, exact fit
    ushortT* YC_bf   = inp_bf;                        // 1920x1856 spans inp_bf+XN_bf (7.13<=7.37MB)

    dim3 blk(256);
    auto cdiv = [](int a, int b) { return (a + b - 1) / b; };
    const size_t PSTR  = 1620000;   // 1800*900 elements (bf16 partial stride)
    const size_t XPSTR = 172800;    // 1800*96 f32 partial stride

    // 0) all conversions (8 cols/thread)
    hipLaunchKernelGGL(cvt_all_k, dim3(1740, 6), blk, 0, stream,
                       inp, inp_bf, W_emb, Wemb_bf, W_in, Win_bf,
                       W_xp, Wxp_bf, W_dt, Wdt_bf, W_out, Wout_bf);
    // 1) embedding GEMM split-4 -> Pemb (bf16 partials)
    hipLaunchKernelGGL(gemm_mfma_k, dim3(8, 15, 4), blk, 0, stream,
                       inp_bf, inp_bf, KP_DM, Wemb_bf, KP_DM, KP_DM/64, 4,
                       (float*)nullptr, (float*)nullptr, 0, (size_t)0,
                       Pemb, Pemb, 900, PSTR,
                       MROWS, 900, (const float*)nullptr, 1);
    // 2) emb epilogue + rmsnorm -> XS, XN_bf
    hipLaunchKernelGGL(rmsnorm_emb_k, dim3(MROWS), blk, 0, stream,
                       Pemb, PSTR, b_emb, pe, norm_w, XS, XN_bf, KP_DM);
    // 3) in-proj split-1, fused G epilogue -> XR (xm half bf16) + G_bf
    hipLaunchKernelGGL(gemm_mfma_k, dim3(29, 15, 1), blk, 0, stream,
                       XN_bf, XN_bf, KP_DM, Win_bf, KP_DM, KP_DM/64, 1,
                       (float*)G_bf, (float*)G_bf, 0, (size_t)0,
                       XR, XR, D_INNER, (size_t)0,
                       MROWS, 3600, (const float*)nullptr, 6);
    // 4) conv + silu (4 ch/thread, single XR)
    hipLaunchKernelGGL(conv_silu_k, dim3(cdiv(MROWS * (D_INNER/4), 256)), blk, 0, stream,
                       XR, conv_w, conv_b, XMC_bf, XBC_bf);
    // 5) x-proj split-8 both dirs -> XPp (f32 partials)
    hipLaunchKernelGGL(gemm_mfma_k, dim3(1, 15, 16), blk, 0, stream,
                       XMC_bf, XBC_bf, KP_DI, Wxp_bf, KP_DI, KP_DI/64, 8,
                       XPp, XPp + 8 * XPSTR, 96, XPSTR,
                       (ushortT*)nullptr, (ushortT*)nullptr, 0, (size_t)0,
                       MROWS, 96, (const float*)nullptr, 0);
    // 5b) xp reduce -> XDC (compact BC) + bf16 dt inputs
    hipLaunchKernelGGL(xp_reduce_k, dim3(cdiv(2 * MROWS * 96, 256)), blk, 0, stream,
                       XPp, XPSTR, XDC, XDM_bf, XDB_bf);
    // 6) dt GEMM both dirs + fast-softplus -> DMb, DBb (bf16)
    hipLaunchKernelGGL(gemm_mfma_k, dim3(15, 15, 2), blk, 0, stream,
                       XDM_bf, XDB_bf, KP_DT, Wdt_bf, KP_DT, 1, 1,
                       (float*)nullptr, (float*)nullptr, 0, (size_t)0,
                       DMb, DBb, D_INNER, (size_t)0,
                       MROWS, D_INNER, b_dt, 5);
    // 7) chunked scan (HL bf16)
    hipLaunchKernelGGL(scan_l1_k, dim3(cdiv(D_INNER, 256), NCHUNK, 4), blk, 0, stream,
                       DMb, DBb, XMC_bf, XBC_bf, XDC, A_log, HL, SD);
    hipLaunchKernelGGL(scan_l2_k, dim3(cdiv(4 * D_INNER * D_STATE, 256)), blk, 0, stream, HL, SD, A_log);
    // 7c) level 3 + gate fused -> YC bf16
    hipLaunchKernelGGL(scan3_gate_k, dim3(cdiv(D_INNER, 256), NCHUNK, 2), blk, 0, stream,
                       DMb, DBb, XMC_bf, XBC_bf, XDC, A_log, Dv, HL, G_bf, YC_bf);
    // 9) out-proj split-4 -> ZP (bf16 partials)
    hipLaunchKernelGGL(gemm_mfma_k, dim3(8, 15, 4), blk, 0, stream,
                       YC_bf, YC_bf, KP_DI, Wout_bf, KP_DI, KP_DI/64, 4,
                       (float*)nullptr, (float*)nullptr, 0, (size_t)0,
                       ZP, ZP, 900, PSTR,
                       MROWS, 900, (const float*)nullptr, 1);
    // 10) final reduce + residual + rmsnorm -> d_out
    hipLaunchKernelGGL(rmsnorm_final_k, dim3(MROWS), blk, 0, stream,
                       ZP, PSTR, XS, normf_w, (float*)d_out);
}